// Round 11
// baseline (572.516 us; speedup 1.0000x reference)
//
#include <hip/hip_runtime.h>
#include <cstdint>
#include <cstddef>

typedef __bf16 bf16;
typedef __bf16 bf16x8 __attribute__((ext_vector_type(8)));
typedef float f32x4 __attribute__((ext_vector_type(4)));

#define B_ 8
#define N_ 1024
#define D_ 768
#define H_ 3
#define DC_ 1536
#define DK_ 512
#define PC_ 766
#define MB_ (1024ull*1024ull)

// ---------------- workspace layout (byte offsets) ----------------
static const size_t O_DEN   = 0;
static const size_t O_DEN2  = 32768;
static const size_t O_ADIAG = 65536;
static const size_t O_T2P   = 98304;
static const size_t O_THR   = 163840;
static const size_t O_CNTS  = 164096;
static const size_t O_HSEL  = 164352;
static const size_t O_SELC  = 164608;
static const size_t O_FLAG  = 164864;
static const size_t O_QKB   = 165120;
static const size_t O_SEL   = 180224;
static const size_t O_ATTN  = 262144;            // f32 [8,1024,1024] 32MB
static const size_t O_X     = O_ATTN + 32*MB_;   // bf16 [8,1024,1536] 24MB
static const size_t O_AX2   = O_X    + 24*MB_;   // bf16 [8,1024,1536] 24MB (QK out overlays early)
static const size_t O_ADJB  = O_AX2  + 24*MB_;   // bf16 [8,1024,1024] 16MB
static const size_t O_INT   = O_ADJB + 16*MB_;   // bf16 [8,768,1024] inputs^T -> OUT0T (12MB)
static const size_t O_BBA   = O_INT  + 12*MB_;
static const size_t O_BBB   = O_BBA  + 12*MB_;
static const size_t O_BBC   = O_BBB  + 12*MB_;
static const size_t O_W0T   = O_BBC  + 12*MB_;   // [768][768]
static const size_t O_W1T   = O_W0T + 1179648;   // [768][1536]
static const size_t O_QKWT  = O_W1T + 2359296;   // [3072][1536]
static const size_t O_CWB   = O_QKWT + 9437184;  // CW2 [1024][3072]
static const size_t O_LCT   = O_CWB + 6291456;
static const size_t O_F1T   = O_LCT + 1179648;
static const size_t O_F2T   = O_F1T + 1179648;
static const size_t WS_NEED = O_F2T + 1179648;
static const size_t O_OUT0T = O_INT;

// ---------------- helpers ----------------
__device__ __forceinline__ bool mask_at(const void* p, int flag, size_t i) {
    switch (flag) {
        case 1:  return ((const int*)p)[i] != 0;
        case 2:  return ((const float*)p)[i] != 0.0f;
        case 3:  return ((const long long*)p)[i] != 0;
        default: return ((const unsigned char*)p)[i] != 0;
    }
}

__device__ __forceinline__ void gload16(const void* g, void* l) {
    __builtin_amdgcn_global_load_lds(
        (const __attribute__((address_space(1))) void*)g,
        (__attribute__((address_space(3))) void*)l, 16, 0, 0);
}

__device__ inline float blockMax256(float v) {
    __shared__ float red[4];
    for (int off = 32; off; off >>= 1) v = fmaxf(v, __shfl_xor(v, off));
    int lane = threadIdx.x & 63, wid = threadIdx.x >> 6;
    if (lane == 0) red[wid] = v;
    __syncthreads();
    v = fmaxf(fmaxf(red[0], red[1]), fmaxf(red[2], red[3]));
    __syncthreads();
    return v;
}

__device__ inline float blockSum256(float v) {
    __shared__ float red[4];
    for (int off = 32; off; off >>= 1) v += __shfl_xor(v, off);
    int lane = threadIdx.x & 63, wid = threadIdx.x >> 6;
    if (lane == 0) red[wid] = v;
    __syncthreads();
    v = red[0] + red[1] + red[2] + red[3];
    __syncthreads();
    return v;
}

// ================= bf16 MFMA NT GEMM =================
// 64x128 block, 4 waves (each 32x64), BK=64, unroll-by-2 (K % 128 == 0 at every
// call site). A operand: global -> REGISTERS (ping/pong afP/afQ, no LDS traffic).
// B operand: LDS double-buffer via global_load_lds with 8-chunk XOR swizzle
// (phys chunk = logical ^ (row&7), staged via pre-swizzled GLOBAL source).
// Counted vmcnt(8) = {4 B-stage + 4 A-reg} of the NEXT half stay in flight.
// EPI: 0 bias->bf16 | 1 GCN: relu((acc+bias[n])/den)+Dadd ->bf16 | 2 relu->bf16
//      3 plain->f32 | 4 scores masked ->f32 | 5 conv relu+pad | 6 plain->bf16
//      7 dual: n<1024 -> Cb (+bias[boff+n]); n>=1024 -> Cb2 (+bias2[n-1024]), B from Bt2
template<int EPI>
__global__ __launch_bounds__(256) void mm(
    const bf16* __restrict__ A, size_t sA, int lda,
    const bf16* __restrict__ Bt, size_t sB, int ldb,
    const int* __restrict__ rowIdx, int rowMul,
    const float* __restrict__ bias,
    const bf16* __restrict__ Dadd, int ldd,
    const float* __restrict__ denv,
    const void* __restrict__ smask, const int* __restrict__ flagp,
    bf16* __restrict__ Cb, float* __restrict__ Cf, size_t sC, int ldc,
    int M, int N, int K,
    const bf16* __restrict__ Bt2, const float* __restrict__ bias2,
    bf16* __restrict__ Cb2, size_t sC2, int ldc2)
{
    __shared__ __align__(16) bf16 Bs[2][128 * 64];   // 2 x 16KB

    // bijective chunked XCD swizzle (nwg % 8 == 0 at all call sites)
    const int gx = gridDim.x, gy = gridDim.y;
    const int nwg = gx * gy * (int)gridDim.z;
    int lin = ((int)blockIdx.z * gy + (int)blockIdx.y) * gx + (int)blockIdx.x;
    int cpx = nwg >> 3;
    int swz = (lin & 7) * cpx + (lin >> 3);
    int ty = swz % gy;
    int tt = swz / gy;
    int tx = tt % gx;
    int b  = tt / gx;

    const int bm = ty * 64, bn = tx * 128;
    const int tid = threadIdx.x;
    const int lane = tid & 63, w = tid >> 6;   // 4 waves
    const int wr = w >> 1, wc = w & 1;         // wave -> (row half, col half)
    const int boff = rowIdx ? rowIdx[b] * rowMul : 0;

    const bf16* Ab = A + (size_t)b * sA;
    const bf16* Bb = Bt + (size_t)b * sB;

    // EPI7: block-uniform B source select at the 1024-column boundary
    const bf16* Bsrc = Bb;
    int bRow0 = boff + bn;
    if (EPI == 7 && bn >= 1024) { Bsrc = Bt2; bRow0 = bn - 1024; }

    // B staging (8-row panel per gload): lane l -> row_in_panel l>>3, slot chunk l&7;
    // source k-chunk = (l&7) ^ (l>>3)   (pre-swizzled global address, rule #21)
    const int sr = lane >> 3;
    const int gk = ((lane & 7) ^ (lane >> 3)) * 8;

    // B read side: lane group g8 reads logical chunk e = ks*4+g8; phys = e ^ (row&7)
    const int rl = lane & 15;
    const int g8 = lane >> 4;
    const int rx = lane & 7;

    // A fragment row pointers (direct global->reg, no swizzle)
    const bf16* a0 = Ab + (size_t)(bm + wr * 32 + rl) * lda;
    const bf16* a1 = Ab + (size_t)(bm + wr * 32 + 16 + rl) * lda;
    const int c0o = g8 * 8;          // ks=0 chunk offset (elements)
    const int c1o = (4 + g8) * 8;    // ks=1 chunk offset

    f32x4 zero = {0.f, 0.f, 0.f, 0.f};
    f32x4 acc[2][4];
    #pragma unroll
    for (int i = 0; i < 2; ++i)
        #pragma unroll
        for (int j = 0; j < 4; ++j) acc[i][j] = zero;

    #define STAGE_B(k0_, buf_)                                                          \
        _Pragma("unroll")                                                               \
        for (int q = 0; q < 4; ++q)                                                     \
            gload16((const void*)(Bsrc + (size_t)(bRow0 + w * 32 + q * 8 + sr) * ldb + (k0_) + gk), \
                    (void*)(Bs[buf_] + (w * 32 + q * 8) * 64));

    #define LOAD_A(af_, k0_)                                    \
        af_[0][0] = *(const bf16x8*)(a0 + (k0_) + c0o);         \
        af_[0][1] = *(const bf16x8*)(a0 + (k0_) + c1o);         \
        af_[1][0] = *(const bf16x8*)(a1 + (k0_) + c0o);         \
        af_[1][1] = *(const bf16x8*)(a1 + (k0_) + c1o);

    #define COMPUTE(buf_, af_)                                                              \
        {                                                                                   \
            bf16x8 bfv[4][2];                                                               \
            _Pragma("unroll")                                                               \
            for (int ks = 0; ks < 2; ++ks) {                                                \
                int e = ks * 4 + g8;                                                        \
                _Pragma("unroll")                                                           \
                for (int j = 0; j < 4; ++j)                                                 \
                    bfv[j][ks] = *(const bf16x8*)(Bs[buf_] + (wc * 64 + j * 16 + rl) * 64 + (e ^ rx) * 8); \
            }                                                                               \
            _Pragma("unroll")                                                               \
            for (int ks = 0; ks < 2; ++ks)                                                  \
                _Pragma("unroll")                                                           \
                for (int i = 0; i < 2; ++i)                                                 \
                    _Pragma("unroll")                                                       \
                    for (int j = 0; j < 4; ++j)                                             \
                        acc[i][j] = __builtin_amdgcn_mfma_f32_16x16x32_bf16(af_[i][ks], bfv[j][ks], acc[i][j], 0, 0, 0); \
        }

    bf16x8 afP[2][2], afQ[2][2];

    // prologue: B(0) -> Bs[0]; A(0) -> afP
    STAGE_B(0, 0)
    LOAD_A(afP, 0)

    for (int k0 = 0; k0 < K; k0 += 128) {
        // ---- half A: compute Bs[0]/afP; prefetch k0+64 into Bs[1]/afQ ----
        STAGE_B(k0 + 64, 1)
        LOAD_A(afQ, k0 + 64)
        asm volatile("s_waitcnt vmcnt(8)" ::: "memory");   // k0's B+A done; k0+64's 8 pending
        __builtin_amdgcn_s_barrier();
        __builtin_amdgcn_sched_barrier(0);
        COMPUTE(0, afP)
        __builtin_amdgcn_s_barrier();
        __builtin_amdgcn_sched_barrier(0);

        // ---- half B: compute Bs[1]/afQ; prefetch k0+128 into Bs[0]/afP ----
        if (k0 + 128 < K) {
            STAGE_B(k0 + 128, 0)
            LOAD_A(afP, k0 + 128)
            asm volatile("s_waitcnt vmcnt(8)" ::: "memory");
        } else {
            asm volatile("s_waitcnt vmcnt(0)" ::: "memory");
        }
        __builtin_amdgcn_s_barrier();
        __builtin_amdgcn_sched_barrier(0);
        COMPUTE(1, afQ)
        __builtin_amdgcn_s_barrier();
        __builtin_amdgcn_sched_barrier(0);
    }
    #undef STAGE_B
    #undef LOAD_A
    #undef COMPUTE

    const int r0 = (lane >> 4) * 4, c0 = lane & 15;
    int flag = 0, h0 = 0;
    if (EPI == 4) { flag = flagp[0]; h0 = rowIdx[b]; }
    #pragma unroll
    for (int i = 0; i < 2; ++i) {
        #pragma unroll
        for (int r = 0; r < 4; ++r) {
            int m = bm + wr * 32 + i * 16 + r0 + r;
            #pragma unroll
            for (int j = 0; j < 4; ++j) {
                int n = bn + wc * 64 + j * 16 + c0;
                float v = acc[i][j][r];
                size_t oidx = (size_t)b * sC + (size_t)m * ldc + n;
                if (EPI == 0) {
                    Cb[oidx] = (bf16)(v + bias[boff + n]);
                } else if (EPI == 1) {
                    v = fmaxf((v + bias[n]) / denv[(size_t)b * M + m], 0.f)
                        + (float)Dadd[((size_t)b * M + m) * ldd + n];
                    Cb[oidx] = (bf16)v;
                } else if (EPI == 2) {
                    Cb[oidx] = (bf16)fmaxf(v, 0.f);
                } else if (EPI == 3) {
                    Cf[oidx] = v;
                } else if (EPI == 4) {
                    size_t mi = (((size_t)b * H_ + h0) * N_ + m) * N_ + n;
                    Cf[oidx] = mask_at(smask, flag, mi) ? -1e9f : v * 0.04419417382415922f;
                } else if (EPI == 5) {
                    Cb[oidx] = (n < PC_) ? (bf16)fmaxf(v + bias[m], 0.f) : (bf16)0.f;
                } else if (EPI == 7) {
                    if (n < 1024)
                        Cb[(size_t)b * sC + (size_t)m * ldc + n] = (bf16)(v + bias[boff + n]);
                    else
                        Cb2[(size_t)b * sC2 + (size_t)m * ldc2 + (n - 1024)] = (bf16)(v + bias2[n - 1024]);
                } else {
                    Cb[oidx] = (bf16)v;
                }
            }
        }
    }
}

// ================= prep device functions =================

__device__ int d_detect(const unsigned int* __restrict__ sm) {
    __shared__ int sGt1, sF32, sOddNZ, sFlag;
    if (threadIdx.x == 0) { sGt1 = 0; sF32 = 0; sOddNZ = 0; }
    __syncthreads();
    int gt1 = 0, f32c = 0, oddnz = 0;
    for (int s = 0; s < 16; ++s) {
        int idx = s * 256 + threadIdx.x;
        unsigned wv = sm[idx];
        if (wv > 1u) gt1 = 1;
        if (wv == 0x3F800000u) f32c++;
        if ((idx & 1) && wv != 0u) oddnz = 1;
    }
    if (gt1)   atomicOr(&sGt1, 1);
    if (f32c)  atomicAdd(&sF32, f32c);
    if (oddnz) atomicOr(&sOddNZ, 1);
    __syncthreads();
    if (threadIdx.x == 0) {
        int f;
        if (sF32 > 512) f = 2;
        else if (!sGt1) f = sOddNZ ? 1 : 3;
        else f = 0;
        sFlag = f;
    }
    __syncthreads();
    return sFlag;
}

__device__ void d_trcvt(const float* __restrict__ src, bf16* __restrict__ dst,
                        int R, int C, int Rpad, int Cpad,
                        size_t sSrc, size_t sDst, int mode, int bx, int by, int bz) {
    __shared__ float t[32][33];
    int r0 = by * 32, c0 = bx * 32;
    int tx = threadIdx.x & 31, ty = threadIdx.x >> 5;
    const float* s = src + (size_t)bz * sSrc;
    bf16* d = dst + (size_t)bz * sDst;
    #pragma unroll
    for (int q = 0; q < 4; ++q) {
        int r = r0 + ty + q * 8, c = c0 + tx;
        t[ty + q * 8][tx] = (r < R && c < C) ? s[(size_t)r * C + c] : 0.f;
    }
    __syncthreads();
    #pragma unroll
    for (int q = 0; q < 4; ++q) {
        int dr = c0 + ty + q * 8, dc = r0 + tx;
        if (dr < Cpad && dc < Rpad) {
            int drm = dr;
            if (mode == 1) drm = (dr >> 9) * 1024 + (dr & 511);
            else if (mode == 2) drm = (dr >> 9) * 1024 + 512 + (dr & 511);
            d[(size_t)drm * Rpad + dc] = (bf16)t[tx][ty + q * 8];
        }
    }
}

// job boundaries (flat z)
#define PB_DET   1
#define PB_QKB   13
#define PB_CW2   1037
#define PB_ADJ   9229
#define PB_ROWS  17421
#define PB_INT   23565
#define PB_W0    24141
#define PB_W1    25293
#define PB_QW    27597
#define PB_KW    29901
#define PB_LC    30477
#define PB_F1    31053
#define PB_F2    31629
#define PB_CNT   31653

// mega-prep: all independent prep jobs in one dispatch
__global__ __launch_bounds__(256) void k_prep(
    const void* __restrict__ smask, int* __restrict__ flag, int* __restrict__ counts,
    const float* __restrict__ adj, bf16* __restrict__ adjb, float* __restrict__ den,
    const float* __restrict__ inputs, bf16* __restrict__ X, bf16* __restrict__ INT_,
    const float* __restrict__ convw, bf16* __restrict__ CW2,
    const float* __restrict__ qb, const float* __restrict__ kb, float* __restrict__ qkbD,
    const float* __restrict__ W0w, bf16* __restrict__ W0T,
    const float* __restrict__ W1w, bf16* __restrict__ W1T,
    const float* __restrict__ qw, const float* __restrict__ kw, bf16* __restrict__ QKWT,
    const float* __restrict__ lincw, bf16* __restrict__ LCT,
    const float* __restrict__ fc1w, bf16* __restrict__ F1T,
    const float* __restrict__ fc2w, bf16* __restrict__ F2T)
{
    const int id = blockIdx.x;
    const size_t sND = (size_t)N_ * D_;
    if (id < PB_DET) {
        int f = d_detect((const unsigned int*)smask);
        if (threadIdx.x == 0) flag[0] = f;
    } else if (id < PB_QKB) {
        int idx = (id - PB_DET) * 256 + threadIdx.x;
        if (idx < 3072) {
            int h = idx >> 10, rem = idx & 1023, s = rem >> 9, r = rem & 511;
            qkbD[idx] = (s ? kb : qb)[h * 512 + r];
        }
    } else if (id < PB_CW2) {
        int o = id - PB_QKB;
        const float* s = convw + (size_t)o * 3072;
        bf16* dp = CW2 + (size_t)o * 3072;
        for (int q = 0; q < 4; ++q) {
            int i = q * 256 + threadIdx.x;
            float v0 = s[i * 3], v1 = s[i * 3 + 1], v2 = s[i * 3 + 2];
            dp[i] = (bf16)v0; dp[1024 + i] = (bf16)v1; dp[2048 + i] = (bf16)v2;
        }
    } else if (id < PB_ADJ) {
        int t = id - PB_CW2;
        int row = t & 1023, b = t >> 10;
        size_t base = ((size_t)b * N_ + row) * N_;
        float4 v = ((const float4*)(adj + base))[threadIdx.x];
        union { bf16 b[4]; uint2 u; } o;
        o.b[0] = (bf16)v.x; o.b[1] = (bf16)v.y; o.b[2] = (bf16)v.z; o.b[3] = (bf16)v.w;
        ((uint2*)(adjb + base))[threadIdx.x] = o.u;
        float s = blockSum256(v.x + v.y + v.z + v.w);
        if (threadIdx.x == 0) den[b * N_ + row] = s + 1.0f;
    } else if (id < PB_ROWS) {
        int row = id - PB_ADJ;
        int t = threadIdx.x;
        if (t < 192) {
            float4 v = ((const float4*)(inputs + (size_t)row * D_))[t];
            union { bf16 b[4]; uint2 u; } o;
            o.b[0] = (bf16)v.x; o.b[1] = (bf16)v.y; o.b[2] = (bf16)v.z; o.b[3] = (bf16)v.w;
            *(uint2*)(X + (size_t)row * DC_ + t * 4) = o.u;
        }
    } else if (id < PB_INT) {
        int t = id - PB_ROWS;
        int bx = t % 24; int u = t / 24; int by = u % 32; int bz = u / 32;
        d_trcvt(inputs, INT_, N_, D_, N_, D_, sND, sND, 0, bx, by, bz);
    } else if (id < PB_W0) {
        int t = id - PB_INT;
        d_trcvt(W0w, W0T, D_, D_, D_, D_, 0, 0, 0, t % 24, t / 24, 0);
    } else if (id < PB_W1) {
        int t = id - PB_W0;
        d_trcvt(W1w, W1T, DC_, D_, DC_, D_, 0, 0, 0, t % 24, t / 24, 0);
    } else if (id < PB_QW) {
        int t = id - PB_W1;
        d_trcvt(qw, QKWT, DC_, DC_, DC_, DC_, 0, 0, 1, t % 48, t / 48, 0);
    } else if (id < PB_KW) {
        int t = id - PB_QW;
        d_trcvt(kw, QKWT, DC_, DC_, DC_, DC_, 0, 0, 2, t % 48, t / 48, 0);
    } else if (id < PB_LC) {
        int t = id - PB_KW;
        d_trcvt(lincw, LCT, PC_, D_, D_, D_, 0, 0, 0, t % 24, t / 24, 0);
    } else if (id < PB_F1) {
        int t = id - PB_LC;
        d_trcvt(fc1w, F1T, D_, D_, D_, D_, 0, 0, 0, t % 24, t / 24, 0);
    } else if (id < PB_F2) {
        int t = id - PB_F1;
        d_trcvt(fc2w, F2T, D_, D_, D_, D_, 0, 0, 0, t % 24, t / 24, 0);
    } else if (id < PB_CNT) {
        int bh = id - PB_F2;
        int f = d_detect((const unsigned int*)smask);   // local, same result
        float c = 0.f;
        for (int s = 0; s < 4; ++s) {
            int q = s * 256 + threadIdx.x;
            size_t mi = ((size_t)bh * N_ + q) * N_;
            if (!mask_at(smask, f, mi)) c += 1.f;
        }
        c = blockSum256(c);
        if (threadIdx.x == 0) counts[bh] = (int)(c + 0.5f);
    }
}

// ================= remaining support kernels =================

__global__ void k_select_head(const int* __restrict__ counts, int* __restrict__ hsel) {
    if (threadIdx.x != 0 || blockIdx.x != 0) return;
    float p[B_][H_];
    for (int h = 0; h < H_; ++h) {
        float mx = -1e30f;
        for (int b = 0; b < B_; ++b) mx = fmaxf(mx, (float)counts[b * H_ + h]);
        float s = 0.f;
        for (int b = 0; b < B_; ++b) { p[b][h] = expf((float)counts[b * H_ + h] - mx); s += p[b][h]; }
        for (int b = 0; b < B_; ++b) p[b][h] /= s;
    }
    for (int b = 0; b < B_; ++b) {
        int best = 0; float bv = p[b][0];
        for (int h = 1; h < H_; ++h) if (p[b][h] > bv) { bv = p[b][h]; best = h; }
        hsel[b] = best;
    }
}

__global__ __launch_bounds__(256) void k_tr_bf16(const bf16* __restrict__ src,
                                                 bf16* __restrict__ dst) {
    __shared__ bf16 t[32][34];
    int b = blockIdx.z;
    int i0 = blockIdx.y * 32, p0 = blockIdx.x * 32;
    int tx = threadIdx.x & 31, ty = threadIdx.x >> 5;
    const bf16* s = src + (size_t)b * N_ * D_;
    bf16* d = dst + (size_t)b * D_ * N_;
    #pragma unroll
    for (int q = 0; q < 4; ++q)
        t[ty + q * 8][tx] = s[(size_t)(i0 + ty + q * 8) * D_ + p0 + tx];
    __syncthreads();
    #pragma unroll
    for (int q = 0; q < 4; ++q)
        d[(size_t)(p0 + ty + q * 8) * N_ + i0 + tx] = t[tx][ty + q * 8];
}

__global__ __launch_bounds__(256) void k_softmax(float* __restrict__ Sc,
                                                 const void* __restrict__ smask,
                                                 const int* __restrict__ flagp,
                                                 const int* __restrict__ hsel,
                                                 float* __restrict__ part) {
    __shared__ float s1[256], s2[256];
    int b = blockIdx.y, row = blockIdx.x;
    int h0 = hsel[b], flag = flagp[0];
    float* rp = Sc + ((size_t)b * N_ + row) * N_;
    float v[4];
    float mx = -INFINITY;
    #pragma unroll
    for (int s = 0; s < 4; ++s) { v[s] = rp[s * 256 + threadIdx.x]; mx = fmaxf(mx, v[s]); }
    mx = blockMax256(mx);
    float sum = 0.f;
    #pragma unroll
    for (int s = 0; s < 4; ++s) { v[s] = expf(v[s] - mx); sum += v[s]; }
    sum = blockSum256(sum);
    size_t ki = (((size_t)b * H_ + h0) * N_ + row) * N_;
    float keep = mask_at(smask, flag, ki) ? 0.f : 1.f;
    float inv = keep / sum;
    float m1 = -INFINITY, m2 = -INFINITY;
    #pragma unroll
    for (int s = 0; s < 4; ++s) {
        float x = v[s] * inv;
        rp[s * 256 + threadIdx.x] = x;
        if (x > m1) { m2 = m1; m1 = x; } else m2 = fmaxf(m2, x);
    }
    int tid = threadIdx.x;
    s1[tid] = m1; s2[tid] = m2;
    __syncthreads();
    for (int off = 128; off; off >>= 1) {
        if (tid < off) {
            float a1 = s1[tid], a2 = s2[tid], b1 = s1[tid + off], b2 = s2[tid + off];
            s1[tid] = fmaxf(a1, b1);
            s2[tid] = fmaxf(fminf(a1, b1), fmaxf(a2, b2));
        }
        __syncthreads();
    }
    if (tid == 0) {
        part[((size_t)b * N_ + row) * 2]     = s1[0];
        part[((size_t)b * N_ + row) * 2 + 1] = s2[0];
    }
}

__global__ __launch_bounds__(256) void k_top2_s2(const float* __restrict__ part,
                                                 float* __restrict__ thr,
                                                 int* __restrict__ selcnt) {
    __shared__ float s1[256], s2[256];
    int b = blockIdx.x, tid = threadIdx.x;
    float m1 = -INFINITY, m2 = -INFINITY;
    for (int s = 0; s < 4; ++s) {
        int r = s * 256 + tid;
        float a1 = part[((size_t)b * N_ + r) * 2];
        float a2 = part[((size_t)b * N_ + r) * 2 + 1];
        float n1 = fmaxf(m1, a1);
        float n2 = fmaxf(fminf(m1, a1), fmaxf(m2, a2));
        m1 = n1; m2 = n2;
    }
    s1[tid] = m1; s2[tid] = m2;
    __syncthreads();
    for (int off = 128; off; off >>= 1) {
        if (tid < off) {
            float a1 = s1[tid], a2 = s2[tid], b1 = s1[tid + off], b2 = s2[tid + off];
            s1[tid] = fmaxf(a1, b1);
            s2[tid] = fmaxf(fminf(a1, b1), fmaxf(a2, b2));
        }
        __syncthreads();
    }
    if (tid == 0) { thr[b] = s2[0]; selcnt[b] = 0; }
}

// extract + diag + den2 + ax2_init fused: block (row,b) owns attn row `row`
__global__ __launch_bounds__(256) void k_extract(const float* __restrict__ attn,
                                                 const float* __restrict__ thr,
                                                 int* __restrict__ selcnt,
                                                 int* __restrict__ sel,
                                                 float* __restrict__ adiag,
                                                 float* __restrict__ den2,
                                                 const bf16* __restrict__ x,
                                                 bf16* __restrict__ ax2) {
    __shared__ float sdiag;
    int b = blockIdx.y, row = blockIdx.x;
    const float* ap = attn + (size_t)b * N_ * N_;
    float t = thr[b];
    size_t base = (size_t)row * 1024;
    for (int s = 0; s < 4; ++s) {
        int col = s * 256 + threadIdx.x;
        float v = ap[base + col];
        if (col == row) {
            adiag[b * N_ + row] = v;
            den2[b * N_ + row] = v + 1.0f;
            sdiag = v;
        }
        if (v >= t) {
            int pos = atomicAdd(&selcnt[b], 1);
            if (pos < 512) {
                sel[((size_t)b * 512 + pos) * 2]     = row;
                sel[((size_t)b * 512 + pos) * 2 + 1] = col;
            }
        }
    }
    __syncthreads();
    float a = sdiag;
    const bf16* xp = x + ((size_t)b * N_ + row) * DC_;
    bf16* op = ax2 + ((size_t)b * N_ + row) * DC_;
    #pragma unroll
    for (int s = 0; s < 6; ++s) {
        int d = s * 256 + threadIdx.x;
        op[d] = (bf16)(a * (float)xp[d]);
    }
}

__global__ __launch_bounds__(256) void k_ax2_sparse(const float* __restrict__ attn,
                                                    const bf16* __restrict__ x,
                                                    const int* __restrict__ selcnt,
                                                    const int* __restrict__ sel,
                                                    bf16* __restrict__ ax2,
                                                    float* __restrict__ den2) {
    int b = blockIdx.x;
    int cnt = selcnt[b]; if (cnt > 512) cnt = 512;
    __shared__ int si[1024];
    if (threadIdx.x == 0) {
        for (int e = 0; e < cnt; ++e) {
            si[e * 2]     = sel[((size_t)b * 512 + e) * 2];
            si[e * 2 + 1] = sel[((size_t)b * 512 + e) * 2 + 1];
        }
        for (int a = 1; a < cnt; ++a) {
            int ii = si[a * 2], jj = si[a * 2 + 1];
            long long key = (long long)ii * N_ + jj;
            int p = a - 1;
            while (p >= 0 && ((long long)si[p * 2] * N_ + si[p * 2 + 1]) > key) {
                si[(p + 1) * 2] = si[p * 2]; si[(p + 1) * 2 + 1] = si[p * 2 + 1]; --p;
            }
            si[(p + 1) * 2] = ii; si[(p + 1) * 2 + 1] = jj;
        }
    }
    __syncthreads();
    const float* ap = attn + (size_t)b * N_ * N_;
    for (int e = 0; e < cnt; ++e) {
        int i = si[e * 2], j = si[e * 2 + 1];
        if (i == j) continue;
        float aij = ap[(size_t)i * N_ + j];
        float aji = ap[(size_t)j * N_ + i];
        bf16* ri = ax2 + ((size_t)b * N_ + i) * DC_;
        bf16* rj = ax2 + ((size_t)b * N_ + j) * DC_;
        const bf16* xi = x + ((size_t)b * N_ + i) * DC_;
        const bf16* xj = x + ((size_t)b * N_ + j) * DC_;
        for (int s = 0; s < 6; ++s) {
            int d = s * 256 + threadIdx.x;
            ri[d] = (bf16)((float)ri[d] + aij * (float)xj[d]);
            rj[d] = (bf16)((float)rj[d] + aji * (float)xi[d]);
        }
        if (threadIdx.x == 0) {
            den2[b * N_ + i] += aij;
            den2[b * N_ + j] += aji;
        }
        __syncthreads();
    }
}

// ---------------- launch ----------------
extern "C" void kernel_launch(void* const* d_in, const int* in_sizes, int n_in,
                              void* d_out, int out_size, void* d_ws, size_t ws_size,
                              hipStream_t stream) {
    if (n_in < 17) return;
    if (ws_size < WS_NEED) return;

    const float* adj    = (const float*)d_in[0];
    const float* inputs = (const float*)d_in[1];
    const void*  smask  = d_in[2];
    const float* W0w = (const float*)d_in[3];
    const float* W0b = (const float*)d_in[4];
    const float* W1w = (const float*)d_in[5];
    const float* W1b = (const float*)d_in[6];
    const float* qw  = (const float*)d_in[7];
    const float* qb  = (const float*)d_in[8];
    const float* kw  = (const float*)d_in[9];
    const float* kb  = (const float*)d_in[10];
    const float* convw = (const float*)d_in[11];
    const float* convb = (const float*)d_in[12];
    const float* lincw = (const float*)d_in[13];
    const float* lincb = (const float*)d_in[14];
    const float* fc1w  = (const float*)d_in[15];
    const float* fc2w  = (const float*)d_in[16];

    char* W = (char*)d_ws;
    float* out = (float*)d_out;

    float* den    = (float*)(W + O_DEN);
    float* den2   = (float*)(W + O_DEN2);
    float* adiag  = (float*)(W + O_ADIAG);
    float* t2p    = (float*)(W + O_T2P);
    float* thr    = (float*)(W + O_THR);
    int*   counts = (int*)(W + O_CNTS);
    int*   hsel   = (int*)(W + O_HSEL);
    int*   selcnt = (int*)(W + O_SELC);
    int*   flag   = (int*)(W + O_FLAG);
    float* qkb    = (float*)(W + O_QKB);
    int*   sel    = (int*)(W + O_SEL);
    float* ATTN   = (float*)(W + O_ATTN);
    bf16* X     = (bf16*)(W + O_X);
    bf16* AX2   = (bf16*)(W + O_AX2);
    bf16* QKOUT = (bf16*)(W + O_AX2);
    bf16* ADJB  = (bf16*)(W + O_ADJB);
    bf16* INT_  = (bf16*)(W + O_INT);
    bf16* OUT0T = (bf16*)(W + O_OUT0T);
    bf16* BBA   = (bf16*)(W + O_BBA);
    bf16* BBB   = (bf16*)(W + O_BBB);
    bf16* BBC   = (bf16*)(W + O_BBC);
    bf16* W0T   = (bf16*)(W + O_W0T);
    bf16* W1T   = (bf16*)(W + O_W1T);
    bf16* QKWT  = (bf16*)(W + O_QKWT);
    bf16* CW2   = (bf16*)(W + O_CWB);
    bf16* LCT   = (bf16*)(W + O_LCT);
    bf16* F1T   = (bf16*)(W + O_F1T);
    bf16* F2T   = (bf16*)(W + O_F2T);

    const size_t sND  = (size_t)N_ * D_;
    const size_t sNDC = (size_t)N_ * DC_;
    const size_t sNN  = (size_t)N_ * N_;

    // ---- all prep in one dispatch ----
    k_prep<<<PB_CNT, 256, 0, stream>>>(smask, flag, counts,
        adj, ADJB, den, inputs, X, INT_, convw, CW2,
        qb, kb, qkb, W0w, W0T, W1w, W1T, qw, kw, QKWT,
        lincw, LCT, fc1w, F1T, fc2w, F2T);
    k_select_head<<<1, 64, 0, stream>>>(counts, hsel);

    // ---- GCN layer 0 ----
    mm<0><<<dim3(6, 16, B_), 256, 0, stream>>>(X, sNDC, DC_, W0T, 0, D_, nullptr, 0,
        W0b, nullptr, 0, nullptr, nullptr, nullptr, BBA, nullptr, sND, D_, N_, D_, D_,
        nullptr, nullptr, nullptr, 0, 0);
    mm<6><<<dim3(6, 16, B_), 256, 0, stream>>>(ADJB, sNN, N_, INT_, sND, N_, nullptr, 0,
        nullptr, nullptr, 0, nullptr, nullptr, nullptr, BBB, nullptr, sND, D_, N_, D_, N_,
        nullptr, nullptr, nullptr, 0, 0);
    mm<1><<<dim3(6, 16, B_), 256, 0, stream>>>(BBB, sND, D_, W0T, 0, D_, nullptr, 0,
        W0b, BBA, D_, den, nullptr, nullptr, BBC, nullptr, sND, D_, N_, D_, D_,
        nullptr, nullptr, nullptr, 0, 0);
    k_tr_bf16<<<dim3(24, 32, B_), 256, 0, stream>>>(BBC, OUT0T);
    mm<5><<<dim3(6, 16, B_), 256, 0, stream>>>(CW2, 0, 3072, OUT0T, sND, N_, nullptr, 0,
        convb, nullptr, 0, nullptr, nullptr, nullptr, BBB, nullptr, sND, D_, N_, D_, 3072,
        nullptr, nullptr, nullptr, 0, 0);
    mm<0><<<dim3(6, 16, B_), 256, 0, stream>>>(BBB, sND, D_, LCT, 0, D_, nullptr, 0,
        lincb, nullptr, 0, nullptr, nullptr, nullptr, X + D_, nullptr, sNDC, DC_, N_, D_, D_,
        nullptr, nullptr, nullptr, 0, 0);

    // ---- merged Q|K projection + xW1 (EPI 7): N = 1024 + 768 = 1792 ----
    mm<7><<<dim3(14, 16, B_), 256, 0, stream>>>(X, sNDC, DC_, QKWT, 0, DC_, hsel, 1024,
        qkb, nullptr, 0, nullptr, nullptr, nullptr, QKOUT, nullptr, sNN, N_, N_, 1792, DC_,
        W1T, W1b, BBA, sND, D_);

    // ---- scores (fp32, masked) ----
    mm<4><<<dim3(8, 16, B_), 256, 0, stream>>>(QKOUT, sNN, N_, QKOUT + 512, sNN, N_, hsel, 0,
        nullptr, nullptr, 0, nullptr, smask, flag, nullptr, ATTN, sNN, N_, N_, N_, DK_,
        nullptr, nullptr, nullptr, 0, 0);
    k_softmax<<<dim3(N_, B_), 256, 0, stream>>>(ATTN, smask, flag, hsel, t2p);

    // ---- top-2 select + sparse adj2 ----
    k_top2_s2<<<B_, 256, 0, stream>>>(t2p, thr, selcnt);
    k_extract<<<dim3(N_, B_), 256, 0, stream>>>(ATTN, thr, selcnt, sel, adiag, den2, X, AX2);
    k_ax2_sparse<<<B_, 256, 0, stream>>>(ATTN, X, selcnt, sel, AX2, den2);

    // ---- GCN layer 1 (xW1 already in BBA from merged GEMM) ----
    mm<1><<<dim3(6, 16, B_), 256, 0, stream>>>(AX2, sNDC, DC_, W1T, 0, DC_, nullptr, 0,
        W1b, BBA, D_, den2, nullptr, nullptr, BBB, nullptr, sND, D_, N_, D_, DC_,
        nullptr, nullptr, nullptr, 0, 0);

    // ---- fc ----
    mm<2><<<dim3(6, 16, B_), 256, 0, stream>>>(BBB, sND, D_, F1T, 0, D_, nullptr, 0,
        nullptr, nullptr, 0, nullptr, nullptr, nullptr, BBC, nullptr, sND, D_, N_, D_, D_,
        nullptr, nullptr, nullptr, 0, 0);
    mm<3><<<dim3(6, 16, B_), 256, 0, stream>>>(BBC, sND, D_, F2T, 0, D_, nullptr, 0,
        nullptr, nullptr, 0, nullptr, nullptr, nullptr, nullptr, out, sND, D_, N_, D_, D_,
        nullptr, nullptr, nullptr, 0, 0);
}

// Round 12
// 406.215 us; speedup vs baseline: 1.4094x; 1.4094x over previous
//
#include <hip/hip_runtime.h>
#include <cstdint>
#include <cstddef>

typedef __bf16 bf16;
typedef __bf16 bf16x8 __attribute__((ext_vector_type(8)));
typedef float f32x4 __attribute__((ext_vector_type(4)));

#define B_ 8
#define N_ 1024
#define D_ 768
#define H_ 3
#define DC_ 1536
#define DK_ 512
#define PC_ 766
#define MB_ (1024ull*1024ull)

// ---------------- workspace layout (byte offsets) ----------------
static const size_t O_DEN   = 0;
static const size_t O_DEN2  = 32768;
static const size_t O_ADIAG = 65536;
static const size_t O_T2P   = 98304;
static const size_t O_THR   = 163840;
static const size_t O_CNTS  = 164096;
static const size_t O_HSEL  = 164352;
static const size_t O_SELC  = 164608;
static const size_t O_FLAG  = 164864;
static const size_t O_QKB   = 165120;
static const size_t O_SEL   = 180224;
static const size_t O_ATTN  = 262144;            // f32 [8,1024,1024] 32MB
static const size_t O_X     = O_ATTN + 32*MB_;   // bf16 [8,1024,1536] 24MB
static const size_t O_AX2   = O_X    + 24*MB_;   // bf16 [8,1024,1536] 24MB (QK out overlays early)
static const size_t O_ADJB  = O_AX2  + 24*MB_;   // bf16 [8,1024,1024] 16MB
static const size_t O_INT   = O_ADJB + 16*MB_;   // bf16 [8,768,1024] inputs^T -> OUT0T (12MB)
static const size_t O_BBA   = O_INT  + 12*MB_;
static const size_t O_BBB   = O_BBA  + 12*MB_;
static const size_t O_BBC   = O_BBB  + 12*MB_;
static const size_t O_W0T   = O_BBC  + 12*MB_;   // [768][768]
static const size_t O_W1T   = O_W0T + 1179648;   // [768][1536]
static const size_t O_QKWT  = O_W1T + 2359296;   // [3072][1536]
static const size_t O_CWB   = O_QKWT + 9437184;  // CW2 [1024][3072]
static const size_t O_LCT   = O_CWB + 6291456;
static const size_t O_F1T   = O_LCT + 1179648;
static const size_t O_F2T   = O_F1T + 1179648;
static const size_t WS_NEED = O_F2T + 1179648;
static const size_t O_OUT0T = O_INT;

// ---------------- helpers ----------------
__device__ __forceinline__ bool mask_at(const void* p, int flag, size_t i) {
    switch (flag) {
        case 1:  return ((const int*)p)[i] != 0;
        case 2:  return ((const float*)p)[i] != 0.0f;
        case 3:  return ((const long long*)p)[i] != 0;
        default: return ((const unsigned char*)p)[i] != 0;
    }
}

__device__ __forceinline__ void gload16(const void* g, void* l) {
    __builtin_amdgcn_global_load_lds(
        (const __attribute__((address_space(1))) void*)g,
        (__attribute__((address_space(3))) void*)l, 16, 0, 0);
}

__device__ inline float blockMax256(float v) {
    __shared__ float red[4];
    for (int off = 32; off; off >>= 1) v = fmaxf(v, __shfl_xor(v, off));
    int lane = threadIdx.x & 63, wid = threadIdx.x >> 6;
    if (lane == 0) red[wid] = v;
    __syncthreads();
    v = fmaxf(fmaxf(red[0], red[1]), fmaxf(red[2], red[3]));
    __syncthreads();
    return v;
}

__device__ inline float blockSum256(float v) {
    __shared__ float red[4];
    for (int off = 32; off; off >>= 1) v += __shfl_xor(v, off);
    int lane = threadIdx.x & 63, wid = threadIdx.x >> 6;
    if (lane == 0) red[wid] = v;
    __syncthreads();
    v = red[0] + red[1] + red[2] + red[3];
    __syncthreads();
    return v;
}

// ================= bf16 MFMA NT GEMM =================
// R10 geometry (best: 408 us): 64x128 block, 4 waves (each 32x64), BK=64,
// 2-phase dbuf, counted vmcnt(6), raw s_barrier pairs, conflict-free 8-chunk
// XOR swizzle (phys chunk = logical ^ (row&7); staged via pre-swizzled GLOBAL
// source, gload_lds dest linear — rule #21).
// EPI: 0 bias->bf16 | 1 GCN: relu((acc+bias[n])/den)+Dadd ->bf16 | 2 relu->bf16
//      3 plain->f32 | 4 scores masked ->f32 | 5 conv relu+pad | 6 plain->bf16
//      7 dual: n<1024 -> Cb (+bias[boff+n]); n>=1024 -> Cb2 (+bias2[n-1024]), B from Bt2
template<int EPI>
__global__ __launch_bounds__(256) void mm(
    const bf16* __restrict__ A, size_t sA, int lda,
    const bf16* __restrict__ Bt, size_t sB, int ldb,
    const int* __restrict__ rowIdx, int rowMul,
    const float* __restrict__ bias,
    const bf16* __restrict__ Dadd, int ldd,
    const float* __restrict__ denv,
    const void* __restrict__ smask, const int* __restrict__ flagp,
    bf16* __restrict__ Cb, float* __restrict__ Cf, size_t sC, int ldc,
    int M, int N, int K,
    const bf16* __restrict__ Bt2, const float* __restrict__ bias2,
    bf16* __restrict__ Cb2, size_t sC2, int ldc2)
{
    __shared__ __align__(16) bf16 As[2][64 * 64];    // 16KB
    __shared__ __align__(16) bf16 Bs[2][128 * 64];   // 32KB

    // bijective chunked XCD swizzle (nwg % 8 == 0 at all call sites)
    const int gx = gridDim.x, gy = gridDim.y;
    const int nwg = gx * gy * (int)gridDim.z;
    int lin = ((int)blockIdx.z * gy + (int)blockIdx.y) * gx + (int)blockIdx.x;
    int cpx = nwg >> 3;
    int swz = (lin & 7) * cpx + (lin >> 3);
    int ty = swz % gy;
    int tt = swz / gy;
    int tx = tt % gx;
    int b  = tt / gx;

    const int bm = ty * 64, bn = tx * 128;
    const int tid = threadIdx.x;
    const int lane = tid & 63, w = tid >> 6;   // 4 waves
    const int wr = w >> 1, wc = w & 1;         // wave -> (row half, col half)
    const int boff = rowIdx ? rowIdx[b] * rowMul : 0;

    const bf16* Ab = A + (size_t)b * sA;
    const bf16* Bb = Bt + (size_t)b * sB;

    // EPI7: block-uniform B source select at the 1024-column boundary
    const bf16* Bsrc = Bb;
    int bRow0 = boff + bn;
    if (EPI == 7 && bn >= 1024) { Bsrc = Bt2; bRow0 = bn - 1024; }

    // staging (8-row panel per gload): lane l -> row_in_panel l>>3, slot chunk l&7;
    // source k-chunk = (l&7) ^ (l>>3)   (pre-swizzled global address, rule #21)
    const int sr = lane >> 3;
    const int gk = ((lane & 7) ^ (lane >> 3)) * 8;

    f32x4 zero = {0.f, 0.f, 0.f, 0.f};
    f32x4 acc[2][4];
    #pragma unroll
    for (int i = 0; i < 2; ++i)
        #pragma unroll
        for (int j = 0; j < 4; ++j) acc[i][j] = zero;

    // prologue: stage k0=0 into buffer 0 (6 loads/wave: A x2 panels, B x4 panels)
    #pragma unroll
    for (int q = 0; q < 2; ++q)
        gload16((const void*)(Ab + (size_t)(bm + w * 16 + q * 8 + sr) * lda + gk),
                (void*)(As[0] + (w * 16 + q * 8) * 64));
    #pragma unroll
    for (int q = 0; q < 4; ++q)
        gload16((const void*)(Bsrc + (size_t)(bRow0 + w * 32 + q * 8 + sr) * ldb + gk),
                (void*)(Bs[0] + (w * 32 + q * 8) * 64));

    // read side: lane group g8 = lane>>4 reads logical chunk e = ks*4+g8;
    // phys chunk = e ^ (row&7)
    const int rl = lane & 15;
    const int g8 = lane >> 4;
    const int rx = lane & 7;

    int cur = 0;
    for (int k0 = 0; k0 < K; k0 += 64) {
        int nxt = cur ^ 1;
        if (k0 + 64 < K) {
            #pragma unroll
            for (int q = 0; q < 2; ++q)
                gload16((const void*)(Ab + (size_t)(bm + w * 16 + q * 8 + sr) * lda + k0 + 64 + gk),
                        (void*)(As[nxt] + (w * 16 + q * 8) * 64));
            #pragma unroll
            for (int q = 0; q < 4; ++q)
                gload16((const void*)(Bsrc + (size_t)(bRow0 + w * 32 + q * 8 + sr) * ldb + k0 + 64 + gk),
                        (void*)(Bs[nxt] + (w * 32 + q * 8) * 64));
            asm volatile("s_waitcnt vmcnt(6)" ::: "memory");   // cur's 6 done; nxt's 6 pending
        } else {
            asm volatile("s_waitcnt vmcnt(0)" ::: "memory");
        }
        __builtin_amdgcn_s_barrier();
        __builtin_amdgcn_sched_barrier(0);

        bf16x8 af[2][2], bfv[4][2];
        #pragma unroll
        for (int ks = 0; ks < 2; ++ks) {
            int e = ks * 4 + g8;
            #pragma unroll
            for (int i = 0; i < 2; ++i)
                af[i][ks] = *(const bf16x8*)(As[cur] + (wr * 32 + i * 16 + rl) * 64 + (e ^ rx) * 8);
            #pragma unroll
            for (int j = 0; j < 4; ++j)
                bfv[j][ks] = *(const bf16x8*)(Bs[cur] + (wc * 64 + j * 16 + rl) * 64 + (e ^ rx) * 8);
        }
        #pragma unroll
        for (int ks = 0; ks < 2; ++ks)
            #pragma unroll
            for (int i = 0; i < 2; ++i)
                #pragma unroll
                for (int j = 0; j < 4; ++j)
                    acc[i][j] = __builtin_amdgcn_mfma_f32_16x16x32_bf16(af[i][ks], bfv[j][ks], acc[i][j], 0, 0, 0);

        __builtin_amdgcn_s_barrier();
        __builtin_amdgcn_sched_barrier(0);
        cur = nxt;
    }

    const int r0 = (lane >> 4) * 4, c0 = lane & 15;
    int flag = 0, h0 = 0;
    if (EPI == 4) { flag = flagp[0]; h0 = rowIdx[b]; }
    #pragma unroll
    for (int i = 0; i < 2; ++i) {
        #pragma unroll
        for (int r = 0; r < 4; ++r) {
            int m = bm + wr * 32 + i * 16 + r0 + r;
            #pragma unroll
            for (int j = 0; j < 4; ++j) {
                int n = bn + wc * 64 + j * 16 + c0;
                float v = acc[i][j][r];
                size_t oidx = (size_t)b * sC + (size_t)m * ldc + n;
                if (EPI == 0) {
                    Cb[oidx] = (bf16)(v + bias[boff + n]);
                } else if (EPI == 1) {
                    v = fmaxf((v + bias[n]) / denv[(size_t)b * M + m], 0.f)
                        + (float)Dadd[((size_t)b * M + m) * ldd + n];
                    Cb[oidx] = (bf16)v;
                } else if (EPI == 2) {
                    Cb[oidx] = (bf16)fmaxf(v, 0.f);
                } else if (EPI == 3) {
                    Cf[oidx] = v;
                } else if (EPI == 4) {
                    size_t mi = (((size_t)b * H_ + h0) * N_ + m) * N_ + n;
                    Cf[oidx] = mask_at(smask, flag, mi) ? -1e9f : v * 0.04419417382415922f;
                } else if (EPI == 5) {
                    Cb[oidx] = (n < PC_) ? (bf16)fmaxf(v + bias[m], 0.f) : (bf16)0.f;
                } else if (EPI == 7) {
                    if (n < 1024)
                        Cb[(size_t)b * sC + (size_t)m * ldc + n] = (bf16)(v + bias[boff + n]);
                    else
                        Cb2[(size_t)b * sC2 + (size_t)m * ldc2 + (n - 1024)] = (bf16)(v + bias2[n - 1024]);
                } else {
                    Cb[oidx] = (bf16)v;
                }
            }
        }
    }
}

// ================= prep device functions =================

__device__ int d_detect(const unsigned int* __restrict__ sm) {
    __shared__ int sGt1, sF32, sOddNZ, sFlag;
    if (threadIdx.x == 0) { sGt1 = 0; sF32 = 0; sOddNZ = 0; }
    __syncthreads();
    int gt1 = 0, f32c = 0, oddnz = 0;
    for (int s = 0; s < 16; ++s) {
        int idx = s * 256 + threadIdx.x;
        unsigned wv = sm[idx];
        if (wv > 1u) gt1 = 1;
        if (wv == 0x3F800000u) f32c++;
        if ((idx & 1) && wv != 0u) oddnz = 1;
    }
    if (gt1)   atomicOr(&sGt1, 1);
    if (f32c)  atomicAdd(&sF32, f32c);
    if (oddnz) atomicOr(&sOddNZ, 1);
    __syncthreads();
    if (threadIdx.x == 0) {
        int f;
        if (sF32 > 512) f = 2;
        else if (!sGt1) f = sOddNZ ? 1 : 3;
        else f = 0;
        sFlag = f;
    }
    __syncthreads();
    return sFlag;
}

__device__ void d_trcvt(const float* __restrict__ src, bf16* __restrict__ dst,
                        int R, int C, int Rpad, int Cpad,
                        size_t sSrc, size_t sDst, int mode, int bx, int by, int bz) {
    __shared__ float t[32][33];
    int r0 = by * 32, c0 = bx * 32;
    int tx = threadIdx.x & 31, ty = threadIdx.x >> 5;
    const float* s = src + (size_t)bz * sSrc;
    bf16* d = dst + (size_t)bz * sDst;
    #pragma unroll
    for (int q = 0; q < 4; ++q) {
        int r = r0 + ty + q * 8, c = c0 + tx;
        t[ty + q * 8][tx] = (r < R && c < C) ? s[(size_t)r * C + c] : 0.f;
    }
    __syncthreads();
    #pragma unroll
    for (int q = 0; q < 4; ++q) {
        int dr = c0 + ty + q * 8, dc = r0 + tx;
        if (dr < Cpad && dc < Rpad) {
            int drm = dr;
            if (mode == 1) drm = (dr >> 9) * 1024 + (dr & 511);
            else if (mode == 2) drm = (dr >> 9) * 1024 + 512 + (dr & 511);
            d[(size_t)drm * Rpad + dc] = (bf16)t[tx][ty + q * 8];
        }
    }
}

// job boundaries (flat z)
#define PB_DET   1
#define PB_QKB   13
#define PB_CW2   1037
#define PB_ADJ   9229
#define PB_ROWS  17421
#define PB_INT   23565
#define PB_W0    24141
#define PB_W1    25293
#define PB_QW    27597
#define PB_KW    29901
#define PB_LC    30477
#define PB_F1    31053
#define PB_F2    31629
#define PB_CNT   31653

// mega-prep: all independent prep jobs in one dispatch
__global__ __launch_bounds__(256) void k_prep(
    const void* __restrict__ smask, int* __restrict__ flag, int* __restrict__ counts,
    const float* __restrict__ adj, bf16* __restrict__ adjb, float* __restrict__ den,
    const float* __restrict__ inputs, bf16* __restrict__ X, bf16* __restrict__ INT_,
    const float* __restrict__ convw, bf16* __restrict__ CW2,
    const float* __restrict__ qb, const float* __restrict__ kb, float* __restrict__ qkbD,
    const float* __restrict__ W0w, bf16* __restrict__ W0T,
    const float* __restrict__ W1w, bf16* __restrict__ W1T,
    const float* __restrict__ qw, const float* __restrict__ kw, bf16* __restrict__ QKWT,
    const float* __restrict__ lincw, bf16* __restrict__ LCT,
    const float* __restrict__ fc1w, bf16* __restrict__ F1T,
    const float* __restrict__ fc2w, bf16* __restrict__ F2T)
{
    const int id = blockIdx.x;
    const size_t sND = (size_t)N_ * D_;
    if (id < PB_DET) {
        int f = d_detect((const unsigned int*)smask);
        if (threadIdx.x == 0) flag[0] = f;
    } else if (id < PB_QKB) {
        int idx = (id - PB_DET) * 256 + threadIdx.x;
        if (idx < 3072) {
            int h = idx >> 10, rem = idx & 1023, s = rem >> 9, r = rem & 511;
            qkbD[idx] = (s ? kb : qb)[h * 512 + r];
        }
    } else if (id < PB_CW2) {
        int o = id - PB_QKB;
        const float* s = convw + (size_t)o * 3072;
        bf16* dp = CW2 + (size_t)o * 3072;
        for (int q = 0; q < 4; ++q) {
            int i = q * 256 + threadIdx.x;
            float v0 = s[i * 3], v1 = s[i * 3 + 1], v2 = s[i * 3 + 2];
            dp[i] = (bf16)v0; dp[1024 + i] = (bf16)v1; dp[2048 + i] = (bf16)v2;
        }
    } else if (id < PB_ADJ) {
        int t = id - PB_CW2;
        int row = t & 1023, b = t >> 10;
        size_t base = ((size_t)b * N_ + row) * N_;
        float4 v = ((const float4*)(adj + base))[threadIdx.x];
        union { bf16 b[4]; uint2 u; } o;
        o.b[0] = (bf16)v.x; o.b[1] = (bf16)v.y; o.b[2] = (bf16)v.z; o.b[3] = (bf16)v.w;
        ((uint2*)(adjb + base))[threadIdx.x] = o.u;
        float s = blockSum256(v.x + v.y + v.z + v.w);
        if (threadIdx.x == 0) den[b * N_ + row] = s + 1.0f;
    } else if (id < PB_ROWS) {
        int row = id - PB_ADJ;
        int t = threadIdx.x;
        if (t < 192) {
            float4 v = ((const float4*)(inputs + (size_t)row * D_))[t];
            union { bf16 b[4]; uint2 u; } o;
            o.b[0] = (bf16)v.x; o.b[1] = (bf16)v.y; o.b[2] = (bf16)v.z; o.b[3] = (bf16)v.w;
            *(uint2*)(X + (size_t)row * DC_ + t * 4) = o.u;
        }
    } else if (id < PB_INT) {
        int t = id - PB_ROWS;
        int bx = t % 24; int u = t / 24; int by = u % 32; int bz = u / 32;
        d_trcvt(inputs, INT_, N_, D_, N_, D_, sND, sND, 0, bx, by, bz);
    } else if (id < PB_W0) {
        int t = id - PB_INT;
        d_trcvt(W0w, W0T, D_, D_, D_, D_, 0, 0, 0, t % 24, t / 24, 0);
    } else if (id < PB_W1) {
        int t = id - PB_W0;
        d_trcvt(W1w, W1T, DC_, D_, DC_, D_, 0, 0, 0, t % 24, t / 24, 0);
    } else if (id < PB_QW) {
        int t = id - PB_W1;
        d_trcvt(qw, QKWT, DC_, DC_, DC_, DC_, 0, 0, 1, t % 48, t / 48, 0);
    } else if (id < PB_KW) {
        int t = id - PB_QW;
        d_trcvt(kw, QKWT, DC_, DC_, DC_, DC_, 0, 0, 2, t % 48, t / 48, 0);
    } else if (id < PB_LC) {
        int t = id - PB_KW;
        d_trcvt(lincw, LCT, PC_, D_, D_, D_, 0, 0, 0, t % 24, t / 24, 0);
    } else if (id < PB_F1) {
        int t = id - PB_LC;
        d_trcvt(fc1w, F1T, D_, D_, D_, D_, 0, 0, 0, t % 24, t / 24, 0);
    } else if (id < PB_F2) {
        int t = id - PB_F1;
        d_trcvt(fc2w, F2T, D_, D_, D_, D_, 0, 0, 0, t % 24, t / 24, 0);
    } else if (id < PB_CNT) {
        int bh = id - PB_F2;
        int f = d_detect((const unsigned int*)smask);   // local, same result
        float c = 0.f;
        for (int s = 0; s < 4; ++s) {
            int q = s * 256 + threadIdx.x;
            size_t mi = ((size_t)bh * N_ + q) * N_;
            if (!mask_at(smask, f, mi)) c += 1.f;
        }
        c = blockSum256(c);
        if (threadIdx.x == 0) counts[bh] = (int)(c + 0.5f);
    }
}

// ================= remaining support kernels =================

__global__ void k_select_head(const int* __restrict__ counts, int* __restrict__ hsel) {
    if (threadIdx.x != 0 || blockIdx.x != 0) return;
    float p[B_][H_];
    for (int h = 0; h < H_; ++h) {
        float mx = -1e30f;
        for (int b = 0; b < B_; ++b) mx = fmaxf(mx, (float)counts[b * H_ + h]);
        float s = 0.f;
        for (int b = 0; b < B_; ++b) { p[b][h] = expf((float)counts[b * H_ + h] - mx); s += p[b][h]; }
        for (int b = 0; b < B_; ++b) p[b][h] /= s;
    }
    for (int b = 0; b < B_; ++b) {
        int best = 0; float bv = p[b][0];
        for (int h = 1; h < H_; ++h) if (p[b][h] > bv) { bv = p[b][h]; best = h; }
        hsel[b] = best;
    }
}

__global__ __launch_bounds__(256) void k_tr_bf16(const bf16* __restrict__ src,
                                                 bf16* __restrict__ dst) {
    __shared__ bf16 t[32][34];
    int b = blockIdx.z;
    int i0 = blockIdx.y * 32, p0 = blockIdx.x * 32;
    int tx = threadIdx.x & 31, ty = threadIdx.x >> 5;
    const bf16* s = src + (size_t)b * N_ * D_;
    bf16* d = dst + (size_t)b * D_ * N_;
    #pragma unroll
    for (int q = 0; q < 4; ++q)
        t[ty + q * 8][tx] = s[(size_t)(i0 + ty + q * 8) * D_ + p0 + tx];
    __syncthreads();
    #pragma unroll
    for (int q = 0; q < 4; ++q)
        d[(size_t)(p0 + ty + q * 8) * N_ + i0 + tx] = t[tx][ty + q * 8];
}

__global__ __launch_bounds__(256) void k_softmax(float* __restrict__ Sc,
                                                 const void* __restrict__ smask,
                                                 const int* __restrict__ flagp,
                                                 const int* __restrict__ hsel,
                                                 float* __restrict__ part) {
    __shared__ float s1[256], s2[256];
    int b = blockIdx.y, row = blockIdx.x;
    int h0 = hsel[b], flag = flagp[0];
    float* rp = Sc + ((size_t)b * N_ + row) * N_;
    float v[4];
    float mx = -INFINITY;
    #pragma unroll
    for (int s = 0; s < 4; ++s) { v[s] = rp[s * 256 + threadIdx.x]; mx = fmaxf(mx, v[s]); }
    mx = blockMax256(mx);
    float sum = 0.f;
    #pragma unroll
    for (int s = 0; s < 4; ++s) { v[s] = expf(v[s] - mx); sum += v[s]; }
    sum = blockSum256(sum);
    size_t ki = (((size_t)b * H_ + h0) * N_ + row) * N_;
    float keep = mask_at(smask, flag, ki) ? 0.f : 1.f;
    float inv = keep / sum;
    float m1 = -INFINITY, m2 = -INFINITY;
    #pragma unroll
    for (int s = 0; s < 4; ++s) {
        float x = v[s] * inv;
        rp[s * 256 + threadIdx.x] = x;
        if (x > m1) { m2 = m1; m1 = x; } else m2 = fmaxf(m2, x);
    }
    int tid = threadIdx.x;
    s1[tid] = m1; s2[tid] = m2;
    __syncthreads();
    for (int off = 128; off; off >>= 1) {
        if (tid < off) {
            float a1 = s1[tid], a2 = s2[tid], b1 = s1[tid + off], b2 = s2[tid + off];
            s1[tid] = fmaxf(a1, b1);
            s2[tid] = fmaxf(fminf(a1, b1), fmaxf(a2, b2));
        }
        __syncthreads();
    }
    if (tid == 0) {
        part[((size_t)b * N_ + row) * 2]     = s1[0];
        part[((size_t)b * N_ + row) * 2 + 1] = s2[0];
    }
}

__global__ __launch_bounds__(256) void k_top2_s2(const float* __restrict__ part,
                                                 float* __restrict__ thr,
                                                 int* __restrict__ selcnt) {
    __shared__ float s1[256], s2[256];
    int b = blockIdx.x, tid = threadIdx.x;
    float m1 = -INFINITY, m2 = -INFINITY;
    for (int s = 0; s < 4; ++s) {
        int r = s * 256 + tid;
        float a1 = part[((size_t)b * N_ + r) * 2];
        float a2 = part[((size_t)b * N_ + r) * 2 + 1];
        float n1 = fmaxf(m1, a1);
        float n2 = fmaxf(fminf(m1, a1), fmaxf(m2, a2));
        m1 = n1; m2 = n2;
    }
    s1[tid] = m1; s2[tid] = m2;
    __syncthreads();
    for (int off = 128; off; off >>= 1) {
        if (tid < off) {
            float a1 = s1[tid], a2 = s2[tid], b1 = s1[tid + off], b2 = s2[tid + off];
            s1[tid] = fmaxf(a1, b1);
            s2[tid] = fmaxf(fminf(a1, b1), fmaxf(a2, b2));
        }
        __syncthreads();
    }
    if (tid == 0) { thr[b] = s2[0]; selcnt[b] = 0; }
}

// extract + diag + den2 + ax2_init fused: block (row,b) owns attn row `row`
__global__ __launch_bounds__(256) void k_extract(const float* __restrict__ attn,
                                                 const float* __restrict__ thr,
                                                 int* __restrict__ selcnt,
                                                 int* __restrict__ sel,
                                                 float* __restrict__ adiag,
                                                 float* __restrict__ den2,
                                                 const bf16* __restrict__ x,
                                                 bf16* __restrict__ ax2) {
    __shared__ float sdiag;
    int b = blockIdx.y, row = blockIdx.x;
    const float* ap = attn + (size_t)b * N_ * N_;
    float t = thr[b];
    size_t base = (size_t)row * 1024;
    for (int s = 0; s < 4; ++s) {
        int col = s * 256 + threadIdx.x;
        float v = ap[base + col];
        if (col == row) {
            adiag[b * N_ + row] = v;
            den2[b * N_ + row] = v + 1.0f;
            sdiag = v;
        }
        if (v >= t) {
            int pos = atomicAdd(&selcnt[b], 1);
            if (pos < 512) {
                sel[((size_t)b * 512 + pos) * 2]     = row;
                sel[((size_t)b * 512 + pos) * 2 + 1] = col;
            }
        }
    }
    __syncthreads();
    float a = sdiag;
    const bf16* xp = x + ((size_t)b * N_ + row) * DC_;
    bf16* op = ax2 + ((size_t)b * N_ + row) * DC_;
    #pragma unroll
    for (int s = 0; s < 6; ++s) {
        int d = s * 256 + threadIdx.x;
        op[d] = (bf16)(a * (float)xp[d]);
    }
}

__global__ __launch_bounds__(256) void k_ax2_sparse(const float* __restrict__ attn,
                                                    const bf16* __restrict__ x,
                                                    const int* __restrict__ selcnt,
                                                    const int* __restrict__ sel,
                                                    bf16* __restrict__ ax2,
                                                    float* __restrict__ den2) {
    int b = blockIdx.x;
    int cnt = selcnt[b]; if (cnt > 512) cnt = 512;
    __shared__ int si[1024];
    if (threadIdx.x == 0) {
        for (int e = 0; e < cnt; ++e) {
            si[e * 2]     = sel[((size_t)b * 512 + e) * 2];
            si[e * 2 + 1] = sel[((size_t)b * 512 + e) * 2 + 1];
        }
        for (int a = 1; a < cnt; ++a) {
            int ii = si[a * 2], jj = si[a * 2 + 1];
            long long key = (long long)ii * N_ + jj;
            int p = a - 1;
            while (p >= 0 && ((long long)si[p * 2] * N_ + si[p * 2 + 1]) > key) {
                si[(p + 1) * 2] = si[p * 2]; si[(p + 1) * 2 + 1] = si[p * 2 + 1]; --p;
            }
            si[(p + 1) * 2] = ii; si[(p + 1) * 2 + 1] = jj;
        }
    }
    __syncthreads();
    const float* ap = attn + (size_t)b * N_ * N_;
    for (int e = 0; e < cnt; ++e) {
        int i = si[e * 2], j = si[e * 2 + 1];
        if (i == j) continue;
        float aij = ap[(size_t)i * N_ + j];
        float aji = ap[(size_t)j * N_ + i];
        bf16* ri = ax2 + ((size_t)b * N_ + i) * DC_;
        bf16* rj = ax2 + ((size_t)b * N_ + j) * DC_;
        const bf16* xi = x + ((size_t)b * N_ + i) * DC_;
        const bf16* xj = x + ((size_t)b * N_ + j) * DC_;
        for (int s = 0; s < 6; ++s) {
            int d = s * 256 + threadIdx.x;
            ri[d] = (bf16)((float)ri[d] + aij * (float)xj[d]);
            rj[d] = (bf16)((float)rj[d] + aji * (float)xi[d]);
        }
        if (threadIdx.x == 0) {
            den2[b * N_ + i] += aij;
            den2[b * N_ + j] += aji;
        }
        __syncthreads();
    }
}

// ---------------- launch ----------------
extern "C" void kernel_launch(void* const* d_in, const int* in_sizes, int n_in,
                              void* d_out, int out_size, void* d_ws, size_t ws_size,
                              hipStream_t stream) {
    if (n_in < 17) return;
    if (ws_size < WS_NEED) return;

    const float* adj    = (const float*)d_in[0];
    const float* inputs = (const float*)d_in[1];
    const void*  smask  = d_in[2];
    const float* W0w = (const float*)d_in[3];
    const float* W0b = (const float*)d_in[4];
    const float* W1w = (const float*)d_in[5];
    const float* W1b = (const float*)d_in[6];
    const float* qw  = (const float*)d_in[7];
    const float* qb  = (const float*)d_in[8];
    const float* kw  = (const float*)d_in[9];
    const float* kb  = (const float*)d_in[10];
    const float* convw = (const float*)d_in[11];
    const float* convb = (const float*)d_in[12];
    const float* lincw = (const float*)d_in[13];
    const float* lincb = (const float*)d_in[14];
    const float* fc1w  = (const float*)d_in[15];
    const float* fc2w  = (const float*)d_in[16];

    char* W = (char*)d_ws;
    float* out = (float*)d_out;

    float* den    = (float*)(W + O_DEN);
    float* den2   = (float*)(W + O_DEN2);
    float* adiag  = (float*)(W + O_ADIAG);
    float* t2p    = (float*)(W + O_T2P);
    float* thr    = (float*)(W + O_THR);
    int*   counts = (int*)(W + O_CNTS);
    int*   hsel   = (int*)(W + O_HSEL);
    int*   selcnt = (int*)(W + O_SELC);
    int*   flag   = (int*)(W + O_FLAG);
    float* qkb    = (float*)(W + O_QKB);
    int*   sel    = (int*)(W + O_SEL);
    float* ATTN   = (float*)(W + O_ATTN);
    bf16* X     = (bf16*)(W + O_X);
    bf16* AX2   = (bf16*)(W + O_AX2);
    bf16* QKOUT = (bf16*)(W + O_AX2);
    bf16* ADJB  = (bf16*)(W + O_ADJB);
    bf16* INT_  = (bf16*)(W + O_INT);
    bf16* OUT0T = (bf16*)(W + O_OUT0T);
    bf16* BBA   = (bf16*)(W + O_BBA);
    bf16* BBB   = (bf16*)(W + O_BBB);
    bf16* BBC   = (bf16*)(W + O_BBC);
    bf16* W0T   = (bf16*)(W + O_W0T);
    bf16* W1T   = (bf16*)(W + O_W1T);
    bf16* QKWT  = (bf16*)(W + O_QKWT);
    bf16* CW2   = (bf16*)(W + O_CWB);
    bf16* LCT   = (bf16*)(W + O_LCT);
    bf16* F1T   = (bf16*)(W + O_F1T);
    bf16* F2T   = (bf16*)(W + O_F2T);

    const size_t sND  = (size_t)N_ * D_;
    const size_t sNDC = (size_t)N_ * DC_;
    const size_t sNN  = (size_t)N_ * N_;

    // ---- all prep in one dispatch ----
    k_prep<<<PB_CNT, 256, 0, stream>>>(smask, flag, counts,
        adj, ADJB, den, inputs, X, INT_, convw, CW2,
        qb, kb, qkb, W0w, W0T, W1w, W1T, qw, kw, QKWT,
        lincw, LCT, fc1w, F1T, fc2w, F2T);
    k_select_head<<<1, 64, 0, stream>>>(counts, hsel);

    // ---- GCN layer 0 ----
    mm<0><<<dim3(6, 16, B_), 256, 0, stream>>>(X, sNDC, DC_, W0T, 0, D_, nullptr, 0,
        W0b, nullptr, 0, nullptr, nullptr, nullptr, BBA, nullptr, sND, D_, N_, D_, D_,
        nullptr, nullptr, nullptr, 0, 0);
    mm<6><<<dim3(6, 16, B_), 256, 0, stream>>>(ADJB, sNN, N_, INT_, sND, N_, nullptr, 0,
        nullptr, nullptr, 0, nullptr, nullptr, nullptr, BBB, nullptr, sND, D_, N_, D_, N_,
        nullptr, nullptr, nullptr, 0, 0);
    mm<1><<<dim3(6, 16, B_), 256, 0, stream>>>(BBB, sND, D_, W0T, 0, D_, nullptr, 0,
        W0b, BBA, D_, den, nullptr, nullptr, BBC, nullptr, sND, D_, N_, D_, D_,
        nullptr, nullptr, nullptr, 0, 0);
    k_tr_bf16<<<dim3(24, 32, B_), 256, 0, stream>>>(BBC, OUT0T);
    mm<5><<<dim3(6, 16, B_), 256, 0, stream>>>(CW2, 0, 3072, OUT0T, sND, N_, nullptr, 0,
        convb, nullptr, 0, nullptr, nullptr, nullptr, BBB, nullptr, sND, D_, N_, D_, 3072,
        nullptr, nullptr, nullptr, 0, 0);
    mm<0><<<dim3(6, 16, B_), 256, 0, stream>>>(BBB, sND, D_, LCT, 0, D_, nullptr, 0,
        lincb, nullptr, 0, nullptr, nullptr, nullptr, X + D_, nullptr, sNDC, DC_, N_, D_, D_,
        nullptr, nullptr, nullptr, 0, 0);

    // ---- merged Q|K projection + xW1 (EPI 7): N = 1024 + 768 = 1792 ----
    mm<7><<<dim3(14, 16, B_), 256, 0, stream>>>(X, sNDC, DC_, QKWT, 0, DC_, hsel, 1024,
        qkb, nullptr, 0, nullptr, nullptr, nullptr, QKOUT, nullptr, sNN, N_, N_, 1792, DC_,
        W1T, W1b, BBA, sND, D_);

    // ---- scores (fp32, masked) ----
    mm<4><<<dim3(8, 16, B_), 256, 0, stream>>>(QKOUT, sNN, N_, QKOUT + 512, sNN, N_, hsel, 0,
        nullptr, nullptr, 0, nullptr, smask, flag, nullptr, ATTN, sNN, N_, N_, N_, DK_,
        nullptr, nullptr, nullptr, 0, 0);
    k_softmax<<<dim3(N_, B_), 256, 0, stream>>>(ATTN, smask, flag, hsel, t2p);

    // ---- top-2 select + sparse adj2 ----
    k_top2_s2<<<B_, 256, 0, stream>>>(t2p, thr, selcnt);
    k_extract<<<dim3(N_, B_), 256, 0, stream>>>(ATTN, thr, selcnt, sel, adiag, den2, X, AX2);
    k_ax2_sparse<<<B_, 256, 0, stream>>>(ATTN, X, selcnt, sel, AX2, den2);

    // ---- GCN layer 1 (xW1 already in BBA from merged GEMM) ----
    mm<1><<<dim3(6, 16, B_), 256, 0, stream>>>(AX2, sNDC, DC_, W1T, 0, DC_, nullptr, 0,
        W1b, BBA, D_, den2, nullptr, nullptr, BBB, nullptr, sND, D_, N_, D_, DC_,
        nullptr, nullptr, nullptr, 0, 0);

    // ---- fc ----
    mm<2><<<dim3(6, 16, B_), 256, 0, stream>>>(BBB, sND, D_, F1T, 0, D_, nullptr, 0,
        nullptr, nullptr, 0, nullptr, nullptr, nullptr, BBC, nullptr, sND, D_, N_, D_, D_,
        nullptr, nullptr, nullptr, 0, 0);
    mm<3><<<dim3(6, 16, B_), 256, 0, stream>>>(BBC, sND, D_, F2T, 0, D_, nullptr, 0,
        nullptr, nullptr, 0, nullptr, nullptr, nullptr, nullptr, out, sND, D_, N_, D_, D_,
        nullptr, nullptr, nullptr, 0, 0);
}

// Round 13
// 397.048 us; speedup vs baseline: 1.4419x; 1.0231x over previous
//
#include <hip/hip_runtime.h>
#include <cstdint>
#include <cstddef>

typedef __bf16 bf16;
typedef __bf16 bf16x8 __attribute__((ext_vector_type(8)));
typedef float f32x4 __attribute__((ext_vector_type(4)));

#define B_ 8
#define N_ 1024
#define D_ 768
#define H_ 3
#define DC_ 1536
#define DK_ 512
#define PC_ 766
#define MB_ (1024ull*1024ull)

// ---------------- workspace layout (byte offsets) ----------------
static const size_t O_DEN   = 0;
static const size_t O_DEN2  = 32768;
static const size_t O_ADIAG = 65536;
static const size_t O_T2P   = 98304;
static const size_t O_THR   = 163840;
static const size_t O_CNTS  = 164096;
static const size_t O_HSEL  = 164352;
static const size_t O_SELC  = 164608;
static const size_t O_FLAG  = 164864;
static const size_t O_QKB   = 165120;
static const size_t O_SEL   = 180224;
static const size_t O_ATTN  = 262144;            // f32 [8,1024,1024] 32MB
static const size_t O_X     = O_ATTN + 32*MB_;   // bf16 [8,1024,1536] 24MB
static const size_t O_AX2   = O_X    + 24*MB_;   // bf16 [8,1024,1536] 24MB (QK out overlays early)
static const size_t O_ADJB  = O_AX2  + 24*MB_;   // bf16 [8,1024,1024] 16MB
static const size_t O_INT   = O_ADJB + 16*MB_;   // bf16 [8,768,1024] inputs^T -> OUT0T (12MB)
static const size_t O_BBA   = O_INT  + 12*MB_;
static const size_t O_BBB   = O_BBA  + 12*MB_;
static const size_t O_BBC   = O_BBB  + 12*MB_;
static const size_t O_W0T   = O_BBC  + 12*MB_;   // [768][768]
static const size_t O_W1T   = O_W0T + 1179648;   // [768][1536]
static const size_t O_QKWT  = O_W1T + 2359296;   // [3072][1536]
static const size_t O_CWB   = O_QKWT + 9437184;  // CW2 [1024][3072]
static const size_t O_LCT   = O_CWB + 6291456;
static const size_t O_F1T   = O_LCT + 1179648;
static const size_t O_F2T   = O_F1T + 1179648;
static const size_t WS_NEED = O_F2T + 1179648;
static const size_t O_OUT0T = O_INT;

// ---------------- helpers ----------------
__device__ __forceinline__ bool mask_at(const void* p, int flag, size_t i) {
    switch (flag) {
        case 1:  return ((const int*)p)[i] != 0;
        case 2:  return ((const float*)p)[i] != 0.0f;
        case 3:  return ((const long long*)p)[i] != 0;
        default: return ((const unsigned char*)p)[i] != 0;
    }
}

__device__ __forceinline__ void gload16(const void* g, void* l) {
    __builtin_amdgcn_global_load_lds(
        (const __attribute__((address_space(1))) void*)g,
        (__attribute__((address_space(3))) void*)l, 16, 0, 0);
}

__device__ inline float blockMax256(float v) {
    __shared__ float red[4];
    for (int off = 32; off; off >>= 1) v = fmaxf(v, __shfl_xor(v, off));
    int lane = threadIdx.x & 63, wid = threadIdx.x >> 6;
    if (lane == 0) red[wid] = v;
    __syncthreads();
    v = fmaxf(fmaxf(red[0], red[1]), fmaxf(red[2], red[3]));
    __syncthreads();
    return v;
}

__device__ inline float blockSum256(float v) {
    __shared__ float red[4];
    for (int off = 32; off; off >>= 1) v += __shfl_xor(v, off);
    int lane = threadIdx.x & 63, wid = threadIdx.x >> 6;
    if (lane == 0) red[wid] = v;
    __syncthreads();
    v = red[0] + red[1] + red[2] + red[3];
    __syncthreads();
    return v;
}

// shared epilogue
template<int EPI>
__device__ __forceinline__ void epi_store(
    float v, int b, int m, int n, int M,
    const int boff, const float* __restrict__ bias,
    const bf16* __restrict__ Dadd, int ldd,
    const float* __restrict__ denv,
    const void* __restrict__ smask, int flag, int h0,
    bf16* __restrict__ Cb, float* __restrict__ Cf, size_t sC, int ldc,
    const float* __restrict__ bias2, bf16* __restrict__ Cb2, size_t sC2, int ldc2)
{
    size_t oidx = (size_t)b * sC + (size_t)m * ldc + n;
    if (EPI == 0) {
        Cb[oidx] = (bf16)(v + bias[boff + n]);
    } else if (EPI == 1) {
        v = fmaxf((v + bias[n]) / denv[(size_t)b * M + m], 0.f)
            + (float)Dadd[((size_t)b * M + m) * ldd + n];
        Cb[oidx] = (bf16)v;
    } else if (EPI == 2) {
        Cb[oidx] = (bf16)fmaxf(v, 0.f);
    } else if (EPI == 3) {
        Cf[oidx] = v;
    } else if (EPI == 4) {
        size_t mi = (((size_t)b * H_ + h0) * N_ + m) * N_ + n;
        Cf[oidx] = mask_at(smask, flag, mi) ? -1e9f : v * 0.04419417382415922f;
    } else if (EPI == 5) {
        Cb[oidx] = (n < PC_) ? (bf16)fmaxf(v + bias[m], 0.f) : (bf16)0.f;
    } else if (EPI == 7) {
        if (n < 1024)
            Cb[(size_t)b * sC + (size_t)m * ldc + n] = (bf16)(v + bias[boff + n]);
        else
            Cb2[(size_t)b * sC2 + (size_t)m * ldc2 + (n - 1024)] = (bf16)(v + bias2[n - 1024]);
    } else {
        Cb[oidx] = (bf16)v;
    }
}

// ================= bf16 MFMA NT GEMM (64x128 tile) =================
// R10 geometry: 4 waves (each 32x64), BK=64, 2-phase dbuf, counted vmcnt(6),
// raw s_barrier pairs, conflict-free 8-chunk XOR swizzle.
template<int EPI>
__global__ __launch_bounds__(256) void mm(
    const bf16* __restrict__ A, size_t sA, int lda,
    const bf16* __restrict__ Bt, size_t sB, int ldb,
    const int* __restrict__ rowIdx, int rowMul,
    const float* __restrict__ bias,
    const bf16* __restrict__ Dadd, int ldd,
    const float* __restrict__ denv,
    const void* __restrict__ smask, const int* __restrict__ flagp,
    bf16* __restrict__ Cb, float* __restrict__ Cf, size_t sC, int ldc,
    int M, int N, int K,
    const bf16* __restrict__ Bt2, const float* __restrict__ bias2,
    bf16* __restrict__ Cb2, size_t sC2, int ldc2)
{
    __shared__ __align__(16) bf16 As[2][64 * 64];
    __shared__ __align__(16) bf16 Bs[2][128 * 64];

    const int gx = gridDim.x, gy = gridDim.y;
    const int nwg = gx * gy * (int)gridDim.z;
    int lin = ((int)blockIdx.z * gy + (int)blockIdx.y) * gx + (int)blockIdx.x;
    int cpx = nwg >> 3;
    int swz = (lin & 7) * cpx + (lin >> 3);
    int ty = swz % gy;
    int tt = swz / gy;
    int tx = tt % gx;
    int b  = tt / gx;

    const int bm = ty * 64, bn = tx * 128;
    const int tid = threadIdx.x;
    const int lane = tid & 63, w = tid >> 6;
    const int wr = w >> 1, wc = w & 1;
    const int boff = rowIdx ? rowIdx[b] * rowMul : 0;

    const bf16* Ab = A + (size_t)b * sA;
    const bf16* Bb = Bt + (size_t)b * sB;

    const bf16* Bsrc = Bb;
    int bRow0 = boff + bn;
    if (EPI == 7 && bn >= 1024) { Bsrc = Bt2; bRow0 = bn - 1024; }

    const int sr = lane >> 3;
    const int gk = ((lane & 7) ^ (lane >> 3)) * 8;

    f32x4 zero = {0.f, 0.f, 0.f, 0.f};
    f32x4 acc[2][4];
    #pragma unroll
    for (int i = 0; i < 2; ++i)
        #pragma unroll
        for (int j = 0; j < 4; ++j) acc[i][j] = zero;

    #pragma unroll
    for (int q = 0; q < 2; ++q)
        gload16((const void*)(Ab + (size_t)(bm + w * 16 + q * 8 + sr) * lda + gk),
                (void*)(As[0] + (w * 16 + q * 8) * 64));
    #pragma unroll
    for (int q = 0; q < 4; ++q)
        gload16((const void*)(Bsrc + (size_t)(bRow0 + w * 32 + q * 8 + sr) * ldb + gk),
                (void*)(Bs[0] + (w * 32 + q * 8) * 64));

    const int rl = lane & 15;
    const int g8 = lane >> 4;
    const int rx = lane & 7;

    int cur = 0;
    for (int k0 = 0; k0 < K; k0 += 64) {
        int nxt = cur ^ 1;
        if (k0 + 64 < K) {
            #pragma unroll
            for (int q = 0; q < 2; ++q)
                gload16((const void*)(Ab + (size_t)(bm + w * 16 + q * 8 + sr) * lda + k0 + 64 + gk),
                        (void*)(As[nxt] + (w * 16 + q * 8) * 64));
            #pragma unroll
            for (int q = 0; q < 4; ++q)
                gload16((const void*)(Bsrc + (size_t)(bRow0 + w * 32 + q * 8 + sr) * ldb + k0 + 64 + gk),
                        (void*)(Bs[nxt] + (w * 32 + q * 8) * 64));
            asm volatile("s_waitcnt vmcnt(6)" ::: "memory");
        } else {
            asm volatile("s_waitcnt vmcnt(0)" ::: "memory");
        }
        __builtin_amdgcn_s_barrier();
        __builtin_amdgcn_sched_barrier(0);

        bf16x8 af[2][2], bfv[4][2];
        #pragma unroll
        for (int ks = 0; ks < 2; ++ks) {
            int e = ks * 4 + g8;
            #pragma unroll
            for (int i = 0; i < 2; ++i)
                af[i][ks] = *(const bf16x8*)(As[cur] + (wr * 32 + i * 16 + rl) * 64 + (e ^ rx) * 8);
            #pragma unroll
            for (int j = 0; j < 4; ++j)
                bfv[j][ks] = *(const bf16x8*)(Bs[cur] + (wc * 64 + j * 16 + rl) * 64 + (e ^ rx) * 8);
        }
        #pragma unroll
        for (int ks = 0; ks < 2; ++ks)
            #pragma unroll
            for (int i = 0; i < 2; ++i)
                #pragma unroll
                for (int j = 0; j < 4; ++j)
                    acc[i][j] = __builtin_amdgcn_mfma_f32_16x16x32_bf16(af[i][ks], bfv[j][ks], acc[i][j], 0, 0, 0);

        __builtin_amdgcn_s_barrier();
        __builtin_amdgcn_sched_barrier(0);
        cur = nxt;
    }

    const int r0 = (lane >> 4) * 4, c0 = lane & 15;
    int flag = 0, h0 = 0;
    if (EPI == 4) { flag = flagp[0]; h0 = rowIdx[b]; }
    #pragma unroll
    for (int i = 0; i < 2; ++i)
        #pragma unroll
        for (int r = 0; r < 4; ++r) {
            int m = bm + wr * 32 + i * 16 + r0 + r;
            #pragma unroll
            for (int j = 0; j < 4; ++j) {
                int n = bn + wc * 64 + j * 16 + c0;
                epi_store<EPI>(acc[i][j][r], b, m, n, M, boff, bias, Dadd, ldd, denv,
                               smask, flag, h0, Cb, Cf, sC, ldc, bias2, Cb2, sC2, ldc2);
            }
        }
}

// ================= bf16 MFMA NT GEMM (128x128 tile, high LDS-intensity) =================
// 4 waves (each 64x64 -> 32 FLOP/LDS-byte), BK=64, 2-phase dbuf, counted vmcnt(8).
// Used only where grid >= 2 blocks/CU balanced (merged N=1792, scores N=1024).
template<int EPI>
__global__ __launch_bounds__(256) void mm2(
    const bf16* __restrict__ A, size_t sA, int lda,
    const bf16* __restrict__ Bt, size_t sB, int ldb,
    const int* __restrict__ rowIdx, int rowMul,
    const float* __restrict__ bias,
    const bf16* __restrict__ Dadd, int ldd,
    const float* __restrict__ denv,
    const void* __restrict__ smask, const int* __restrict__ flagp,
    bf16* __restrict__ Cb, float* __restrict__ Cf, size_t sC, int ldc,
    int M, int N, int K,
    const bf16* __restrict__ Bt2, const float* __restrict__ bias2,
    bf16* __restrict__ Cb2, size_t sC2, int ldc2)
{
    __shared__ __align__(16) bf16 As[2][128 * 64];   // 32KB
    __shared__ __align__(16) bf16 Bs[2][128 * 64];   // 32KB

    const int gx = gridDim.x, gy = gridDim.y;
    const int nwg = gx * gy * (int)gridDim.z;
    int lin = ((int)blockIdx.z * gy + (int)blockIdx.y) * gx + (int)blockIdx.x;
    int cpx = nwg >> 3;
    int swz = (lin & 7) * cpx + (lin >> 3);
    int ty = swz % gy;
    int tt = swz / gy;
    int tx = tt % gx;
    int b  = tt / gx;

    const int bm = ty * 128, bn = tx * 128;
    const int tid = threadIdx.x;
    const int lane = tid & 63, w = tid >> 6;
    const int wr = w >> 1, wc = w & 1;         // 64x64 quadrant
    const int boff = rowIdx ? rowIdx[b] * rowMul : 0;

    const bf16* Ab = A + (size_t)b * sA;
    const bf16* Bb = Bt + (size_t)b * sB;

    const bf16* Bsrc = Bb;
    int bRow0 = boff + bn;
    if (EPI == 7 && bn >= 1024) { Bsrc = Bt2; bRow0 = bn - 1024; }

    const int sr = lane >> 3;
    const int gk = ((lane & 7) ^ (lane >> 3)) * 8;

    f32x4 zero = {0.f, 0.f, 0.f, 0.f};
    f32x4 acc[4][4];
    #pragma unroll
    for (int i = 0; i < 4; ++i)
        #pragma unroll
        for (int j = 0; j < 4; ++j) acc[i][j] = zero;

    // prologue: 8 loads/wave (A x4 panels, B x4 panels)
    #pragma unroll
    for (int q = 0; q < 4; ++q)
        gload16((const void*)(Ab + (size_t)(bm + w * 32 + q * 8 + sr) * lda + gk),
                (void*)(As[0] + (w * 32 + q * 8) * 64));
    #pragma unroll
    for (int q = 0; q < 4; ++q)
        gload16((const void*)(Bsrc + (size_t)(bRow0 + w * 32 + q * 8 + sr) * ldb + gk),
                (void*)(Bs[0] + (w * 32 + q * 8) * 64));

    const int rl = lane & 15;
    const int g8 = lane >> 4;
    const int rx = lane & 7;

    int cur = 0;
    for (int k0 = 0; k0 < K; k0 += 64) {
        int nxt = cur ^ 1;
        if (k0 + 64 < K) {
            #pragma unroll
            for (int q = 0; q < 4; ++q)
                gload16((const void*)(Ab + (size_t)(bm + w * 32 + q * 8 + sr) * lda + k0 + 64 + gk),
                        (void*)(As[nxt] + (w * 32 + q * 8) * 64));
            #pragma unroll
            for (int q = 0; q < 4; ++q)
                gload16((const void*)(Bsrc + (size_t)(bRow0 + w * 32 + q * 8 + sr) * ldb + k0 + 64 + gk),
                        (void*)(Bs[nxt] + (w * 32 + q * 8) * 64));
            asm volatile("s_waitcnt vmcnt(8)" ::: "memory");
        } else {
            asm volatile("s_waitcnt vmcnt(0)" ::: "memory");
        }
        __builtin_amdgcn_s_barrier();
        __builtin_amdgcn_sched_barrier(0);

        #pragma unroll
        for (int ks = 0; ks < 2; ++ks) {
            int e = ks * 4 + g8;
            bf16x8 af[4], bfv[4];
            #pragma unroll
            for (int i = 0; i < 4; ++i)
                af[i] = *(const bf16x8*)(As[cur] + (wr * 64 + i * 16 + rl) * 64 + (e ^ rx) * 8);
            #pragma unroll
            for (int j = 0; j < 4; ++j)
                bfv[j] = *(const bf16x8*)(Bs[cur] + (wc * 64 + j * 16 + rl) * 64 + (e ^ rx) * 8);
            #pragma unroll
            for (int i = 0; i < 4; ++i)
                #pragma unroll
                for (int j = 0; j < 4; ++j)
                    acc[i][j] = __builtin_amdgcn_mfma_f32_16x16x32_bf16(af[i], bfv[j], acc[i][j], 0, 0, 0);
        }

        __builtin_amdgcn_s_barrier();
        __builtin_amdgcn_sched_barrier(0);
        cur = nxt;
    }

    const int r0 = (lane >> 4) * 4, c0 = lane & 15;
    int flag = 0, h0 = 0;
    if (EPI == 4) { flag = flagp[0]; h0 = rowIdx[b]; }
    #pragma unroll
    for (int i = 0; i < 4; ++i)
        #pragma unroll
        for (int r = 0; r < 4; ++r) {
            int m = bm + wr * 64 + i * 16 + r0 + r;
            #pragma unroll
            for (int j = 0; j < 4; ++j) {
                int n = bn + wc * 64 + j * 16 + c0;
                epi_store<EPI>(acc[i][j][r], b, m, n, M, boff, bias, Dadd, ldd, denv,
                               smask, flag, h0, Cb, Cf, sC, ldc, bias2, Cb2, sC2, ldc2);
            }
        }
}

// ================= prep device functions =================

__device__ int d_detect(const unsigned int* __restrict__ sm) {
    __shared__ int sGt1, sF32, sOddNZ, sFlag;
    if (threadIdx.x == 0) { sGt1 = 0; sF32 = 0; sOddNZ = 0; }
    __syncthreads();
    int gt1 = 0, f32c = 0, oddnz = 0;
    for (int s = 0; s < 16; ++s) {
        int idx = s * 256 + threadIdx.x;
        unsigned wv = sm[idx];
        if (wv > 1u) gt1 = 1;
        if (wv == 0x3F800000u) f32c++;
        if ((idx & 1) && wv != 0u) oddnz = 1;
    }
    if (gt1)   atomicOr(&sGt1, 1);
    if (f32c)  atomicAdd(&sF32, f32c);
    if (oddnz) atomicOr(&sOddNZ, 1);
    __syncthreads();
    if (threadIdx.x == 0) {
        int f;
        if (sF32 > 512) f = 2;
        else if (!sGt1) f = sOddNZ ? 1 : 3;
        else f = 0;
        sFlag = f;
    }
    __syncthreads();
    return sFlag;
}

__device__ void d_trcvt(const float* __restrict__ src, bf16* __restrict__ dst,
                        int R, int C, int Rpad, int Cpad,
                        size_t sSrc, size_t sDst, int mode, int bx, int by, int bz) {
    __shared__ float t[32][33];
    int r0 = by * 32, c0 = bx * 32;
    int tx = threadIdx.x & 31, ty = threadIdx.x >> 5;
    const float* s = src + (size_t)bz * sSrc;
    bf16* d = dst + (size_t)bz * sDst;
    #pragma unroll
    for (int q = 0; q < 4; ++q) {
        int r = r0 + ty + q * 8, c = c0 + tx;
        t[ty + q * 8][tx] = (r < R && c < C) ? s[(size_t)r * C + c] : 0.f;
    }
    __syncthreads();
    #pragma unroll
    for (int q = 0; q < 4; ++q) {
        int dr = c0 + ty + q * 8, dc = r0 + tx;
        if (dr < Cpad && dc < Rpad) {
            int drm = dr;
            if (mode == 1) drm = (dr >> 9) * 1024 + (dr & 511);
            else if (mode == 2) drm = (dr >> 9) * 1024 + 512 + (dr & 511);
            d[(size_t)drm * Rpad + dc] = (bf16)t[tx][ty + q * 8];
        }
    }
}

// job boundaries (flat z)
#define PB_DET   1
#define PB_QKB   13
#define PB_CW2   1037
#define PB_ADJ   9229
#define PB_ROWS  17421
#define PB_INT   23565
#define PB_W0    24141
#define PB_W1    25293
#define PB_QW    27597
#define PB_KW    29901
#define PB_LC    30477
#define PB_F1    31053
#define PB_F2    31629
#define PB_CNT   31653

// mega-prep: all independent prep jobs in one dispatch
__global__ __launch_bounds__(256) void k_prep(
    const void* __restrict__ smask, int* __restrict__ flag, int* __restrict__ counts,
    const float* __restrict__ adj, bf16* __restrict__ adjb, float* __restrict__ den,
    const float* __restrict__ inputs, bf16* __restrict__ X, bf16* __restrict__ INT_,
    const float* __restrict__ convw, bf16* __restrict__ CW2,
    const float* __restrict__ qb, const float* __restrict__ kb, float* __restrict__ qkbD,
    const float* __restrict__ W0w, bf16* __restrict__ W0T,
    const float* __restrict__ W1w, bf16* __restrict__ W1T,
    const float* __restrict__ qw, const float* __restrict__ kw, bf16* __restrict__ QKWT,
    const float* __restrict__ lincw, bf16* __restrict__ LCT,
    const float* __restrict__ fc1w, bf16* __restrict__ F1T,
    const float* __restrict__ fc2w, bf16* __restrict__ F2T)
{
    const int id = blockIdx.x;
    const size_t sND = (size_t)N_ * D_;
    if (id < PB_DET) {
        int f = d_detect((const unsigned int*)smask);
        if (threadIdx.x == 0) flag[0] = f;
    } else if (id < PB_QKB) {
        int idx = (id - PB_DET) * 256 + threadIdx.x;
        if (idx < 3072) {
            int h = idx >> 10, rem = idx & 1023, s = rem >> 9, r = rem & 511;
            qkbD[idx] = (s ? kb : qb)[h * 512 + r];
        }
    } else if (id < PB_CW2) {
        int o = id - PB_QKB;
        const float* s = convw + (size_t)o * 3072;
        bf16* dp = CW2 + (size_t)o * 3072;
        for (int q = 0; q < 4; ++q) {
            int i = q * 256 + threadIdx.x;
            float v0 = s[i * 3], v1 = s[i * 3 + 1], v2 = s[i * 3 + 2];
            dp[i] = (bf16)v0; dp[1024 + i] = (bf16)v1; dp[2048 + i] = (bf16)v2;
        }
    } else if (id < PB_ADJ) {
        int t = id - PB_CW2;
        int row = t & 1023, b = t >> 10;
        size_t base = ((size_t)b * N_ + row) * N_;
        float4 v = ((const float4*)(adj + base))[threadIdx.x];
        union { bf16 b[4]; uint2 u; } o;
        o.b[0] = (bf16)v.x; o.b[1] = (bf16)v.y; o.b[2] = (bf16)v.z; o.b[3] = (bf16)v.w;
        ((uint2*)(adjb + base))[threadIdx.x] = o.u;
        float s = blockSum256(v.x + v.y + v.z + v.w);
        if (threadIdx.x == 0) den[b * N_ + row] = s + 1.0f;
    } else if (id < PB_ROWS) {
        int row = id - PB_ADJ;
        int t = threadIdx.x;
        if (t < 192) {
            float4 v = ((const float4*)(inputs + (size_t)row * D_))[t];
            union { bf16 b[4]; uint2 u; } o;
            o.b[0] = (bf16)v.x; o.b[1] = (bf16)v.y; o.b[2] = (bf16)v.z; o.b[3] = (bf16)v.w;
            *(uint2*)(X + (size_t)row * DC_ + t * 4) = o.u;
        }
    } else if (id < PB_INT) {
        int t = id - PB_ROWS;
        int bx = t % 24; int u = t / 24; int by = u % 32; int bz = u / 32;
        d_trcvt(inputs, INT_, N_, D_, N_, D_, sND, sND, 0, bx, by, bz);
    } else if (id < PB_W0) {
        int t = id - PB_INT;
        d_trcvt(W0w, W0T, D_, D_, D_, D_, 0, 0, 0, t % 24, t / 24, 0);
    } else if (id < PB_W1) {
        int t = id - PB_W0;
        d_trcvt(W1w, W1T, DC_, D_, DC_, D_, 0, 0, 0, t % 24, t / 24, 0);
    } else if (id < PB_QW) {
        int t = id - PB_W1;
        d_trcvt(qw, QKWT, DC_, DC_, DC_, DC_, 0, 0, 1, t % 48, t / 48, 0);
    } else if (id < PB_KW) {
        int t = id - PB_QW;
        d_trcvt(kw, QKWT, DC_, DC_, DC_, DC_, 0, 0, 2, t % 48, t / 48, 0);
    } else if (id < PB_LC) {
        int t = id - PB_KW;
        d_trcvt(lincw, LCT, PC_, D_, D_, D_, 0, 0, 0, t % 24, t / 24, 0);
    } else if (id < PB_F1) {
        int t = id - PB_LC;
        d_trcvt(fc1w, F1T, D_, D_, D_, D_, 0, 0, 0, t % 24, t / 24, 0);
    } else if (id < PB_F2) {
        int t = id - PB_F1;
        d_trcvt(fc2w, F2T, D_, D_, D_, D_, 0, 0, 0, t % 24, t / 24, 0);
    } else if (id < PB_CNT) {
        int bh = id - PB_F2;
        int f = d_detect((const unsigned int*)smask);   // local, same result
        float c = 0.f;
        for (int s = 0; s < 4; ++s) {
            int q = s * 256 + threadIdx.x;
            size_t mi = ((size_t)bh * N_ + q) * N_;
            if (!mask_at(smask, f, mi)) c += 1.f;
        }
        c = blockSum256(c);
        if (threadIdx.x == 0) counts[bh] = (int)(c + 0.5f);
    }
}

// ================= remaining support kernels =================

__global__ void k_select_head(const int* __restrict__ counts, int* __restrict__ hsel) {
    if (threadIdx.x != 0 || blockIdx.x != 0) return;
    float p[B_][H_];
    for (int h = 0; h < H_; ++h) {
        float mx = -1e30f;
        for (int b = 0; b < B_; ++b) mx = fmaxf(mx, (float)counts[b * H_ + h]);
        float s = 0.f;
        for (int b = 0; b < B_; ++b) { p[b][h] = expf((float)counts[b * H_ + h] - mx); s += p[b][h]; }
        for (int b = 0; b < B_; ++b) p[b][h] /= s;
    }
    for (int b = 0; b < B_; ++b) {
        int best = 0; float bv = p[b][0];
        for (int h = 1; h < H_; ++h) if (p[b][h] > bv) { bv = p[b][h]; best = h; }
        hsel[b] = best;
    }
}

__global__ __launch_bounds__(256) void k_tr_bf16(const bf16* __restrict__ src,
                                                 bf16* __restrict__ dst) {
    __shared__ bf16 t[32][34];
    int b = blockIdx.z;
    int i0 = blockIdx.y * 32, p0 = blockIdx.x * 32;
    int tx = threadIdx.x & 31, ty = threadIdx.x >> 5;
    const bf16* s = src + (size_t)b * N_ * D_;
    bf16* d = dst + (size_t)b * D_ * N_;
    #pragma unroll
    for (int q = 0; q < 4; ++q)
        t[ty + q * 8][tx] = s[(size_t)(i0 + ty + q * 8) * D_ + p0 + tx];
    __syncthreads();
    #pragma unroll
    for (int q = 0; q < 4; ++q)
        d[(size_t)(p0 + ty + q * 8) * N_ + i0 + tx] = t[tx][ty + q * 8];
}

__global__ __launch_bounds__(256) void k_softmax(float* __restrict__ Sc,
                                                 const void* __restrict__ smask,
                                                 const int* __restrict__ flagp,
                                                 const int* __restrict__ hsel,
                                                 float* __restrict__ part) {
    __shared__ float s1[256], s2[256];
    int b = blockIdx.y, row = blockIdx.x;
    int h0 = hsel[b], flag = flagp[0];
    float* rp = Sc + ((size_t)b * N_ + row) * N_;
    float v[4];
    float mx = -INFINITY;
    #pragma unroll
    for (int s = 0; s < 4; ++s) { v[s] = rp[s * 256 + threadIdx.x]; mx = fmaxf(mx, v[s]); }
    mx = blockMax256(mx);
    float sum = 0.f;
    #pragma unroll
    for (int s = 0; s < 4; ++s) { v[s] = expf(v[s] - mx); sum += v[s]; }
    sum = blockSum256(sum);
    size_t ki = (((size_t)b * H_ + h0) * N_ + row) * N_;
    float keep = mask_at(smask, flag, ki) ? 0.f : 1.f;
    float inv = keep / sum;
    float m1 = -INFINITY, m2 = -INFINITY;
    #pragma unroll
    for (int s = 0; s < 4; ++s) {
        float x = v[s] * inv;
        rp[s * 256 + threadIdx.x] = x;
        if (x > m1) { m2 = m1; m1 = x; } else m2 = fmaxf(m2, x);
    }
    int tid = threadIdx.x;
    s1[tid] = m1; s2[tid] = m2;
    __syncthreads();
    for (int off = 128; off; off >>= 1) {
        if (tid < off) {
            float a1 = s1[tid], a2 = s2[tid], b1 = s1[tid + off], b2 = s2[tid + off];
            s1[tid] = fmaxf(a1, b1);
            s2[tid] = fmaxf(fminf(a1, b1), fmaxf(a2, b2));
        }
        __syncthreads();
    }
    if (tid == 0) {
        part[((size_t)b * N_ + row) * 2]     = s1[0];
        part[((size_t)b * N_ + row) * 2 + 1] = s2[0];
    }
}

__global__ __launch_bounds__(256) void k_top2_s2(const float* __restrict__ part,
                                                 float* __restrict__ thr,
                                                 int* __restrict__ selcnt) {
    __shared__ float s1[256], s2[256];
    int b = blockIdx.x, tid = threadIdx.x;
    float m1 = -INFINITY, m2 = -INFINITY;
    for (int s = 0; s < 4; ++s) {
        int r = s * 256 + tid;
        float a1 = part[((size_t)b * N_ + r) * 2];
        float a2 = part[((size_t)b * N_ + r) * 2 + 1];
        float n1 = fmaxf(m1, a1);
        float n2 = fmaxf(fminf(m1, a1), fmaxf(m2, a2));
        m1 = n1; m2 = n2;
    }
    s1[tid] = m1; s2[tid] = m2;
    __syncthreads();
    for (int off = 128; off; off >>= 1) {
        if (tid < off) {
            float a1 = s1[tid], a2 = s2[tid], b1 = s1[tid + off], b2 = s2[tid + off];
            s1[tid] = fmaxf(a1, b1);
            s2[tid] = fmaxf(fminf(a1, b1), fmaxf(a2, b2));
        }
        __syncthreads();
    }
    if (tid == 0) { thr[b] = s2[0]; selcnt[b] = 0; }
}

// extract + diag + den2 + ax2_init fused: block (row,b) owns attn row `row`
__global__ __launch_bounds__(256) void k_extract(const float* __restrict__ attn,
                                                 const float* __restrict__ thr,
                                                 int* __restrict__ selcnt,
                                                 int* __restrict__ sel,
                                                 float* __restrict__ adiag,
                                                 float* __restrict__ den2,
                                                 const bf16* __restrict__ x,
                                                 bf16* __restrict__ ax2) {
    __shared__ float sdiag;
    int b = blockIdx.y, row = blockIdx.x;
    const float* ap = attn + (size_t)b * N_ * N_;
    float t = thr[b];
    size_t base = (size_t)row * 1024;
    for (int s = 0; s < 4; ++s) {
        int col = s * 256 + threadIdx.x;
        float v = ap[base + col];
        if (col == row) {
            adiag[b * N_ + row] = v;
            den2[b * N_ + row] = v + 1.0f;
            sdiag = v;
        }
        if (v >= t) {
            int pos = atomicAdd(&selcnt[b], 1);
            if (pos < 512) {
                sel[((size_t)b * 512 + pos) * 2]     = row;
                sel[((size_t)b * 512 + pos) * 2 + 1] = col;
            }
        }
    }
    __syncthreads();
    float a = sdiag;
    const bf16* xp = x + ((size_t)b * N_ + row) * DC_;
    bf16* op = ax2 + ((size_t)b * N_ + row) * DC_;
    #pragma unroll
    for (int s = 0; s < 6; ++s) {
        int d = s * 256 + threadIdx.x;
        op[d] = (bf16)(a * (float)xp[d]);
    }
}

__global__ __launch_bounds__(256) void k_ax2_sparse(const float* __restrict__ attn,
                                                    const bf16* __restrict__ x,
                                                    const int* __restrict__ selcnt,
                                                    const int* __restrict__ sel,
                                                    bf16* __restrict__ ax2,
                                                    float* __restrict__ den2) {
    int b = blockIdx.x;
    int cnt = selcnt[b]; if (cnt > 512) cnt = 512;
    __shared__ int si[1024];
    if (threadIdx.x == 0) {
        for (int e = 0; e < cnt; ++e) {
            si[e * 2]     = sel[((size_t)b * 512 + e) * 2];
            si[e * 2 + 1] = sel[((size_t)b * 512 + e) * 2 + 1];
        }
        for (int a = 1; a < cnt; ++a) {
            int ii = si[a * 2], jj = si[a * 2 + 1];
            long long key = (long long)ii * N_ + jj;
            int p = a - 1;
            while (p >= 0 && ((long long)si[p * 2] * N_ + si[p * 2 + 1]) > key) {
                si[(p + 1) * 2] = si[p * 2]; si[(p + 1) * 2 + 1] = si[p * 2 + 1]; --p;
            }
            si[(p + 1) * 2] = ii; si[(p + 1) * 2 + 1] = jj;
        }
    }
    __syncthreads();
    const float* ap = attn + (size_t)b * N_ * N_;
    for (int e = 0; e < cnt; ++e) {
        int i = si[e * 2], j = si[e * 2 + 1];
        if (i == j) continue;
        float aij = ap[(size_t)i * N_ + j];
        float aji = ap[(size_t)j * N_ + i];
        bf16* ri = ax2 + ((size_t)b * N_ + i) * DC_;
        bf16* rj = ax2 + ((size_t)b * N_ + j) * DC_;
        const bf16* xi = x + ((size_t)b * N_ + i) * DC_;
        const bf16* xj = x + ((size_t)b * N_ + j) * DC_;
        for (int s = 0; s < 6; ++s) {
            int d = s * 256 + threadIdx.x;
            ri[d] = (bf16)((float)ri[d] + aij * (float)xj[d]);
            rj[d] = (bf16)((float)rj[d] + aji * (float)xi[d]);
        }
        if (threadIdx.x == 0) {
            den2[b * N_ + i] += aij;
            den2[b * N_ + j] += aji;
        }
        __syncthreads();
    }
}

// ---------------- launch ----------------
extern "C" void kernel_launch(void* const* d_in, const int* in_sizes, int n_in,
                              void* d_out, int out_size, void* d_ws, size_t ws_size,
                              hipStream_t stream) {
    if (n_in < 17) return;
    if (ws_size < WS_NEED) return;

    const float* adj    = (const float*)d_in[0];
    const float* inputs = (const float*)d_in[1];
    const void*  smask  = d_in[2];
    const float* W0w = (const float*)d_in[3];
    const float* W0b = (const float*)d_in[4];
    const float* W1w = (const float*)d_in[5];
    const float* W1b = (const float*)d_in[6];
    const float* qw  = (const float*)d_in[7];
    const float* qb  = (const float*)d_in[8];
    const float* kw  = (const float*)d_in[9];
    const float* kb  = (const float*)d_in[10];
    const float* convw = (const float*)d_in[11];
    const float* convb = (const float*)d_in[12];
    const float* lincw = (const float*)d_in[13];
    const float* lincb = (const float*)d_in[14];
    const float* fc1w  = (const float*)d_in[15];
    const float* fc2w  = (const float*)d_in[16];

    char* W = (char*)d_ws;
    float* out = (float*)d_out;

    float* den    = (float*)(W + O_DEN);
    float* den2   = (float*)(W + O_DEN2);
    float* adiag  = (float*)(W + O_ADIAG);
    float* t2p    = (float*)(W + O_T2P);
    float* thr    = (float*)(W + O_THR);
    int*   counts = (int*)(W + O_CNTS);
    int*   hsel   = (int*)(W + O_HSEL);
    int*   selcnt = (int*)(W + O_SELC);
    int*   flag   = (int*)(W + O_FLAG);
    float* qkb    = (float*)(W + O_QKB);
    int*   sel    = (int*)(W + O_SEL);
    float* ATTN   = (float*)(W + O_ATTN);
    bf16* X     = (bf16*)(W + O_X);
    bf16* AX2   = (bf16*)(W + O_AX2);
    bf16* QKOUT = (bf16*)(W + O_AX2);
    bf16* ADJB  = (bf16*)(W + O_ADJB);
    bf16* INT_  = (bf16*)(W + O_INT);
    bf16* OUT0T = (bf16*)(W + O_OUT0T);
    bf16* BBA   = (bf16*)(W + O_BBA);
    bf16* BBB   = (bf16*)(W + O_BBB);
    bf16* BBC   = (bf16*)(W + O_BBC);
    bf16* W0T   = (bf16*)(W + O_W0T);
    bf16* W1T   = (bf16*)(W + O_W1T);
    bf16* QKWT  = (bf16*)(W + O_QKWT);
    bf16* CW2   = (bf16*)(W + O_CWB);
    bf16* LCT   = (bf16*)(W + O_LCT);
    bf16* F1T   = (bf16*)(W + O_F1T);
    bf16* F2T   = (bf16*)(W + O_F2T);

    const size_t sND  = (size_t)N_ * D_;
    const size_t sNDC = (size_t)N_ * DC_;
    const size_t sNN  = (size_t)N_ * N_;

    // ---- all prep in one dispatch ----
    k_prep<<<PB_CNT, 256, 0, stream>>>(smask, flag, counts,
        adj, ADJB, den, inputs, X, INT_, convw, CW2,
        qb, kb, qkb, W0w, W0T, W1w, W1T, qw, kw, QKWT,
        lincw, LCT, fc1w, F1T, fc2w, F2T);
    k_select_head<<<1, 64, 0, stream>>>(counts, hsel);

    // ---- GCN layer 0 ----
    mm<0><<<dim3(6, 16, B_), 256, 0, stream>>>(X, sNDC, DC_, W0T, 0, D_, nullptr, 0,
        W0b, nullptr, 0, nullptr, nullptr, nullptr, BBA, nullptr, sND, D_, N_, D_, D_,
        nullptr, nullptr, nullptr, 0, 0);
    mm<6><<<dim3(6, 16, B_), 256, 0, stream>>>(ADJB, sNN, N_, INT_, sND, N_, nullptr, 0,
        nullptr, nullptr, 0, nullptr, nullptr, nullptr, BBB, nullptr, sND, D_, N_, D_, N_,
        nullptr, nullptr, nullptr, 0, 0);
    mm<1><<<dim3(6, 16, B_), 256, 0, stream>>>(BBB, sND, D_, W0T, 0, D_, nullptr, 0,
        W0b, BBA, D_, den, nullptr, nullptr, BBC, nullptr, sND, D_, N_, D_, D_,
        nullptr, nullptr, nullptr, 0, 0);
    k_tr_bf16<<<dim3(24, 32, B_), 256, 0, stream>>>(BBC, OUT0T);
    mm<5><<<dim3(6, 16, B_), 256, 0, stream>>>(CW2, 0, 3072, OUT0T, sND, N_, nullptr, 0,
        convb, nullptr, 0, nullptr, nullptr, nullptr, BBB, nullptr, sND, D_, N_, D_, 3072,
        nullptr, nullptr, nullptr, 0, 0);
    mm<0><<<dim3(6, 16, B_), 256, 0, stream>>>(BBB, sND, D_, LCT, 0, D_, nullptr, 0,
        lincb, nullptr, 0, nullptr, nullptr, nullptr, X + D_, nullptr, sNDC, DC_, N_, D_, D_,
        nullptr, nullptr, nullptr, 0, 0);

    // ---- merged Q|K projection + xW1 (EPI 7, 128x128 tiles): N = 1792, grid 896 ----
    mm2<7><<<dim3(14, 8, B_), 256, 0, stream>>>(X, sNDC, DC_, QKWT, 0, DC_, hsel, 1024,
        qkb, nullptr, 0, nullptr, nullptr, nullptr, QKOUT, nullptr, sNN, N_, N_, 1792, DC_,
        W1T, W1b, BBA, sND, D_);

    // ---- scores (fp32, masked; 128x128 tiles): grid 512 = 2/CU balanced ----
    mm2<4><<<dim3(8, 8, B_), 256, 0, stream>>>(QKOUT, sNN, N_, QKOUT + 512, sNN, N_, hsel, 0,
        nullptr, nullptr, 0, nullptr, smask, flag, nullptr, ATTN, sNN, N_, N_, N_, DK_,
        nullptr, nullptr, nullptr, 0, 0);
    k_softmax<<<dim3(N_, B_), 256, 0, stream>>>(ATTN, smask, flag, hsel, t2p);

    // ---- top-2 select + sparse adj2 ----
    k_top2_s2<<<B_, 256, 0, stream>>>(t2p, thr, selcnt);
    k_extract<<<dim3(N_, B_), 256, 0, stream>>>(ATTN, thr, selcnt, sel, adiag, den2, X, AX2);
    k_ax2_sparse<<<B_, 256, 0, stream>>>(ATTN, X, selcnt, sel, AX2, den2);

    // ---- GCN layer 1 (xW1 already in BBA from merged GEMM) ----
    mm<1><<<dim3(6, 16, B_), 256, 0, stream>>>(AX2, sNDC, DC_, W1T, 0, DC_, nullptr, 0,
        W1b, BBA, D_, den2, nullptr, nullptr, BBB, nullptr, sND, D_, N_, D_, DC_,
        nullptr, nullptr, nullptr, 0, 0);

    // ---- fc ----
    mm<2><<<dim3(6, 16, B_), 256, 0, stream>>>(BBB, sND, D_, F1T, 0, D_, nullptr, 0,
        nullptr, nullptr, 0, nullptr, nullptr, nullptr, BBC, nullptr, sND, D_, N_, D_, D_,
        nullptr, nullptr, nullptr, 0, 0);
    mm<3><<<dim3(6, 16, B_), 256, 0, stream>>>(BBC, sND, D_, F2T, 0, D_, nullptr, 0,
        nullptr, nullptr, 0, nullptr, nullptr, nullptr, nullptr, out, sND, D_, N_, D_, D_,
        nullptr, nullptr, nullptr, 0, 0);
}

// Round 14
// 390.193 us; speedup vs baseline: 1.4673x; 1.0176x over previous
//
#include <hip/hip_runtime.h>
#include <cstdint>
#include <cstddef>

typedef __bf16 bf16;
typedef __bf16 bf16x8 __attribute__((ext_vector_type(8)));
typedef float f32x4 __attribute__((ext_vector_type(4)));

#define B_ 8
#define N_ 1024
#define D_ 768
#define H_ 3
#define DC_ 1536
#define DK_ 512
#define PC_ 766
#define MB_ (1024ull*1024ull)

// ---------------- workspace layout (byte offsets) ----------------
static const size_t O_DEN   = 0;
static const size_t O_DEN2  = 32768;
static const size_t O_ADIAG = 65536;
static const size_t O_THR   = 163840;
static const size_t O_CNTS  = 164096;
static const size_t O_HSEL  = 164352;
static const size_t O_SELC  = 164608;
static const size_t O_FLAG  = 164864;
static const size_t O_QKB   = 165120;
static const size_t O_SEL   = 180224;
static const size_t O_ATTN  = 262144;            // f32 [8,1024,1024] 32MB
static const size_t O_X     = O_ATTN + 32*MB_;   // bf16 [8,1024,1536] 24MB
static const size_t O_AX2   = O_X    + 24*MB_;   // bf16 [8,1024,1536] 24MB (QK out overlays early)
static const size_t O_ADJB  = O_AX2  + 24*MB_;   // bf16 [8,1024,1024] 16MB
static const size_t O_INT   = O_ADJB + 16*MB_;   // bf16 [8,768,1024] inputs^T -> OUT0T (12MB)
static const size_t O_BBA   = O_INT  + 12*MB_;
static const size_t O_BBB   = O_BBA  + 12*MB_;
static const size_t O_BBC   = O_BBB  + 12*MB_;   // out0 -> [T2P4 during attention phase] -> fc1out
static const size_t O_W0T   = O_BBC  + 12*MB_;   // [768][768]
static const size_t O_W1T   = O_W0T + 1179648;   // [768][1536]
static const size_t O_QKWT  = O_W1T + 2359296;   // [3072][1536]
static const size_t O_CWB   = O_QKWT + 9437184;  // CW2 [1024][3072]
static const size_t O_LCT   = O_CWB + 6291456;
static const size_t O_F1T   = O_LCT + 1179648;
static const size_t O_F2T   = O_F1T + 1179648;
static const size_t WS_NEED = O_F2T + 1179648;
static const size_t O_OUT0T = O_INT;
// t2p float4[8*1024] (128KB) overlays BBC head: out0 consumed (tr+conv) before
// softmax writes it; fc1 writes BBC after top2sel consumed it.
static const size_t O_T2P4  = O_BBC;

// ---------------- helpers ----------------
__device__ __forceinline__ bool mask_at(const void* p, int flag, size_t i) {
    switch (flag) {
        case 1:  return ((const int*)p)[i] != 0;
        case 2:  return ((const float*)p)[i] != 0.0f;
        case 3:  return ((const long long*)p)[i] != 0;
        default: return ((const unsigned char*)p)[i] != 0;
    }
}

__device__ __forceinline__ void gload16(const void* g, void* l) {
    __builtin_amdgcn_global_load_lds(
        (const __attribute__((address_space(1))) void*)g,
        (__attribute__((address_space(3))) void*)l, 16, 0, 0);
}

__device__ inline float blockMax256(float v) {
    __shared__ float red[4];
    for (int off = 32; off; off >>= 1) v = fmaxf(v, __shfl_xor(v, off));
    int lane = threadIdx.x & 63, wid = threadIdx.x >> 6;
    if (lane == 0) red[wid] = v;
    __syncthreads();
    v = fmaxf(fmaxf(red[0], red[1]), fmaxf(red[2], red[3]));
    __syncthreads();
    return v;
}

__device__ inline float blockSum256(float v) {
    __shared__ float red[4];
    for (int off = 32; off; off >>= 1) v += __shfl_xor(v, off);
    int lane = threadIdx.x & 63, wid = threadIdx.x >> 6;
    if (lane == 0) red[wid] = v;
    __syncthreads();
    v = red[0] + red[1] + red[2] + red[3];
    __syncthreads();
    return v;
}

// shared epilogue
template<int EPI>
__device__ __forceinline__ void epi_store(
    float v, int b, int m, int n, int M,
    const int boff, const float* __restrict__ bias,
    const bf16* __restrict__ Dadd, int ldd,
    const float* __restrict__ denv,
    const void* __restrict__ smask, int flag, int h0,
    bf16* __restrict__ Cb, float* __restrict__ Cf, size_t sC, int ldc,
    const float* __restrict__ bias2, bf16* __restrict__ Cb2, size_t sC2, int ldc2)
{
    size_t oidx = (size_t)b * sC + (size_t)m * ldc + n;
    if (EPI == 0) {
        Cb[oidx] = (bf16)(v + bias[boff + n]);
    } else if (EPI == 1) {
        v = fmaxf((v + bias[n]) / denv[(size_t)b * M + m], 0.f)
            + (float)Dadd[((size_t)b * M + m) * ldd + n];
        Cb[oidx] = (bf16)v;
    } else if (EPI == 2) {
        Cb[oidx] = (bf16)fmaxf(v, 0.f);
    } else if (EPI == 3) {
        Cf[oidx] = v;
    } else if (EPI == 4) {
        size_t mi = (((size_t)b * H_ + h0) * N_ + m) * N_ + n;
        Cf[oidx] = mask_at(smask, flag, mi) ? -1e9f : v * 0.04419417382415922f;
    } else if (EPI == 5) {
        Cb[oidx] = (n < PC_) ? (bf16)fmaxf(v + bias[m], 0.f) : (bf16)0.f;
    } else if (EPI == 7) {
        if (n < 1024)
            Cb[(size_t)b * sC + (size_t)m * ldc + n] = (bf16)(v + bias[boff + n]);
        else
            Cb2[(size_t)b * sC2 + (size_t)m * ldc2 + (n - 1024)] = (bf16)(v + bias2[n - 1024]);
    } else {
        Cb[oidx] = (bf16)v;
    }
}

// ================= bf16 MFMA NT GEMM (64x128 tile) =================
// R10 geometry: 4 waves (each 32x64), BK=64, 2-phase dbuf, counted vmcnt(6),
// raw s_barrier pairs, conflict-free 8-chunk XOR swizzle.
template<int EPI>
__global__ __launch_bounds__(256) void mm(
    const bf16* __restrict__ A, size_t sA, int lda,
    const bf16* __restrict__ Bt, size_t sB, int ldb,
    const int* __restrict__ rowIdx, int rowMul,
    const float* __restrict__ bias,
    const bf16* __restrict__ Dadd, int ldd,
    const float* __restrict__ denv,
    const void* __restrict__ smask, const int* __restrict__ flagp,
    bf16* __restrict__ Cb, float* __restrict__ Cf, size_t sC, int ldc,
    int M, int N, int K,
    const bf16* __restrict__ Bt2, const float* __restrict__ bias2,
    bf16* __restrict__ Cb2, size_t sC2, int ldc2)
{
    __shared__ __align__(16) bf16 As[2][64 * 64];
    __shared__ __align__(16) bf16 Bs[2][128 * 64];

    const int gx = gridDim.x, gy = gridDim.y;
    const int nwg = gx * gy * (int)gridDim.z;
    int lin = ((int)blockIdx.z * gy + (int)blockIdx.y) * gx + (int)blockIdx.x;
    int cpx = nwg >> 3;
    int swz = (lin & 7) * cpx + (lin >> 3);
    int ty = swz % gy;
    int tt = swz / gy;
    int tx = tt % gx;
    int b  = tt / gx;

    const int bm = ty * 64, bn = tx * 128;
    const int tid = threadIdx.x;
    const int lane = tid & 63, w = tid >> 6;
    const int wr = w >> 1, wc = w & 1;
    const int boff = rowIdx ? rowIdx[b] * rowMul : 0;

    const bf16* Ab = A + (size_t)b * sA;
    const bf16* Bb = Bt + (size_t)b * sB;

    const bf16* Bsrc = Bb;
    int bRow0 = boff + bn;
    if (EPI == 7 && bn >= 1024) { Bsrc = Bt2; bRow0 = bn - 1024; }

    const int sr = lane >> 3;
    const int gk = ((lane & 7) ^ (lane >> 3)) * 8;

    f32x4 zero = {0.f, 0.f, 0.f, 0.f};
    f32x4 acc[2][4];
    #pragma unroll
    for (int i = 0; i < 2; ++i)
        #pragma unroll
        for (int j = 0; j < 4; ++j) acc[i][j] = zero;

    #pragma unroll
    for (int q = 0; q < 2; ++q)
        gload16((const void*)(Ab + (size_t)(bm + w * 16 + q * 8 + sr) * lda + gk),
                (void*)(As[0] + (w * 16 + q * 8) * 64));
    #pragma unroll
    for (int q = 0; q < 4; ++q)
        gload16((const void*)(Bsrc + (size_t)(bRow0 + w * 32 + q * 8 + sr) * ldb + gk),
                (void*)(Bs[0] + (w * 32 + q * 8) * 64));

    const int rl = lane & 15;
    const int g8 = lane >> 4;
    const int rx = lane & 7;

    int cur = 0;
    for (int k0 = 0; k0 < K; k0 += 64) {
        int nxt = cur ^ 1;
        if (k0 + 64 < K) {
            #pragma unroll
            for (int q = 0; q < 2; ++q)
                gload16((const void*)(Ab + (size_t)(bm + w * 16 + q * 8 + sr) * lda + k0 + 64 + gk),
                        (void*)(As[nxt] + (w * 16 + q * 8) * 64));
            #pragma unroll
            for (int q = 0; q < 4; ++q)
                gload16((const void*)(Bsrc + (size_t)(bRow0 + w * 32 + q * 8 + sr) * ldb + k0 + 64 + gk),
                        (void*)(Bs[nxt] + (w * 32 + q * 8) * 64));
            asm volatile("s_waitcnt vmcnt(6)" ::: "memory");
        } else {
            asm volatile("s_waitcnt vmcnt(0)" ::: "memory");
        }
        __builtin_amdgcn_s_barrier();
        __builtin_amdgcn_sched_barrier(0);

        bf16x8 af[2][2], bfv[4][2];
        #pragma unroll
        for (int ks = 0; ks < 2; ++ks) {
            int e = ks * 4 + g8;
            #pragma unroll
            for (int i = 0; i < 2; ++i)
                af[i][ks] = *(const bf16x8*)(As[cur] + (wr * 32 + i * 16 + rl) * 64 + (e ^ rx) * 8);
            #pragma unroll
            for (int j = 0; j < 4; ++j)
                bfv[j][ks] = *(const bf16x8*)(Bs[cur] + (wc * 64 + j * 16 + rl) * 64 + (e ^ rx) * 8);
        }
        #pragma unroll
        for (int ks = 0; ks < 2; ++ks)
            #pragma unroll
            for (int i = 0; i < 2; ++i)
                #pragma unroll
                for (int j = 0; j < 4; ++j)
                    acc[i][j] = __builtin_amdgcn_mfma_f32_16x16x32_bf16(af[i][ks], bfv[j][ks], acc[i][j], 0, 0, 0);

        __builtin_amdgcn_s_barrier();
        __builtin_amdgcn_sched_barrier(0);
        cur = nxt;
    }

    const int r0 = (lane >> 4) * 4, c0 = lane & 15;
    int flag = 0, h0 = 0;
    if (EPI == 4) { flag = flagp[0]; h0 = rowIdx[b]; }
    #pragma unroll
    for (int i = 0; i < 2; ++i)
        #pragma unroll
        for (int r = 0; r < 4; ++r) {
            int m = bm + wr * 32 + i * 16 + r0 + r;
            #pragma unroll
            for (int j = 0; j < 4; ++j) {
                int n = bn + wc * 64 + j * 16 + c0;
                epi_store<EPI>(acc[i][j][r], b, m, n, M, boff, bias, Dadd, ldd, denv,
                               smask, flag, h0, Cb, Cf, sC, ldc, bias2, Cb2, sC2, ldc2);
            }
        }
}

// ================= jammed pair of independent GEMMs (64x128 tile) =================
// job 0: C0 = A0 @ B0t + bias0 (bf16);  job 1: C1 = A1 @ B1t (bf16).
// Same structure as mm; job = block-uniform bit of swizzled id.
__global__ __launch_bounds__(256) void mmJam(
    const bf16* __restrict__ A0, size_t sA0, int lda0,
    const bf16* __restrict__ B0t, size_t sB0, int ldb0,
    const float* __restrict__ bias0,
    bf16* __restrict__ C0, size_t sC0, int ldc0, int K0,
    const bf16* __restrict__ A1, size_t sA1, int lda1,
    const bf16* __restrict__ B1t, size_t sB1, int ldb1,
    bf16* __restrict__ C1, size_t sC1, int ldc1, int K1)
{
    __shared__ __align__(16) bf16 As[2][64 * 64];
    __shared__ __align__(16) bf16 Bs[2][128 * 64];

    const int gx = gridDim.x, gy = gridDim.y;   // gz = 16 (2 jobs x 8 batches)
    const int nwg = gx * gy * (int)gridDim.z;
    int lin = ((int)blockIdx.z * gy + (int)blockIdx.y) * gx + (int)blockIdx.x;
    int cpx = nwg >> 3;
    int swz = (lin & 7) * cpx + (lin >> 3);
    int ty = swz % gy;
    int tt = swz / gy;
    int tx = tt % gx;
    int zz = tt / gx;            // 0..15
    int job = zz >> 3;           // block-uniform
    int b   = zz & 7;

    const bf16* A  = job ? A1 : A0;
    const bf16* Bt = job ? B1t : B0t;
    bf16* C        = job ? C1 : C0;
    const size_t sA = job ? sA1 : sA0;
    const size_t sB = job ? sB1 : sB0;
    const size_t sC = job ? sC1 : sC0;
    const int lda = job ? lda1 : lda0;
    const int ldb = job ? ldb1 : ldb0;
    const int ldc = job ? ldc1 : ldc0;
    const int K   = job ? K1 : K0;

    const int bm = ty * 64, bn = tx * 128;
    const int tid = threadIdx.x;
    const int lane = tid & 63, w = tid >> 6;
    const int wr = w >> 1, wc = w & 1;

    const bf16* Ab = A + (size_t)b * sA;
    const bf16* Bb = Bt + (size_t)b * sB;

    const int sr = lane >> 3;
    const int gk = ((lane & 7) ^ (lane >> 3)) * 8;

    f32x4 zero = {0.f, 0.f, 0.f, 0.f};
    f32x4 acc[2][4];
    #pragma unroll
    for (int i = 0; i < 2; ++i)
        #pragma unroll
        for (int j = 0; j < 4; ++j) acc[i][j] = zero;

    #pragma unroll
    for (int q = 0; q < 2; ++q)
        gload16((const void*)(Ab + (size_t)(bm + w * 16 + q * 8 + sr) * lda + gk),
                (void*)(As[0] + (w * 16 + q * 8) * 64));
    #pragma unroll
    for (int q = 0; q < 4; ++q)
        gload16((const void*)(Bb + (size_t)(bn + w * 32 + q * 8 + sr) * ldb + gk),
                (void*)(Bs[0] + (w * 32 + q * 8) * 64));

    const int rl = lane & 15;
    const int g8 = lane >> 4;
    const int rx = lane & 7;

    int cur = 0;
    for (int k0 = 0; k0 < K; k0 += 64) {
        int nxt = cur ^ 1;
        if (k0 + 64 < K) {
            #pragma unroll
            for (int q = 0; q < 2; ++q)
                gload16((const void*)(Ab + (size_t)(bm + w * 16 + q * 8 + sr) * lda + k0 + 64 + gk),
                        (void*)(As[nxt] + (w * 16 + q * 8) * 64));
            #pragma unroll
            for (int q = 0; q < 4; ++q)
                gload16((const void*)(Bb + (size_t)(bn + w * 32 + q * 8 + sr) * ldb + k0 + 64 + gk),
                        (void*)(Bs[nxt] + (w * 32 + q * 8) * 64));
            asm volatile("s_waitcnt vmcnt(6)" ::: "memory");
        } else {
            asm volatile("s_waitcnt vmcnt(0)" ::: "memory");
        }
        __builtin_amdgcn_s_barrier();
        __builtin_amdgcn_sched_barrier(0);

        bf16x8 af[2][2], bfv[4][2];
        #pragma unroll
        for (int ks = 0; ks < 2; ++ks) {
            int e = ks * 4 + g8;
            #pragma unroll
            for (int i = 0; i < 2; ++i)
                af[i][ks] = *(const bf16x8*)(As[cur] + (wr * 32 + i * 16 + rl) * 64 + (e ^ rx) * 8);
            #pragma unroll
            for (int j = 0; j < 4; ++j)
                bfv[j][ks] = *(const bf16x8*)(Bs[cur] + (wc * 64 + j * 16 + rl) * 64 + (e ^ rx) * 8);
        }
        #pragma unroll
        for (int ks = 0; ks < 2; ++ks)
            #pragma unroll
            for (int i = 0; i < 2; ++i)
                #pragma unroll
                for (int j = 0; j < 4; ++j)
                    acc[i][j] = __builtin_amdgcn_mfma_f32_16x16x32_bf16(af[i][ks], bfv[j][ks], acc[i][j], 0, 0, 0);

        __builtin_amdgcn_s_barrier();
        __builtin_amdgcn_sched_barrier(0);
        cur = nxt;
    }

    const int r0 = (lane >> 4) * 4, c0 = lane & 15;
    #pragma unroll
    for (int i = 0; i < 2; ++i)
        #pragma unroll
        for (int r = 0; r < 4; ++r) {
            int m = bm + wr * 32 + i * 16 + r0 + r;
            #pragma unroll
            for (int j = 0; j < 4; ++j) {
                int n = bn + wc * 64 + j * 16 + c0;
                float v = acc[i][j][r];
                if (job == 0) v += bias0[n];
                C[(size_t)b * sC + (size_t)m * ldc + n] = (bf16)v;
            }
        }
}

// ================= bf16 MFMA NT GEMM (128x128 tile) =================
template<int EPI>
__global__ __launch_bounds__(256) void mm2(
    const bf16* __restrict__ A, size_t sA, int lda,
    const bf16* __restrict__ Bt, size_t sB, int ldb,
    const int* __restrict__ rowIdx, int rowMul,
    const float* __restrict__ bias,
    const bf16* __restrict__ Dadd, int ldd,
    const float* __restrict__ denv,
    const void* __restrict__ smask, const int* __restrict__ flagp,
    bf16* __restrict__ Cb, float* __restrict__ Cf, size_t sC, int ldc,
    int M, int N, int K,
    const bf16* __restrict__ Bt2, const float* __restrict__ bias2,
    bf16* __restrict__ Cb2, size_t sC2, int ldc2)
{
    __shared__ __align__(16) bf16 As[2][128 * 64];
    __shared__ __align__(16) bf16 Bs[2][128 * 64];

    const int gx = gridDim.x, gy = gridDim.y;
    const int nwg = gx * gy * (int)gridDim.z;
    int lin = ((int)blockIdx.z * gy + (int)blockIdx.y) * gx + (int)blockIdx.x;
    int cpx = nwg >> 3;
    int swz = (lin & 7) * cpx + (lin >> 3);
    int ty = swz % gy;
    int tt = swz / gy;
    int tx = tt % gx;
    int b  = tt / gx;

    const int bm = ty * 128, bn = tx * 128;
    const int tid = threadIdx.x;
    const int lane = tid & 63, w = tid >> 6;
    const int wr = w >> 1, wc = w & 1;
    const int boff = rowIdx ? rowIdx[b] * rowMul : 0;

    const bf16* Ab = A + (size_t)b * sA;
    const bf16* Bb = Bt + (size_t)b * sB;

    const bf16* Bsrc = Bb;
    int bRow0 = boff + bn;
    if (EPI == 7 && bn >= 1024) { Bsrc = Bt2; bRow0 = bn - 1024; }

    const int sr = lane >> 3;
    const int gk = ((lane & 7) ^ (lane >> 3)) * 8;

    f32x4 zero = {0.f, 0.f, 0.f, 0.f};
    f32x4 acc[4][4];
    #pragma unroll
    for (int i = 0; i < 4; ++i)
        #pragma unroll
        for (int j = 0; j < 4; ++j) acc[i][j] = zero;

    #pragma unroll
    for (int q = 0; q < 4; ++q)
        gload16((const void*)(Ab + (size_t)(bm + w * 32 + q * 8 + sr) * lda + gk),
                (void*)(As[0] + (w * 32 + q * 8) * 64));
    #pragma unroll
    for (int q = 0; q < 4; ++q)
        gload16((const void*)(Bsrc + (size_t)(bRow0 + w * 32 + q * 8 + sr) * ldb + gk),
                (void*)(Bs[0] + (w * 32 + q * 8) * 64));

    const int rl = lane & 15;
    const int g8 = lane >> 4;
    const int rx = lane & 7;

    int cur = 0;
    for (int k0 = 0; k0 < K; k0 += 64) {
        int nxt = cur ^ 1;
        if (k0 + 64 < K) {
            #pragma unroll
            for (int q = 0; q < 4; ++q)
                gload16((const void*)(Ab + (size_t)(bm + w * 32 + q * 8 + sr) * lda + k0 + 64 + gk),
                        (void*)(As[nxt] + (w * 32 + q * 8) * 64));
            #pragma unroll
            for (int q = 0; q < 4; ++q)
                gload16((const void*)(Bsrc + (size_t)(bRow0 + w * 32 + q * 8 + sr) * ldb + k0 + 64 + gk),
                        (void*)(Bs[nxt] + (w * 32 + q * 8) * 64));
            asm volatile("s_waitcnt vmcnt(8)" ::: "memory");
        } else {
            asm volatile("s_waitcnt vmcnt(0)" ::: "memory");
        }
        __builtin_amdgcn_s_barrier();
        __builtin_amdgcn_sched_barrier(0);

        #pragma unroll
        for (int ks = 0; ks < 2; ++ks) {
            int e = ks * 4 + g8;
            bf16x8 af[4], bfv[4];
            #pragma unroll
            for (int i = 0; i < 4; ++i)
                af[i] = *(const bf16x8*)(As[cur] + (wr * 64 + i * 16 + rl) * 64 + (e ^ rx) * 8);
            #pragma unroll
            for (int j = 0; j < 4; ++j)
                bfv[j] = *(const bf16x8*)(Bs[cur] + (wc * 64 + j * 16 + rl) * 64 + (e ^ rx) * 8);
            #pragma unroll
            for (int i = 0; i < 4; ++i)
                #pragma unroll
                for (int j = 0; j < 4; ++j)
                    acc[i][j] = __builtin_amdgcn_mfma_f32_16x16x32_bf16(af[i], bfv[j], acc[i][j], 0, 0, 0);
        }

        __builtin_amdgcn_s_barrier();
        __builtin_amdgcn_sched_barrier(0);
        cur = nxt;
    }

    const int r0 = (lane >> 4) * 4, c0 = lane & 15;
    int flag = 0, h0 = 0;
    if (EPI == 4) { flag = flagp[0]; h0 = rowIdx[b]; }
    #pragma unroll
    for (int i = 0; i < 4; ++i)
        #pragma unroll
        for (int r = 0; r < 4; ++r) {
            int m = bm + wr * 64 + i * 16 + r0 + r;
            #pragma unroll
            for (int j = 0; j < 4; ++j) {
                int n = bn + wc * 64 + j * 16 + c0;
                epi_store<EPI>(acc[i][j][r], b, m, n, M, boff, bias, Dadd, ldd, denv,
                               smask, flag, h0, Cb, Cf, sC, ldc, bias2, Cb2, sC2, ldc2);
            }
        }
}

// ================= prep device functions =================

__device__ int d_detect(const unsigned int* __restrict__ sm) {
    __shared__ int sGt1, sF32, sOddNZ, sFlag;
    if (threadIdx.x == 0) { sGt1 = 0; sF32 = 0; sOddNZ = 0; }
    __syncthreads();
    int gt1 = 0, f32c = 0, oddnz = 0;
    for (int s = 0; s < 16; ++s) {
        int idx = s * 256 + threadIdx.x;
        unsigned wv = sm[idx];
        if (wv > 1u) gt1 = 1;
        if (wv == 0x3F800000u) f32c++;
        if ((idx & 1) && wv != 0u) oddnz = 1;
    }
    if (gt1)   atomicOr(&sGt1, 1);
    if (f32c)  atomicAdd(&sF32, f32c);
    if (oddnz) atomicOr(&sOddNZ, 1);
    __syncthreads();
    if (threadIdx.x == 0) {
        int f;
        if (sF32 > 512) f = 2;
        else if (!sGt1) f = sOddNZ ? 1 : 3;
        else f = 0;
        sFlag = f;
    }
    __syncthreads();
    return sFlag;
}

__device__ void d_trcvt(const float* __restrict__ src, bf16* __restrict__ dst,
                        int R, int C, int Rpad, int Cpad,
                        size_t sSrc, size_t sDst, int mode, int bx, int by, int bz) {
    __shared__ float t[32][33];
    int r0 = by * 32, c0 = bx * 32;
    int tx = threadIdx.x & 31, ty = threadIdx.x >> 5;
    const float* s = src + (size_t)bz * sSrc;
    bf16* d = dst + (size_t)bz * sDst;
    #pragma unroll
    for (int q = 0; q < 4; ++q) {
        int r = r0 + ty + q * 8, c = c0 + tx;
        t[ty + q * 8][tx] = (r < R && c < C) ? s[(size_t)r * C + c] : 0.f;
    }
    __syncthreads();
    #pragma unroll
    for (int q = 0; q < 4; ++q) {
        int dr = c0 + ty + q * 8, dc = r0 + tx;
        if (dr < Cpad && dc < Rpad) {
            int drm = dr;
            if (mode == 1) drm = (dr >> 9) * 1024 + (dr & 511);
            else if (mode == 2) drm = (dr >> 9) * 1024 + 512 + (dr & 511);
            d[(size_t)drm * Rpad + dc] = (bf16)t[tx][ty + q * 8];
        }
    }
}

// job boundaries (flat z)
#define PB_DET   1
#define PB_QKB   13
#define PB_CW2   1037
#define PB_ADJ   9229
#define PB_ROWS  17421
#define PB_INT   23565
#define PB_W0    24141
#define PB_W1    25293
#define PB_QW    27597
#define PB_KW    29901
#define PB_LC    30477
#define PB_F1    31053
#define PB_F2    31629
#define PB_CNT   31653

__global__ __launch_bounds__(256) void k_prep(
    const void* __restrict__ smask, int* __restrict__ flag, int* __restrict__ counts,
    const float* __restrict__ adj, bf16* __restrict__ adjb, float* __restrict__ den,
    const float* __restrict__ inputs, bf16* __restrict__ X, bf16* __restrict__ INT_,
    const float* __restrict__ convw, bf16* __restrict__ CW2,
    const float* __restrict__ qb, const float* __restrict__ kb, float* __restrict__ qkbD,
    const float* __restrict__ W0w, bf16* __restrict__ W0T,
    const float* __restrict__ W1w, bf16* __restrict__ W1T,
    const float* __restrict__ qw, const float* __restrict__ kw, bf16* __restrict__ QKWT,
    const float* __restrict__ lincw, bf16* __restrict__ LCT,
    const float* __restrict__ fc1w, bf16* __restrict__ F1T,
    const float* __restrict__ fc2w, bf16* __restrict__ F2T)
{
    const int id = blockIdx.x;
    const size_t sND = (size_t)N_ * D_;
    if (id < PB_DET) {
        int f = d_detect((const unsigned int*)smask);
        if (threadIdx.x == 0) flag[0] = f;
    } else if (id < PB_QKB) {
        int idx = (id - PB_DET) * 256 + threadIdx.x;
        if (idx < 3072) {
            int h = idx >> 10, rem = idx & 1023, s = rem >> 9, r = rem & 511;
            qkbD[idx] = (s ? kb : qb)[h * 512 + r];
        }
    } else if (id < PB_CW2) {
        int o = id - PB_QKB;
        const float* s = convw + (size_t)o * 3072;
        bf16* dp = CW2 + (size_t)o * 3072;
        for (int q = 0; q < 4; ++q) {
            int i = q * 256 + threadIdx.x;
            float v0 = s[i * 3], v1 = s[i * 3 + 1], v2 = s[i * 3 + 2];
            dp[i] = (bf16)v0; dp[1024 + i] = (bf16)v1; dp[2048 + i] = (bf16)v2;
        }
    } else if (id < PB_ADJ) {
        int t = id - PB_CW2;
        int row = t & 1023, b = t >> 10;
        size_t base = ((size_t)b * N_ + row) * N_;
        float4 v = ((const float4*)(adj + base))[threadIdx.x];
        union { bf16 b[4]; uint2 u; } o;
        o.b[0] = (bf16)v.x; o.b[1] = (bf16)v.y; o.b[2] = (bf16)v.z; o.b[3] = (bf16)v.w;
        ((uint2*)(adjb + base))[threadIdx.x] = o.u;
        float s = blockSum256(v.x + v.y + v.z + v.w);
        if (threadIdx.x == 0) den[b * N_ + row] = s + 1.0f;
    } else if (id < PB_ROWS) {
        int row = id - PB_ADJ;
        int t = threadIdx.x;
        if (t < 192) {
            float4 v = ((const float4*)(inputs + (size_t)row * D_))[t];
            union { bf16 b[4]; uint2 u; } o;
            o.b[0] = (bf16)v.x; o.b[1] = (bf16)v.y; o.b[2] = (bf16)v.z; o.b[3] = (bf16)v.w;
            *(uint2*)(X + (size_t)row * DC_ + t * 4) = o.u;
        }
    } else if (id < PB_INT) {
        int t = id - PB_ROWS;
        int bx = t % 24; int u = t / 24; int by = u % 32; int bz = u / 32;
        d_trcvt(inputs, INT_, N_, D_, N_, D_, sND, sND, 0, bx, by, bz);
    } else if (id < PB_W0) {
        int t = id - PB_INT;
        d_trcvt(W0w, W0T, D_, D_, D_, D_, 0, 0, 0, t % 24, t / 24, 0);
    } else if (id < PB_W1) {
        int t = id - PB_W0;
        d_trcvt(W1w, W1T, DC_, D_, DC_, D_, 0, 0, 0, t % 24, t / 24, 0);
    } else if (id < PB_QW) {
        int t = id - PB_W1;
        d_trcvt(qw, QKWT, DC_, DC_, DC_, DC_, 0, 0, 1, t % 48, t / 48, 0);
    } else if (id < PB_KW) {
        int t = id - PB_QW;
        d_trcvt(kw, QKWT, DC_, DC_, DC_, DC_, 0, 0, 2, t % 48, t / 48, 0);
    } else if (id < PB_LC) {
        int t = id - PB_KW;
        d_trcvt(lincw, LCT, PC_, D_, D_, D_, 0, 0, 0, t % 24, t / 24, 0);
    } else if (id < PB_F1) {
        int t = id - PB_LC;
        d_trcvt(fc1w, F1T, D_, D_, D_, D_, 0, 0, 0, t % 24, t / 24, 0);
    } else if (id < PB_F2) {
        int t = id - PB_F1;
        d_trcvt(fc2w, F2T, D_, D_, D_, D_, 0, 0, 0, t % 24, t / 24, 0);
    } else if (id < PB_CNT) {
        int bh = id - PB_F2;
        int f = d_detect((const unsigned int*)smask);
        float c = 0.f;
        for (int s = 0; s < 4; ++s) {
            int q = s * 256 + threadIdx.x;
            size_t mi = ((size_t)bh * N_ + q) * N_;
            if (!mask_at(smask, f, mi)) c += 1.f;
        }
        c = blockSum256(c);
        if (threadIdx.x == 0) counts[bh] = (int)(c + 0.5f);
    }
}

// ================= remaining support kernels =================

__global__ void k_select_head(const int* __restrict__ counts, int* __restrict__ hsel) {
    if (threadIdx.x != 0 || blockIdx.x != 0) return;
    float p[B_][H_];
    for (int h = 0; h < H_; ++h) {
        float mx = -1e30f;
        for (int b = 0; b < B_; ++b) mx = fmaxf(mx, (float)counts[b * H_ + h]);
        float s = 0.f;
        for (int b = 0; b < B_; ++b) { p[b][h] = expf((float)counts[b * H_ + h] - mx); s += p[b][h]; }
        for (int b = 0; b < B_; ++b) p[b][h] /= s;
    }
    for (int b = 0; b < B_; ++b) {
        int best = 0; float bv = p[b][0];
        for (int h = 1; h < H_; ++h) if (p[b][h] > bv) { bv = p[b][h]; best = h; }
        hsel[b] = best;
    }
}

__global__ __launch_bounds__(256) void k_tr_bf16(const bf16* __restrict__ src,
                                                 bf16* __restrict__ dst) {
    __shared__ bf16 t[32][34];
    int b = blockIdx.z;
    int i0 = blockIdx.y * 32, p0 = blockIdx.x * 32;
    int tx = threadIdx.x & 31, ty = threadIdx.x >> 5;
    const bf16* s = src + (size_t)b * N_ * D_;
    bf16* d = dst + (size_t)b * D_ * N_;
    #pragma unroll
    for (int q = 0; q < 4; ++q)
        t[ty + q * 8][tx] = s[(size_t)(i0 + ty + q * 8) * D_ + p0 + tx];
    __syncthreads();
    #pragma unroll
    for (int q = 0; q < 4; ++q)
        d[(size_t)(p0 + ty + q * 8) * N_ + i0 + tx] = t[tx][ty + q * 8];
}

// softmax + per-row top2 (value,col) + diag/den2 extraction + ax2 diagonal init
__global__ __launch_bounds__(256) void k_softmax(float* __restrict__ Sc,
                                                 const void* __restrict__ smask,
                                                 const int* __restrict__ flagp,
                                                 const int* __restrict__ hsel,
                                                 float4* __restrict__ t2p,
                                                 float* __restrict__ adiag,
                                                 float* __restrict__ den2,
                                                 const bf16* __restrict__ x,
                                                 bf16* __restrict__ ax2) {
    __shared__ float s1[256], s2[256];
    __shared__ int sc1[256], sc2[256];
    __shared__ float sdiag;
    int b = blockIdx.y, row = blockIdx.x;
    int h0 = hsel[b], flag = flagp[0];
    float* rp = Sc + ((size_t)b * N_ + row) * N_;
    float v[4];
    float mx = -INFINITY;
    #pragma unroll
    for (int s = 0; s < 4; ++s) { v[s] = rp[s * 256 + threadIdx.x]; mx = fmaxf(mx, v[s]); }
    mx = blockMax256(mx);
    float sum = 0.f;
    #pragma unroll
    for (int s = 0; s < 4; ++s) { v[s] = expf(v[s] - mx); sum += v[s]; }
    sum = blockSum256(sum);
    size_t ki = (((size_t)b * H_ + h0) * N_ + row) * N_;
    float keep = mask_at(smask, flag, ki) ? 0.f : 1.f;
    float inv = keep / sum;
    float m1 = -INFINITY, m2 = -INFINITY;
    int c1 = 0, c2 = 0;
    #pragma unroll
    for (int s = 0; s < 4; ++s) {
        int col = s * 256 + threadIdx.x;
        float xv = v[s] * inv;
        rp[col] = xv;
        if (col == row) sdiag = xv;
        if (xv > m1) { m2 = m1; c2 = c1; m1 = xv; c1 = col; }
        else if (xv > m2) { m2 = xv; c2 = col; }
    }
    int tid = threadIdx.x;
    s1[tid] = m1; sc1[tid] = c1; s2[tid] = m2; sc2[tid] = c2;
    __syncthreads();
    for (int off = 128; off; off >>= 1) {
        if (tid < off) {
            float a1 = s1[tid], a2 = s2[tid];
            int ac1 = sc1[tid], ac2 = sc2[tid];
            float b1 = s1[tid + off], b2 = s2[tid + off];
            int bc1 = sc1[tid + off], bc2 = sc2[tid + off];
            float n1, n2; int nc1, nc2;
            if (b1 > a1) {
                n1 = b1; nc1 = bc1;
                if (a1 >= b2) { n2 = a1; nc2 = ac1; } else { n2 = b2; nc2 = bc2; }
            } else {
                n1 = a1; nc1 = ac1;
                if (b1 >= a2) { n2 = b1; nc2 = bc1; } else { n2 = a2; nc2 = ac2; }
            }
            s1[tid] = n1; sc1[tid] = nc1; s2[tid] = n2; sc2[tid] = nc2;
        }
        __syncthreads();
    }
    if (tid == 0) {
        float4 o; o.x = s1[0]; o.y = (float)sc1[0]; o.z = s2[0]; o.w = (float)sc2[0];
        t2p[(size_t)b * N_ + row] = o;
        adiag[b * N_ + row] = sdiag;
        den2[b * N_ + row] = sdiag + 1.0f;
    }
    __syncthreads();
    float a = sdiag;
    const bf16* xp = x + ((size_t)b * N_ + row) * DC_;
    bf16* op = ax2 + ((size_t)b * N_ + row) * DC_;
    #pragma unroll
    for (int s = 0; s < 6; ++s) {
        int d = s * 256 + threadIdx.x;
        op[d] = (bf16)(a * (float)xp[d]);
    }
}

// global top-2 threshold + candidate selection from per-row top2 records.
// (global top-2 values are always in the union of per-row top-2 sets)
__global__ __launch_bounds__(256) void k_top2sel(const float4* __restrict__ t2p,
                                                 float* __restrict__ thr,
                                                 int* __restrict__ selcnt,
                                                 int* __restrict__ sel) {
    __shared__ float s1[256], s2[256];
    __shared__ int scnt;
    int b = blockIdx.x, tid = threadIdx.x;
    float m1 = -INFINITY, m2 = -INFINITY;
    for (int s = 0; s < 4; ++s) {
        float4 p = t2p[(size_t)b * N_ + s * 256 + tid];
        float n1 = fmaxf(m1, p.x);
        float n2 = fmaxf(fminf(m1, p.x), fmaxf(m2, p.z));
        m1 = n1; m2 = n2;
    }
    s1[tid] = m1; s2[tid] = m2;
    __syncthreads();
    for (int off = 128; off; off >>= 1) {
        if (tid < off) {
            float a1 = s1[tid], a2 = s2[tid], b1 = s1[tid + off], b2 = s2[tid + off];
            s1[tid] = fmaxf(a1, b1);
            s2[tid] = fmaxf(fminf(a1, b1), fmaxf(a2, b2));
        }
        __syncthreads();
    }
    if (tid == 0) { thr[b] = s2[0]; scnt = 0; }
    __syncthreads();
    float t = s2[0];
    for (int s = 0; s < 4; ++s) {
        int row = s * 256 + tid;
        float4 p = t2p[(size_t)b * N_ + row];
        if (p.x >= t) {
            int pos = atomicAdd(&scnt, 1);
            if (pos < 512) {
                sel[((size_t)b * 512 + pos) * 2]     = row;
                sel[((size_t)b * 512 + pos) * 2 + 1] = (int)p.y;
            }
        }
        if (p.z >= t) {
            int pos = atomicAdd(&scnt, 1);
            if (pos < 512) {
                sel[((size_t)b * 512 + pos) * 2]     = row;
                sel[((size_t)b * 512 + pos) * 2 + 1] = (int)p.w;
            }
        }
    }
    __syncthreads();
    if (tid == 0) selcnt[b] = scnt;
}

__global__ __launch_bounds__(256) void k_ax2_sparse(const float* __restrict__ attn,
                                                    const bf16* __restrict__ x,
                                                    const int* __restrict__ selcnt,
                                                    const int* __restrict__ sel,
                                                    bf16* __restrict__ ax2,
                                                    float* __restrict__ den2) {
    int b = blockIdx.x;
    int cnt = selcnt[b]; if (cnt > 512) cnt = 512;
    __shared__ int si[1024];
    if (threadIdx.x == 0) {
        for (int e = 0; e < cnt; ++e) {
            si[e * 2]     = sel[((size_t)b * 512 + e) * 2];
            si[e * 2 + 1] = sel[((size_t)b * 512 + e) * 2 + 1];
        }
        for (int a = 1; a < cnt; ++a) {
            int ii = si[a * 2], jj = si[a * 2 + 1];
            long long key = (long long)ii * N_ + jj;
            int p = a - 1;
            while (p >= 0 && ((long long)si[p * 2] * N_ + si[p * 2 + 1]) > key) {
                si[(p + 1) * 2] = si[p * 2]; si[(p + 1) * 2 + 1] = si[p * 2 + 1]; --p;
            }
            si[(p + 1) * 2] = ii; si[(p + 1) * 2 + 1] = jj;
        }
    }
    __syncthreads();
    const float* ap = attn + (size_t)b * N_ * N_;
    for (int e = 0; e < cnt; ++e) {
        int i = si[e * 2], j = si[e * 2 + 1];
        if (i == j) continue;
        float aij = ap[(size_t)i * N_ + j];
        float aji = ap[(size_t)j * N_ + i];
        bf16* ri = ax2 + ((size_t)b * N_ + i) * DC_;
        bf16* rj = ax2 + ((size_t)b * N_ + j) * DC_;
        const bf16* xi = x + ((size_t)b * N_ + i) * DC_;
        const bf16* xj = x + ((size_t)b * N_ + j) * DC_;
        for (int s = 0; s < 6; ++s) {
            int d = s * 256 + threadIdx.x;
            ri[d] = (bf16)((float)ri[d] + aij * (float)xj[d]);
            rj[d] = (bf16)((float)rj[d] + aji * (float)xi[d]);
        }
        if (threadIdx.x == 0) {
            den2[b * N_ + i] += aij;
            den2[b * N_ + j] += aji;
        }
        __syncthreads();
    }
}

// ---------------- launch ----------------
extern "C" void kernel_launch(void* const* d_in, const int* in_sizes, int n_in,
                              void* d_out, int out_size, void* d_ws, size_t ws_size,
                              hipStream_t stream) {
    if (n_in < 17) return;
    if (ws_size < WS_NEED) return;

    const float* adj    = (const float*)d_in[0];
    const float* inputs = (const float*)d_in[1];
    const void*  smask  = d_in[2];
    const float* W0w = (const float*)d_in[3];
    const float* W0b = (const float*)d_in[4];
    const float* W1w = (const float*)d_in[5];
    const float* W1b = (const float*)d_in[6];
    const float* qw  = (const float*)d_in[7];
    const float* qb  = (const float*)d_in[8];
    const float* kw  = (const float*)d_in[9];
    const float* kb  = (const float*)d_in[10];
    const float* convw = (const float*)d_in[11];
    const float* convb = (const float*)d_in[12];
    const float* lincw = (const float*)d_in[13];
    const float* lincb = (const float*)d_in[14];
    const float* fc1w  = (const float*)d_in[15];
    const float* fc2w  = (const float*)d_in[16];

    char* W = (char*)d_ws;
    float* out = (float*)d_out;

    float* den    = (float*)(W + O_DEN);
    float* den2   = (float*)(W + O_DEN2);
    float* adiag  = (float*)(W + O_ADIAG);
    float* thr    = (float*)(W + O_THR);
    int*   counts = (int*)(W + O_CNTS);
    int*   hsel   = (int*)(W + O_HSEL);
    int*   selcnt = (int*)(W + O_SELC);
    int*   flag   = (int*)(W + O_FLAG);
    float* qkb    = (float*)(W + O_QKB);
    int*   sel    = (int*)(W + O_SEL);
    float* ATTN   = (float*)(W + O_ATTN);
    float4* t2p4  = (float4*)(W + O_T2P4);
    bf16* X     = (bf16*)(W + O_X);
    bf16* AX2   = (bf16*)(W + O_AX2);
    bf16* QKOUT = (bf16*)(W + O_AX2);
    bf16* ADJB  = (bf16*)(W + O_ADJB);
    bf16* INT_  = (bf16*)(W + O_INT);
    bf16* OUT0T = (bf16*)(W + O_OUT0T);
    bf16* BBA   = (bf16*)(W + O_BBA);
    bf16* BBB   = (bf16*)(W + O_BBB);
    bf16* BBC   = (bf16*)(W + O_BBC);
    bf16* W0T   = (bf16*)(W + O_W0T);
    bf16* W1T   = (bf16*)(W + O_W1T);
    bf16* QKWT  = (bf16*)(W + O_QKWT);
    bf16* CW2   = (bf16*)(W + O_CWB);
    bf16* LCT   = (bf16*)(W + O_LCT);
    bf16* F1T   = (bf16*)(W + O_F1T);
    bf16* F2T   = (bf16*)(W + O_F2T);

    const size_t sND  = (size_t)N_ * D_;
    const size_t sNDC = (size_t)N_ * DC_;
    const size_t sNN  = (size_t)N_ * N_;

    // ---- all prep in one dispatch ----
    k_prep<<<PB_CNT, 256, 0, stream>>>(smask, flag, counts,
        adj, ADJB, den, inputs, X, INT_, convw, CW2,
        qb, kb, qkb, W0w, W0T, W1w, W1T, qw, kw, QKWT,
        lincw, LCT, fc1w, F1T, fc2w, F2T);
    k_select_head<<<1, 64, 0, stream>>>(counts, hsel);

    // ---- GCN layer 0: xW0 and Ax jammed in one dispatch (independent) ----
    mmJam<<<dim3(6, 16, 16), 256, 0, stream>>>(
        X, sNDC, DC_, W0T, 0, D_, W0b, BBA, sND, D_, D_,
        ADJB, sNN, N_, INT_, sND, N_, BBB, sND, D_, N_);
    mm<1><<<dim3(6, 16, B_), 256, 0, stream>>>(BBB, sND, D_, W0T, 0, D_, nullptr, 0,
        W0b, BBA, D_, den, nullptr, nullptr, BBC, nullptr, sND, D_, N_, D_, D_,
        nullptr, nullptr, nullptr, 0, 0);
    k_tr_bf16<<<dim3(24, 32, B_), 256, 0, stream>>>(BBC, OUT0T);
    mm<5><<<dim3(6, 16, B_), 256, 0, stream>>>(CW2, 0, 3072, OUT0T, sND, N_, nullptr, 0,
        convb, nullptr, 0, nullptr, nullptr, nullptr, BBB, nullptr, sND, D_, N_, D_, 3072,
        nullptr, nullptr, nullptr, 0, 0);
    mm<0><<<dim3(6, 16, B_), 256, 0, stream>>>(BBB, sND, D_, LCT, 0, D_, nullptr, 0,
        lincb, nullptr, 0, nullptr, nullptr, nullptr, X + D_, nullptr, sNDC, DC_, N_, D_, D_,
        nullptr, nullptr, nullptr, 0, 0);

    // ---- merged Q|K projection + xW1 (EPI 7, 128x128 tiles): N = 1792, grid 896 ----
    mm2<7><<<dim3(14, 8, B_), 256, 0, stream>>>(X, sNDC, DC_, QKWT, 0, DC_, hsel, 1024,
        qkb, nullptr, 0, nullptr, nullptr, nullptr, QKOUT, nullptr, sNN, N_, N_, 1792, DC_,
        W1T, W1b, BBA, sND, D_);

    // ---- scores (fp32, masked; 128x128 tiles): grid 512 = 2/CU balanced ----
    mm2<4><<<dim3(8, 8, B_), 256, 0, stream>>>(QKOUT, sNN, N_, QKOUT + 512, sNN, N_, hsel, 0,
        nullptr, nullptr, 0, nullptr, smask, flag, nullptr, ATTN, sNN, N_, N_, N_, DK_,
        nullptr, nullptr, nullptr, 0, 0);

    // ---- softmax (+row top2 with cols, diag/den2, ax2 diag init) ----
    k_softmax<<<dim3(N_, B_), 256, 0, stream>>>(ATTN, smask, flag, hsel, t2p4,
                                                adiag, den2, X, AX2);

    // ---- top-2 threshold + candidate selection (no ATTN rescan) ----
    k_top2sel<<<B_, 256, 0, stream>>>(t2p4, thr, selcnt, sel);
    k_ax2_sparse<<<B_, 256, 0, stream>>>(ATTN, X, selcnt, sel, AX2, den2);

    // ---- GCN layer 1 (xW1 already in BBA from merged GEMM) ----
    mm<1><<<dim3(6, 16, B_), 256, 0, stream>>>(AX2, sNDC, DC_, W1T, 0, DC_, nullptr, 0,
        W1b, BBA, D_, den2, nullptr, nullptr, BBB, nullptr, sND, D_, N_, D_, DC_,
        nullptr, nullptr, nullptr, 0, 0);

    // ---- fc ----
    mm<2><<<dim3(6, 16, B_), 256, 0, stream>>>(BBB, sND, D_, F1T, 0, D_, nullptr, 0,
        nullptr, nullptr, 0, nullptr, nullptr, nullptr, BBC, nullptr, sND, D_, N_, D_, D_,
        nullptr, nullptr, nullptr, 0, 0);
    mm<3><<<dim3(6, 16, B_), 256, 0, stream>>>(BBC, sND, D_, F2T, 0, D_, nullptr, 0,
        nullptr, nullptr, 0, nullptr, nullptr, nullptr, nullptr, out, sND, D_, N_, D_, D_,
        nullptr, nullptr, nullptr, 0, 0);
}

// Round 15
// 387.156 us; speedup vs baseline: 1.4788x; 1.0078x over previous
//
#include <hip/hip_runtime.h>
#include <cstdint>
#include <cstddef>

typedef __bf16 bf16;
typedef __bf16 bf16x8 __attribute__((ext_vector_type(8)));
typedef float f32x4 __attribute__((ext_vector_type(4)));

#define B_ 8
#define N_ 1024
#define D_ 768
#define H_ 3
#define DC_ 1536
#define DK_ 512
#define PC_ 766
#define MB_ (1024ull*1024ull)

// ---------------- workspace layout (byte offsets) ----------------
static const size_t O_DEN   = 0;
static const size_t O_DEN2  = 32768;
static const size_t O_ADIAG = 65536;
static const size_t O_THR   = 163840;
static const size_t O_CNTS  = 164096;
static const size_t O_HSEL  = 164352;
static const size_t O_SELC  = 164608;
static const size_t O_FLAG  = 164864;
static const size_t O_QKB   = 165120;
static const size_t O_SEL   = 180224;
static const size_t O_ATTN  = 262144;            // f32 [8,1024,1024] 32MB
static const size_t O_X     = O_ATTN + 32*MB_;   // bf16 [8,1024,1536] 24MB
static const size_t O_AX2   = O_X    + 24*MB_;   // bf16 [8,1024,1536] 24MB (QK out overlays early)
static const size_t O_ADJB  = O_AX2  + 24*MB_;   // bf16 [8,1024,1024] 16MB
static const size_t O_INT   = O_ADJB + 16*MB_;   // bf16 [8,768,1024] inputs^T -> OUT0T (12MB)
static const size_t O_BBA   = O_INT  + 12*MB_;
static const size_t O_BBB   = O_BBA  + 12*MB_;
static const size_t O_BBC   = O_BBB  + 12*MB_;   // [T2P4 during attention phase] -> fc1out
static const size_t O_W0T   = O_BBC  + 12*MB_;   // [768][768]
static const size_t O_W1T   = O_W0T + 1179648;   // [768][1536]
static const size_t O_QKWT  = O_W1T + 2359296;   // [3072][1536]
static const size_t O_CWB   = O_QKWT + 9437184;  // CW2 [1024][3072]
static const size_t O_LCT   = O_CWB + 6291456;
static const size_t O_F1T   = O_LCT + 1179648;
static const size_t O_F2T   = O_F1T + 1179648;
static const size_t WS_NEED = O_F2T + 1179648;
static const size_t O_OUT0T = O_INT;
// t2p float4[8*1024] (128KB) overlays BBC head (dead until fc1 writes it).
static const size_t O_T2P4  = O_BBC;

// ---------------- helpers ----------------
__device__ __forceinline__ bool mask_at(const void* p, int flag, size_t i) {
    switch (flag) {
        case 1:  return ((const int*)p)[i] != 0;
        case 2:  return ((const float*)p)[i] != 0.0f;
        case 3:  return ((const long long*)p)[i] != 0;
        default: return ((const unsigned char*)p)[i] != 0;
    }
}

__device__ __forceinline__ void gload16(const void* g, void* l) {
    __builtin_amdgcn_global_load_lds(
        (const __attribute__((address_space(1))) void*)g,
        (__attribute__((address_space(3))) void*)l, 16, 0, 0);
}

__device__ inline float blockMax256(float v) {
    __shared__ float red[4];
    for (int off = 32; off; off >>= 1) v = fmaxf(v, __shfl_xor(v, off));
    int lane = threadIdx.x & 63, wid = threadIdx.x >> 6;
    if (lane == 0) red[wid] = v;
    __syncthreads();
    v = fmaxf(fmaxf(red[0], red[1]), fmaxf(red[2], red[3]));
    __syncthreads();
    return v;
}

__device__ inline float blockSum256(float v) {
    __shared__ float red[4];
    for (int off = 32; off; off >>= 1) v += __shfl_xor(v, off);
    int lane = threadIdx.x & 63, wid = threadIdx.x >> 6;
    if (lane == 0) red[wid] = v;
    __syncthreads();
    v = red[0] + red[1] + red[2] + red[3];
    __syncthreads();
    return v;
}

// shared epilogue (scalar variants)
template<int EPI>
__device__ __forceinline__ void epi_store(
    float v, int b, int m, int n, int M,
    const int boff, const float* __restrict__ bias,
    const bf16* __restrict__ Dadd, int ldd,
    const float* __restrict__ denv,
    const void* __restrict__ smask, int flag, int h0,
    bf16* __restrict__ Cb, float* __restrict__ Cf, size_t sC, int ldc,
    const float* __restrict__ bias2, bf16* __restrict__ Cb2, size_t sC2, int ldc2)
{
    size_t oidx = (size_t)b * sC + (size_t)m * ldc + n;
    if (EPI == 0) {
        Cb[oidx] = (bf16)(v + bias[boff + n]);
    } else if (EPI == 1) {
        v = fmaxf((v + bias[n]) / denv[(size_t)b * M + m], 0.f)
            + (float)Dadd[((size_t)b * M + m) * ldd + n];
        Cb[oidx] = (bf16)v;
    } else if (EPI == 2) {
        Cb[oidx] = (bf16)fmaxf(v, 0.f);
    } else if (EPI == 3) {
        Cf[oidx] = v;
    } else if (EPI == 4) {
        size_t mi = (((size_t)b * H_ + h0) * N_ + m) * N_ + n;
        Cf[oidx] = mask_at(smask, flag, mi) ? -1e9f : v * 0.04419417382415922f;
    } else if (EPI == 5) {
        Cb[oidx] = (n < PC_) ? (bf16)fmaxf(v + bias[m], 0.f) : (bf16)0.f;
    } else if (EPI == 7) {
        if (n < 1024)
            Cb[(size_t)b * sC + (size_t)m * ldc + n] = (bf16)(v + bias[boff + n]);
        else
            Cb2[(size_t)b * sC2 + (size_t)m * ldc2 + (n - 1024)] = (bf16)(v + bias2[n - 1024]);
    } else {
        Cb[oidx] = (bf16)v;
    }
}

// ================= bf16 MFMA NT GEMM (64x128 tile) =================
// R10 geometry: 4 waves (each 32x64), BK=64, 2-phase dbuf, counted vmcnt(6),
// raw s_barrier pairs, conflict-free 8-chunk XOR swizzle.
// EPI 8: GCN epilogue (relu((acc+bias[n])/den)+Dadd) stored TRANSPOSED:
//        Cb[b][n][m] with ldc = transposed leading dim; 4 consecutive m per
//        fragment -> one aligned 8B store per (i,j). Replaces out0 + k_tr_bf16.
template<int EPI>
__global__ __launch_bounds__(256) void mm(
    const bf16* __restrict__ A, size_t sA, int lda,
    const bf16* __restrict__ Bt, size_t sB, int ldb,
    const int* __restrict__ rowIdx, int rowMul,
    const float* __restrict__ bias,
    const bf16* __restrict__ Dadd, int ldd,
    const float* __restrict__ denv,
    const void* __restrict__ smask, const int* __restrict__ flagp,
    bf16* __restrict__ Cb, float* __restrict__ Cf, size_t sC, int ldc,
    int M, int N, int K,
    const bf16* __restrict__ Bt2, const float* __restrict__ bias2,
    bf16* __restrict__ Cb2, size_t sC2, int ldc2)
{
    __shared__ __align__(16) bf16 As[2][64 * 64];
    __shared__ __align__(16) bf16 Bs[2][128 * 64];

    const int gx = gridDim.x, gy = gridDim.y;
    const int nwg = gx * gy * (int)gridDim.z;
    int lin = ((int)blockIdx.z * gy + (int)blockIdx.y) * gx + (int)blockIdx.x;
    int cpx = nwg >> 3;
    int swz = (lin & 7) * cpx + (lin >> 3);
    int ty = swz % gy;
    int tt = swz / gy;
    int tx = tt % gx;
    int b  = tt / gx;

    const int bm = ty * 64, bn = tx * 128;
    const int tid = threadIdx.x;
    const int lane = tid & 63, w = tid >> 6;
    const int wr = w >> 1, wc = w & 1;
    const int boff = rowIdx ? rowIdx[b] * rowMul : 0;

    const bf16* Ab = A + (size_t)b * sA;
    const bf16* Bb = Bt + (size_t)b * sB;

    const bf16* Bsrc = Bb;
    int bRow0 = boff + bn;
    if (EPI == 7 && bn >= 1024) { Bsrc = Bt2; bRow0 = bn - 1024; }

    const int sr = lane >> 3;
    const int gk = ((lane & 7) ^ (lane >> 3)) * 8;

    f32x4 zero = {0.f, 0.f, 0.f, 0.f};
    f32x4 acc[2][4];
    #pragma unroll
    for (int i = 0; i < 2; ++i)
        #pragma unroll
        for (int j = 0; j < 4; ++j) acc[i][j] = zero;

    #pragma unroll
    for (int q = 0; q < 2; ++q)
        gload16((const void*)(Ab + (size_t)(bm + w * 16 + q * 8 + sr) * lda + gk),
                (void*)(As[0] + (w * 16 + q * 8) * 64));
    #pragma unroll
    for (int q = 0; q < 4; ++q)
        gload16((const void*)(Bsrc + (size_t)(bRow0 + w * 32 + q * 8 + sr) * ldb + gk),
                (void*)(Bs[0] + (w * 32 + q * 8) * 64));

    const int rl = lane & 15;
    const int g8 = lane >> 4;
    const int rx = lane & 7;

    int cur = 0;
    for (int k0 = 0; k0 < K; k0 += 64) {
        int nxt = cur ^ 1;
        if (k0 + 64 < K) {
            #pragma unroll
            for (int q = 0; q < 2; ++q)
                gload16((const void*)(Ab + (size_t)(bm + w * 16 + q * 8 + sr) * lda + k0 + 64 + gk),
                        (void*)(As[nxt] + (w * 16 + q * 8) * 64));
            #pragma unroll
            for (int q = 0; q < 4; ++q)
                gload16((const void*)(Bsrc + (size_t)(bRow0 + w * 32 + q * 8 + sr) * ldb + k0 + 64 + gk),
                        (void*)(Bs[nxt] + (w * 32 + q * 8) * 64));
            asm volatile("s_waitcnt vmcnt(6)" ::: "memory");
        } else {
            asm volatile("s_waitcnt vmcnt(0)" ::: "memory");
        }
        __builtin_amdgcn_s_barrier();
        __builtin_amdgcn_sched_barrier(0);

        bf16x8 af[2][2], bfv[4][2];
        #pragma unroll
        for (int ks = 0; ks < 2; ++ks) {
            int e = ks * 4 + g8;
            #pragma unroll
            for (int i = 0; i < 2; ++i)
                af[i][ks] = *(const bf16x8*)(As[cur] + (wr * 32 + i * 16 + rl) * 64 + (e ^ rx) * 8);
            #pragma unroll
            for (int j = 0; j < 4; ++j)
                bfv[j][ks] = *(const bf16x8*)(Bs[cur] + (wc * 64 + j * 16 + rl) * 64 + (e ^ rx) * 8);
        }
        #pragma unroll
        for (int ks = 0; ks < 2; ++ks)
            #pragma unroll
            for (int i = 0; i < 2; ++i)
                #pragma unroll
                for (int j = 0; j < 4; ++j)
                    acc[i][j] = __builtin_amdgcn_mfma_f32_16x16x32_bf16(af[i][ks], bfv[j][ks], acc[i][j], 0, 0, 0);

        __builtin_amdgcn_s_barrier();
        __builtin_amdgcn_sched_barrier(0);
        cur = nxt;
    }

    const int r0 = (lane >> 4) * 4, c0 = lane & 15;
    int flag = 0, h0 = 0;
    if (EPI == 4) { flag = flagp[0]; h0 = rowIdx[b]; }
    if (EPI == 8) {
        // transposed GCN store: one 8B store per fragment
        #pragma unroll
        for (int i = 0; i < 2; ++i) {
            int m0 = bm + wr * 32 + i * 16 + r0;
            #pragma unroll
            for (int j = 0; j < 4; ++j) {
                int n = bn + wc * 64 + j * 16 + c0;
                union { bf16 h[4]; uint2 u; } o;
                #pragma unroll
                for (int r = 0; r < 4; ++r) {
                    int m = m0 + r;
                    float v = fmaxf((acc[i][j][r] + bias[n]) / denv[(size_t)b * M + m], 0.f)
                              + (float)Dadd[((size_t)b * M + m) * ldd + n];
                    o.h[r] = (bf16)v;
                }
                *(uint2*)&Cb[(size_t)b * sC + (size_t)n * ldc + m0] = o.u;
            }
        }
        return;
    }
    #pragma unroll
    for (int i = 0; i < 2; ++i)
        #pragma unroll
        for (int r = 0; r < 4; ++r) {
            int m = bm + wr * 32 + i * 16 + r0 + r;
            #pragma unroll
            for (int j = 0; j < 4; ++j) {
                int n = bn + wc * 64 + j * 16 + c0;
                epi_store<EPI>(acc[i][j][r], b, m, n, M, boff, bias, Dadd, ldd, denv,
                               smask, flag, h0, Cb, Cf, sC, ldc, bias2, Cb2, sC2, ldc2);
            }
        }
}

// ================= jammed pair of independent GEMMs (64x128 tile) =================
__global__ __launch_bounds__(256) void mmJam(
    const bf16* __restrict__ A0, size_t sA0, int lda0,
    const bf16* __restrict__ B0t, size_t sB0, int ldb0,
    const float* __restrict__ bias0,
    bf16* __restrict__ C0, size_t sC0, int ldc0, int K0,
    const bf16* __restrict__ A1, size_t sA1, int lda1,
    const bf16* __restrict__ B1t, size_t sB1, int ldb1,
    bf16* __restrict__ C1, size_t sC1, int ldc1, int K1)
{
    __shared__ __align__(16) bf16 As[2][64 * 64];
    __shared__ __align__(16) bf16 Bs[2][128 * 64];

    const int gx = gridDim.x, gy = gridDim.y;   // gz = 16 (2 jobs x 8 batches)
    const int nwg = gx * gy * (int)gridDim.z;
    int lin = ((int)blockIdx.z * gy + (int)blockIdx.y) * gx + (int)blockIdx.x;
    int cpx = nwg >> 3;
    int swz = (lin & 7) * cpx + (lin >> 3);
    int ty = swz % gy;
    int tt = swz / gy;
    int tx = tt % gx;
    int zz = tt / gx;
    int job = zz >> 3;
    int b   = zz & 7;

    const bf16* A  = job ? A1 : A0;
    const bf16* Bt = job ? B1t : B0t;
    bf16* C        = job ? C1 : C0;
    const size_t sA = job ? sA1 : sA0;
    const size_t sB = job ? sB1 : sB0;
    const size_t sC = job ? sC1 : sC0;
    const int lda = job ? lda1 : lda0;
    const int ldb = job ? ldb1 : ldb0;
    const int ldc = job ? ldc1 : ldc0;
    const int K   = job ? K1 : K0;

    const int bm = ty * 64, bn = tx * 128;
    const int tid = threadIdx.x;
    const int lane = tid & 63, w = tid >> 6;
    const int wr = w >> 1, wc = w & 1;

    const bf16* Ab = A + (size_t)b * sA;
    const bf16* Bb = Bt + (size_t)b * sB;

    const int sr = lane >> 3;
    const int gk = ((lane & 7) ^ (lane >> 3)) * 8;

    f32x4 zero = {0.f, 0.f, 0.f, 0.f};
    f32x4 acc[2][4];
    #pragma unroll
    for (int i = 0; i < 2; ++i)
        #pragma unroll
        for (int j = 0; j < 4; ++j) acc[i][j] = zero;

    #pragma unroll
    for (int q = 0; q < 2; ++q)
        gload16((const void*)(Ab + (size_t)(bm + w * 16 + q * 8 + sr) * lda + gk),
                (void*)(As[0] + (w * 16 + q * 8) * 64));
    #pragma unroll
    for (int q = 0; q < 4; ++q)
        gload16((const void*)(Bb + (size_t)(bn + w * 32 + q * 8 + sr) * ldb + gk),
                (void*)(Bs[0] + (w * 32 + q * 8) * 64));

    const int rl = lane & 15;
    const int g8 = lane >> 4;
    const int rx = lane & 7;

    int cur = 0;
    for (int k0 = 0; k0 < K; k0 += 64) {
        int nxt = cur ^ 1;
        if (k0 + 64 < K) {
            #pragma unroll
            for (int q = 0; q < 2; ++q)
                gload16((const void*)(Ab + (size_t)(bm + w * 16 + q * 8 + sr) * lda + k0 + 64 + gk),
                        (void*)(As[nxt] + (w * 16 + q * 8) * 64));
            #pragma unroll
            for (int q = 0; q < 4; ++q)
                gload16((const void*)(Bb + (size_t)(bn + w * 32 + q * 8 + sr) * ldb + k0 + 64 + gk),
                        (void*)(Bs[nxt] + (w * 32 + q * 8) * 64));
            asm volatile("s_waitcnt vmcnt(6)" ::: "memory");
        } else {
            asm volatile("s_waitcnt vmcnt(0)" ::: "memory");
        }
        __builtin_amdgcn_s_barrier();
        __builtin_amdgcn_sched_barrier(0);

        bf16x8 af[2][2], bfv[4][2];
        #pragma unroll
        for (int ks = 0; ks < 2; ++ks) {
            int e = ks * 4 + g8;
            #pragma unroll
            for (int i = 0; i < 2; ++i)
                af[i][ks] = *(const bf16x8*)(As[cur] + (wr * 32 + i * 16 + rl) * 64 + (e ^ rx) * 8);
            #pragma unroll
            for (int j = 0; j < 4; ++j)
                bfv[j][ks] = *(const bf16x8*)(Bs[cur] + (wc * 64 + j * 16 + rl) * 64 + (e ^ rx) * 8);
        }
        #pragma unroll
        for (int ks = 0; ks < 2; ++ks)
            #pragma unroll
            for (int i = 0; i < 2; ++i)
                #pragma unroll
                for (int j = 0; j < 4; ++j)
                    acc[i][j] = __builtin_amdgcn_mfma_f32_16x16x32_bf16(af[i][ks], bfv[j][ks], acc[i][j], 0, 0, 0);

        __builtin_amdgcn_s_barrier();
        __builtin_amdgcn_sched_barrier(0);
        cur = nxt;
    }

    const int r0 = (lane >> 4) * 4, c0 = lane & 15;
    #pragma unroll
    for (int i = 0; i < 2; ++i)
        #pragma unroll
        for (int r = 0; r < 4; ++r) {
            int m = bm + wr * 32 + i * 16 + r0 + r;
            #pragma unroll
            for (int j = 0; j < 4; ++j) {
                int n = bn + wc * 64 + j * 16 + c0;
                float v = acc[i][j][r];
                if (job == 0) v += bias0[n];
                C[(size_t)b * sC + (size_t)m * ldc + n] = (bf16)v;
            }
        }
}

// ================= bf16 MFMA NT GEMM (128x128 tile) =================
template<int EPI>
__global__ __launch_bounds__(256) void mm2(
    const bf16* __restrict__ A, size_t sA, int lda,
    const bf16* __restrict__ Bt, size_t sB, int ldb,
    const int* __restrict__ rowIdx, int rowMul,
    const float* __restrict__ bias,
    const bf16* __restrict__ Dadd, int ldd,
    const float* __restrict__ denv,
    const void* __restrict__ smask, const int* __restrict__ flagp,
    bf16* __restrict__ Cb, float* __restrict__ Cf, size_t sC, int ldc,
    int M, int N, int K,
    const bf16* __restrict__ Bt2, const float* __restrict__ bias2,
    bf16* __restrict__ Cb2, size_t sC2, int ldc2)
{
    __shared__ __align__(16) bf16 As[2][128 * 64];
    __shared__ __align__(16) bf16 Bs[2][128 * 64];

    const int gx = gridDim.x, gy = gridDim.y;
    const int nwg = gx * gy * (int)gridDim.z;
    int lin = ((int)blockIdx.z * gy + (int)blockIdx.y) * gx + (int)blockIdx.x;
    int cpx = nwg >> 3;
    int swz = (lin & 7) * cpx + (lin >> 3);
    int ty = swz % gy;
    int tt = swz / gy;
    int tx = tt % gx;
    int b  = tt / gx;

    const int bm = ty * 128, bn = tx * 128;
    const int tid = threadIdx.x;
    const int lane = tid & 63, w = tid >> 6;
    const int wr = w >> 1, wc = w & 1;
    const int boff = rowIdx ? rowIdx[b] * rowMul : 0;

    const bf16* Ab = A + (size_t)b * sA;
    const bf16* Bb = Bt + (size_t)b * sB;

    const bf16* Bsrc = Bb;
    int bRow0 = boff + bn;
    if (EPI == 7 && bn >= 1024) { Bsrc = Bt2; bRow0 = bn - 1024; }

    const int sr = lane >> 3;
    const int gk = ((lane & 7) ^ (lane >> 3)) * 8;

    f32x4 zero = {0.f, 0.f, 0.f, 0.f};
    f32x4 acc[4][4];
    #pragma unroll
    for (int i = 0; i < 4; ++i)
        #pragma unroll
        for (int j = 0; j < 4; ++j) acc[i][j] = zero;

    #pragma unroll
    for (int q = 0; q < 4; ++q)
        gload16((const void*)(Ab + (size_t)(bm + w * 32 + q * 8 + sr) * lda + gk),
                (void*)(As[0] + (w * 32 + q * 8) * 64));
    #pragma unroll
    for (int q = 0; q < 4; ++q)
        gload16((const void*)(Bsrc + (size_t)(bRow0 + w * 32 + q * 8 + sr) * ldb + gk),
                (void*)(Bs[0] + (w * 32 + q * 8) * 64));

    const int rl = lane & 15;
    const int g8 = lane >> 4;
    const int rx = lane & 7;

    int cur = 0;
    for (int k0 = 0; k0 < K; k0 += 64) {
        int nxt = cur ^ 1;
        if (k0 + 64 < K) {
            #pragma unroll
            for (int q = 0; q < 4; ++q)
                gload16((const void*)(Ab + (size_t)(bm + w * 32 + q * 8 + sr) * lda + k0 + 64 + gk),
                        (void*)(As[nxt] + (w * 32 + q * 8) * 64));
            #pragma unroll
            for (int q = 0; q < 4; ++q)
                gload16((const void*)(Bsrc + (size_t)(bRow0 + w * 32 + q * 8 + sr) * ldb + k0 + 64 + gk),
                        (void*)(Bs[nxt] + (w * 32 + q * 8) * 64));
            asm volatile("s_waitcnt vmcnt(8)" ::: "memory");
        } else {
            asm volatile("s_waitcnt vmcnt(0)" ::: "memory");
        }
        __builtin_amdgcn_s_barrier();
        __builtin_amdgcn_sched_barrier(0);

        #pragma unroll
        for (int ks = 0; ks < 2; ++ks) {
            int e = ks * 4 + g8;
            bf16x8 af[4], bfv[4];
            #pragma unroll
            for (int i = 0; i < 4; ++i)
                af[i] = *(const bf16x8*)(As[cur] + (wr * 64 + i * 16 + rl) * 64 + (e ^ rx) * 8);
            #pragma unroll
            for (int j = 0; j < 4; ++j)
                bfv[j] = *(const bf16x8*)(Bs[cur] + (wc * 64 + j * 16 + rl) * 64 + (e ^ rx) * 8);
            #pragma unroll
            for (int i = 0; i < 4; ++i)
                #pragma unroll
                for (int j = 0; j < 4; ++j)
                    acc[i][j] = __builtin_amdgcn_mfma_f32_16x16x32_bf16(af[i], bfv[j], acc[i][j], 0, 0, 0);
        }

        __builtin_amdgcn_s_barrier();
        __builtin_amdgcn_sched_barrier(0);
        cur = nxt;
    }

    const int r0 = (lane >> 4) * 4, c0 = lane & 15;
    int flag = 0, h0 = 0;
    if (EPI == 4) { flag = flagp[0]; h0 = rowIdx[b]; }
    #pragma unroll
    for (int i = 0; i < 4; ++i)
        #pragma unroll
        for (int r = 0; r < 4; ++r) {
            int m = bm + wr * 64 + i * 16 + r0 + r;
            #pragma unroll
            for (int j = 0; j < 4; ++j) {
                int n = bn + wc * 64 + j * 16 + c0;
                epi_store<EPI>(acc[i][j][r], b, m, n, M, boff, bias, Dadd, ldd, denv,
                               smask, flag, h0, Cb, Cf, sC, ldc, bias2, Cb2, sC2, ldc2);
            }
        }
}

// ================= prep device functions =================

__device__ int d_detect(const unsigned int* __restrict__ sm) {
    __shared__ int sGt1, sF32, sOddNZ, sFlag;
    if (threadIdx.x == 0) { sGt1 = 0; sF32 = 0; sOddNZ = 0; }
    __syncthreads();
    int gt1 = 0, f32c = 0, oddnz = 0;
    for (int s = 0; s < 16; ++s) {
        int idx = s * 256 + threadIdx.x;
        unsigned wv = sm[idx];
        if (wv > 1u) gt1 = 1;
        if (wv == 0x3F800000u) f32c++;
        if ((idx & 1) && wv != 0u) oddnz = 1;
    }
    if (gt1)   atomicOr(&sGt1, 1);
    if (f32c)  atomicAdd(&sF32, f32c);
    if (oddnz) atomicOr(&sOddNZ, 1);
    __syncthreads();
    if (threadIdx.x == 0) {
        int f;
        if (sF32 > 512) f = 2;
        else if (!sGt1) f = sOddNZ ? 1 : 3;
        else f = 0;
        sFlag = f;
    }
    __syncthreads();
    return sFlag;
}

__device__ void d_trcvt(const float* __restrict__ src, bf16* __restrict__ dst,
                        int R, int C, int Rpad, int Cpad,
                        size_t sSrc, size_t sDst, int mode, int bx, int by, int bz) {
    __shared__ float t[32][33];
    int r0 = by * 32, c0 = bx * 32;
    int tx = threadIdx.x & 31, ty = threadIdx.x >> 5;
    const float* s = src + (size_t)bz * sSrc;
    bf16* d = dst + (size_t)bz * sDst;
    #pragma unroll
    for (int q = 0; q < 4; ++q) {
        int r = r0 + ty + q * 8, c = c0 + tx;
        t[ty + q * 8][tx] = (r < R && c < C) ? s[(size_t)r * C + c] : 0.f;
    }
    __syncthreads();
    #pragma unroll
    for (int q = 0; q < 4; ++q) {
        int dr = c0 + ty + q * 8, dc = r0 + tx;
        if (dr < Cpad && dc < Rpad) {
            int drm = dr;
            if (mode == 1) drm = (dr >> 9) * 1024 + (dr & 511);
            else if (mode == 2) drm = (dr >> 9) * 1024 + 512 + (dr & 511);
            d[(size_t)drm * Rpad + dc] = (bf16)t[tx][ty + q * 8];
        }
    }
}

// job boundaries (flat z)
#define PB_DET   1
#define PB_QKB   13
#define PB_CW2   1037
#define PB_ADJ   9229
#define PB_ROWS  17421
#define PB_INT   23565
#define PB_W0    24141
#define PB_W1    25293
#define PB_QW    27597
#define PB_KW    29901
#define PB_LC    30477
#define PB_F1    31053
#define PB_F2    31629
#define PB_CNT   31653

__global__ __launch_bounds__(256) void k_prep(
    const void* __restrict__ smask, int* __restrict__ flag, int* __restrict__ counts,
    const float* __restrict__ adj, bf16* __restrict__ adjb, float* __restrict__ den,
    const float* __restrict__ inputs, bf16* __restrict__ X, bf16* __restrict__ INT_,
    const float* __restrict__ convw, bf16* __restrict__ CW2,
    const float* __restrict__ qb, const float* __restrict__ kb, float* __restrict__ qkbD,
    const float* __restrict__ W0w, bf16* __restrict__ W0T,
    const float* __restrict__ W1w, bf16* __restrict__ W1T,
    const float* __restrict__ qw, const float* __restrict__ kw, bf16* __restrict__ QKWT,
    const float* __restrict__ lincw, bf16* __restrict__ LCT,
    const float* __restrict__ fc1w, bf16* __restrict__ F1T,
    const float* __restrict__ fc2w, bf16* __restrict__ F2T)
{
    const int id = blockIdx.x;
    const size_t sND = (size_t)N_ * D_;
    if (id < PB_DET) {
        int f = d_detect((const unsigned int*)smask);
        if (threadIdx.x == 0) flag[0] = f;
    } else if (id < PB_QKB) {
        int idx = (id - PB_DET) * 256 + threadIdx.x;
        if (idx < 3072) {
            int h = idx >> 10, rem = idx & 1023, s = rem >> 9, r = rem & 511;
            qkbD[idx] = (s ? kb : qb)[h * 512 + r];
        }
    } else if (id < PB_CW2) {
        int o = id - PB_QKB;
        const float* s = convw + (size_t)o * 3072;
        bf16* dp = CW2 + (size_t)o * 3072;
        for (int q = 0; q < 4; ++q) {
            int i = q * 256 + threadIdx.x;
            float v0 = s[i * 3], v1 = s[i * 3 + 1], v2 = s[i * 3 + 2];
            dp[i] = (bf16)v0; dp[1024 + i] = (bf16)v1; dp[2048 + i] = (bf16)v2;
        }
    } else if (id < PB_ADJ) {
        int t = id - PB_CW2;
        int row = t & 1023, b = t >> 10;
        size_t base = ((size_t)b * N_ + row) * N_;
        float4 v = ((const float4*)(adj + base))[threadIdx.x];
        union { bf16 b[4]; uint2 u; } o;
        o.b[0] = (bf16)v.x; o.b[1] = (bf16)v.y; o.b[2] = (bf16)v.z; o.b[3] = (bf16)v.w;
        ((uint2*)(adjb + base))[threadIdx.x] = o.u;
        float s = blockSum256(v.x + v.y + v.z + v.w);
        if (threadIdx.x == 0) den[b * N_ + row] = s + 1.0f;
    } else if (id < PB_ROWS) {
        int row = id - PB_ADJ;
        int t = threadIdx.x;
        if (t < 192) {
            float4 v = ((const float4*)(inputs + (size_t)row * D_))[t];
            union { bf16 b[4]; uint2 u; } o;
            o.b[0] = (bf16)v.x; o.b[1] = (bf16)v.y; o.b[2] = (bf16)v.z; o.b[3] = (bf16)v.w;
            *(uint2*)(X + (size_t)row * DC_ + t * 4) = o.u;
        }
    } else if (id < PB_INT) {
        int t = id - PB_ROWS;
        int bx = t % 24; int u = t / 24; int by = u % 32; int bz = u / 32;
        d_trcvt(inputs, INT_, N_, D_, N_, D_, sND, sND, 0, bx, by, bz);
    } else if (id < PB_W0) {
        int t = id - PB_INT;
        d_trcvt(W0w, W0T, D_, D_, D_, D_, 0, 0, 0, t % 24, t / 24, 0);
    } else if (id < PB_W1) {
        int t = id - PB_W0;
        d_trcvt(W1w, W1T, DC_, D_, DC_, D_, 0, 0, 0, t % 24, t / 24, 0);
    } else if (id < PB_QW) {
        int t = id - PB_W1;
        d_trcvt(qw, QKWT, DC_, DC_, DC_, DC_, 0, 0, 1, t % 48, t / 48, 0);
    } else if (id < PB_KW) {
        int t = id - PB_QW;
        d_trcvt(kw, QKWT, DC_, DC_, DC_, DC_, 0, 0, 2, t % 48, t / 48, 0);
    } else if (id < PB_LC) {
        int t = id - PB_KW;
        d_trcvt(lincw, LCT, PC_, D_, D_, D_, 0, 0, 0, t % 24, t / 24, 0);
    } else if (id < PB_F1) {
        int t = id - PB_LC;
        d_trcvt(fc1w, F1T, D_, D_, D_, D_, 0, 0, 0, t % 24, t / 24, 0);
    } else if (id < PB_F2) {
        int t = id - PB_F1;
        d_trcvt(fc2w, F2T, D_, D_, D_, D_, 0, 0, 0, t % 24, t / 24, 0);
    } else if (id < PB_CNT) {
        int bh = id - PB_F2;
        int f = d_detect((const unsigned int*)smask);
        float c = 0.f;
        for (int s = 0; s < 4; ++s) {
            int q = s * 256 + threadIdx.x;
            size_t mi = ((size_t)bh * N_ + q) * N_;
            if (!mask_at(smask, f, mi)) c += 1.f;
        }
        c = blockSum256(c);
        if (threadIdx.x == 0) counts[bh] = (int)(c + 0.5f);
    }
}

// ================= remaining support kernels =================

__global__ void k_select_head(const int* __restrict__ counts, int* __restrict__ hsel) {
    if (threadIdx.x != 0 || blockIdx.x != 0) return;
    float p[B_][H_];
    for (int h = 0; h < H_; ++h) {
        float mx = -1e30f;
        for (int b = 0; b < B_; ++b) mx = fmaxf(mx, (float)counts[b * H_ + h]);
        float s = 0.f;
        for (int b = 0; b < B_; ++b) { p[b][h] = expf((float)counts[b * H_ + h] - mx); s += p[b][h]; }
        for (int b = 0; b < B_; ++b) p[b][h] /= s;
    }
    for (int b = 0; b < B_; ++b) {
        int best = 0; float bv = p[b][0];
        for (int h = 1; h < H_; ++h) if (p[b][h] > bv) { bv = p[b][h]; best = h; }
        hsel[b] = best;
    }
}

// softmax + per-row top2 (value,col) + diag/den2 extraction + ax2 diagonal init
__global__ __launch_bounds__(256) void k_softmax(float* __restrict__ Sc,
                                                 const void* __restrict__ smask,
                                                 const int* __restrict__ flagp,
                                                 const int* __restrict__ hsel,
                                                 float4* __restrict__ t2p,
                                                 float* __restrict__ adiag,
                                                 float* __restrict__ den2,
                                                 const bf16* __restrict__ x,
                                                 bf16* __restrict__ ax2) {
    __shared__ float s1[256], s2[256];
    __shared__ int sc1[256], sc2[256];
    __shared__ float sdiag;
    int b = blockIdx.y, row = blockIdx.x;
    int h0 = hsel[b], flag = flagp[0];
    float* rp = Sc + ((size_t)b * N_ + row) * N_;
    float v[4];
    float mx = -INFINITY;
    #pragma unroll
    for (int s = 0; s < 4; ++s) { v[s] = rp[s * 256 + threadIdx.x]; mx = fmaxf(mx, v[s]); }
    mx = blockMax256(mx);
    float sum = 0.f;
    #pragma unroll
    for (int s = 0; s < 4; ++s) { v[s] = expf(v[s] - mx); sum += v[s]; }
    sum = blockSum256(sum);
    size_t ki = (((size_t)b * H_ + h0) * N_ + row) * N_;
    float keep = mask_at(smask, flag, ki) ? 0.f : 1.f;
    float inv = keep / sum;
    float m1 = -INFINITY, m2 = -INFINITY;
    int c1 = 0, c2 = 0;
    #pragma unroll
    for (int s = 0; s < 4; ++s) {
        int col = s * 256 + threadIdx.x;
        float xv = v[s] * inv;
        rp[col] = xv;
        if (col == row) sdiag = xv;
        if (xv > m1) { m2 = m1; c2 = c1; m1 = xv; c1 = col; }
        else if (xv > m2) { m2 = xv; c2 = col; }
    }
    int tid = threadIdx.x;
    s1[tid] = m1; sc1[tid] = c1; s2[tid] = m2; sc2[tid] = c2;
    __syncthreads();
    for (int off = 128; off; off >>= 1) {
        if (tid < off) {
            float a1 = s1[tid], a2 = s2[tid];
            int ac1 = sc1[tid], ac2 = sc2[tid];
            float b1 = s1[tid + off], b2 = s2[tid + off];
            int bc1 = sc1[tid + off], bc2 = sc2[tid + off];
            float n1, n2; int nc1, nc2;
            if (b1 > a1) {
                n1 = b1; nc1 = bc1;
                if (a1 >= b2) { n2 = a1; nc2 = ac1; } else { n2 = b2; nc2 = bc2; }
            } else {
                n1 = a1; nc1 = ac1;
                if (b1 >= a2) { n2 = b1; nc2 = bc1; } else { n2 = a2; nc2 = ac2; }
            }
            s1[tid] = n1; sc1[tid] = nc1; s2[tid] = n2; sc2[tid] = nc2;
        }
        __syncthreads();
    }
    if (tid == 0) {
        float4 o; o.x = s1[0]; o.y = (float)sc1[0]; o.z = s2[0]; o.w = (float)sc2[0];
        t2p[(size_t)b * N_ + row] = o;
        adiag[b * N_ + row] = sdiag;
        den2[b * N_ + row] = sdiag + 1.0f;
    }
    __syncthreads();
    float a = sdiag;
    const bf16* xp = x + ((size_t)b * N_ + row) * DC_;
    bf16* op = ax2 + ((size_t)b * N_ + row) * DC_;
    #pragma unroll
    for (int s = 0; s < 6; ++s) {
        int d = s * 256 + threadIdx.x;
        op[d] = (bf16)(a * (float)xp[d]);
    }
}

// global top-2 threshold + candidate selection from per-row top2 records
__global__ __launch_bounds__(256) void k_top2sel(const float4* __restrict__ t2p,
                                                 float* __restrict__ thr,
                                                 int* __restrict__ selcnt,
                                                 int* __restrict__ sel) {
    __shared__ float s1[256], s2[256];
    __shared__ int scnt;
    int b = blockIdx.x, tid = threadIdx.x;
    float m1 = -INFINITY, m2 = -INFINITY;
    for (int s = 0; s < 4; ++s) {
        float4 p = t2p[(size_t)b * N_ + s * 256 + tid];
        float n1 = fmaxf(m1, p.x);
        float n2 = fmaxf(fminf(m1, p.x), fmaxf(m2, p.z));
        m1 = n1; m2 = n2;
    }
    s1[tid] = m1; s2[tid] = m2;
    __syncthreads();
    for (int off = 128; off; off >>= 1) {
        if (tid < off) {
            float a1 = s1[tid], a2 = s2[tid], b1 = s1[tid + off], b2 = s2[tid + off];
            s1[tid] = fmaxf(a1, b1);
            s2[tid] = fmaxf(fminf(a1, b1), fmaxf(a2, b2));
        }
        __syncthreads();
    }
    if (tid == 0) { thr[b] = s2[0]; scnt = 0; }
    __syncthreads();
    float t = s2[0];
    for (int s = 0; s < 4; ++s) {
        int row = s * 256 + tid;
        float4 p = t2p[(size_t)b * N_ + row];
        if (p.x >= t) {
            int pos = atomicAdd(&scnt, 1);
            if (pos < 512) {
                sel[((size_t)b * 512 + pos) * 2]     = row;
                sel[((size_t)b * 512 + pos) * 2 + 1] = (int)p.y;
            }
        }
        if (p.z >= t) {
            int pos = atomicAdd(&scnt, 1);
            if (pos < 512) {
                sel[((size_t)b * 512 + pos) * 2]     = row;
                sel[((size_t)b * 512 + pos) * 2 + 1] = (int)p.w;
            }
        }
    }
    __syncthreads();
    if (tid == 0) selcnt[b] = scnt;
}

__global__ __launch_bounds__(256) void k_ax2_sparse(const float* __restrict__ attn,
                                                    const bf16* __restrict__ x,
                                                    const int* __restrict__ selcnt,
                                                    const int* __restrict__ sel,
                                                    bf16* __restrict__ ax2,
                                                    float* __restrict__ den2) {
    int b = blockIdx.x;
    int cnt = selcnt[b]; if (cnt > 512) cnt = 512;
    __shared__ int si[1024];
    if (threadIdx.x == 0) {
        for (int e = 0; e < cnt; ++e) {
            si[e * 2]     = sel[((size_t)b * 512 + e) * 2];
            si[e * 2 + 1] = sel[((size_t)b * 512 + e) * 2 + 1];
        }
        for (int a = 1; a < cnt; ++a) {
            int ii = si[a * 2], jj = si[a * 2 + 1];
            long long key = (long long)ii * N_ + jj;
            int p = a - 1;
            while (p >= 0 && ((long long)si[p * 2] * N_ + si[p * 2 + 1]) > key) {
                si[(p + 1) * 2] = si[p * 2]; si[(p + 1) * 2 + 1] = si[p * 2 + 1]; --p;
            }
            si[(p + 1) * 2] = ii; si[(p + 1) * 2 + 1] = jj;
        }
    }
    __syncthreads();
    const float* ap = attn + (size_t)b * N_ * N_;
    for (int e = 0; e < cnt; ++e) {
        int i = si[e * 2], j = si[e * 2 + 1];
        if (i == j) continue;
        float aij = ap[(size_t)i * N_ + j];
        float aji = ap[(size_t)j * N_ + i];
        bf16* ri = ax2 + ((size_t)b * N_ + i) * DC_;
        bf16* rj = ax2 + ((size_t)b * N_ + j) * DC_;
        const bf16* xi = x + ((size_t)b * N_ + i) * DC_;
        const bf16* xj = x + ((size_t)b * N_ + j) * DC_;
        for (int s = 0; s < 6; ++s) {
            int d = s * 256 + threadIdx.x;
            ri[d] = (bf16)((float)ri[d] + aij * (float)xj[d]);
            rj[d] = (bf16)((float)rj[d] + aji * (float)xi[d]);
        }
        if (threadIdx.x == 0) {
            den2[b * N_ + i] += aij;
            den2[b * N_ + j] += aji;
        }
        __syncthreads();
    }
}

// ---------------- launch ----------------
extern "C" void kernel_launch(void* const* d_in, const int* in_sizes, int n_in,
                              void* d_out, int out_size, void* d_ws, size_t ws_size,
                              hipStream_t stream) {
    if (n_in < 17) return;
    if (ws_size < WS_NEED) return;

    const float* adj    = (const float*)d_in[0];
    const float* inputs = (const float*)d_in[1];
    const void*  smask  = d_in[2];
    const float* W0w = (const float*)d_in[3];
    const float* W0b = (const float*)d_in[4];
    const float* W1w = (const float*)d_in[5];
    const float* W1b = (const float*)d_in[6];
    const float* qw  = (const float*)d_in[7];
    const float* qb  = (const float*)d_in[8];
    const float* kw  = (const float*)d_in[9];
    const float* kb  = (const float*)d_in[10];
    const float* convw = (const float*)d_in[11];
    const float* convb = (const float*)d_in[12];
    const float* lincw = (const float*)d_in[13];
    const float* lincb = (const float*)d_in[14];
    const float* fc1w  = (const float*)d_in[15];
    const float* fc2w  = (const float*)d_in[16];

    char* W = (char*)d_ws;
    float* out = (float*)d_out;

    float* den    = (float*)(W + O_DEN);
    float* den2   = (float*)(W + O_DEN2);
    float* adiag  = (float*)(W + O_ADIAG);
    float* thr    = (float*)(W + O_THR);
    int*   counts = (int*)(W + O_CNTS);
    int*   hsel   = (int*)(W + O_HSEL);
    int*   selcnt = (int*)(W + O_SELC);
    int*   flag   = (int*)(W + O_FLAG);
    float* qkb    = (float*)(W + O_QKB);
    int*   sel    = (int*)(W + O_SEL);
    float* ATTN   = (float*)(W + O_ATTN);
    float4* t2p4  = (float4*)(W + O_T2P4);
    bf16* X     = (bf16*)(W + O_X);
    bf16* AX2   = (bf16*)(W + O_AX2);
    bf16* QKOUT = (bf16*)(W + O_AX2);
    bf16* ADJB  = (bf16*)(W + O_ADJB);
    bf16* INT_  = (bf16*)(W + O_INT);
    bf16* OUT0T = (bf16*)(W + O_OUT0T);
    bf16* BBA   = (bf16*)(W + O_BBA);
    bf16* BBB   = (bf16*)(W + O_BBB);
    bf16* BBC   = (bf16*)(W + O_BBC);
    bf16* W0T   = (bf16*)(W + O_W0T);
    bf16* W1T   = (bf16*)(W + O_W1T);
    bf16* QKWT  = (bf16*)(W + O_QKWT);
    bf16* CW2   = (bf16*)(W + O_CWB);
    bf16* LCT   = (bf16*)(W + O_LCT);
    bf16* F1T   = (bf16*)(W + O_F1T);
    bf16* F2T   = (bf16*)(W + O_F2T);

    const size_t sND  = (size_t)N_ * D_;
    const size_t sNDC = (size_t)N_ * DC_;
    const size_t sNN  = (size_t)N_ * N_;

    // ---- all prep in one dispatch ----
    k_prep<<<PB_CNT, 256, 0, stream>>>(smask, flag, counts,
        adj, ADJB, den, inputs, X, INT_, convw, CW2,
        qb, kb, qkb, W0w, W0T, W1w, W1T, qw, kw, QKWT,
        lincw, LCT, fc1w, F1T, fc2w, F2T);
    k_select_head<<<1, 64, 0, stream>>>(counts, hsel);

    // ---- GCN layer 0: xW0 and Ax jammed in one dispatch (independent) ----
    mmJam<<<dim3(6, 16, 16), 256, 0, stream>>>(
        X, sNDC, DC_, W0T, 0, D_, W0b, BBA, sND, D_, D_,
        ADJB, sNN, N_, INT_, sND, N_, BBB, sND, D_, N_);
    // out0 written DIRECTLY TRANSPOSED into OUT0T (EPI 8) -> no k_tr_bf16
    mm<8><<<dim3(6, 16, B_), 256, 0, stream>>>(BBB, sND, D_, W0T, 0, D_, nullptr, 0,
        W0b, BBA, D_, den, nullptr, nullptr, OUT0T, nullptr, sND, N_, N_, D_, D_,
        nullptr, nullptr, nullptr, 0, 0);
    mm<5><<<dim3(6, 16, B_), 256, 0, stream>>>(CW2, 0, 3072, OUT0T, sND, N_, nullptr, 0,
        convb, nullptr, 0, nullptr, nullptr, nullptr, BBB, nullptr, sND, D_, N_, D_, 3072,
        nullptr, nullptr, nullptr, 0, 0);
    mm<0><<<dim3(6, 16, B_), 256, 0, stream>>>(BBB, sND, D_, LCT, 0, D_, nullptr, 0,
        lincb, nullptr, 0, nullptr, nullptr, nullptr, X + D_, nullptr, sNDC, DC_, N_, D_, D_,
        nullptr, nullptr, nullptr, 0, 0);

    // ---- merged Q|K projection + xW1 (EPI 7, 128x128 tiles): N = 1792, grid 896 ----
    mm2<7><<<dim3(14, 8, B_), 256, 0, stream>>>(X, sNDC, DC_, QKWT, 0, DC_, hsel, 1024,
        qkb, nullptr, 0, nullptr, nullptr, nullptr, QKOUT, nullptr, sNN, N_, N_, 1792, DC_,
        W1T, W1b, BBA, sND, D_);

    // ---- scores (fp32, masked; 128x128 tiles): grid 512 = 2/CU balanced ----
    mm2<4><<<dim3(8, 8, B_), 256, 0, stream>>>(QKOUT, sNN, N_, QKOUT + 512, sNN, N_, hsel, 0,
        nullptr, nullptr, 0, nullptr, smask, flag, nullptr, ATTN, sNN, N_, N_, N_, DK_,
        nullptr, nullptr, nullptr, 0, 0);

    // ---- softmax (+row top2 with cols, diag/den2, ax2 diag init) ----
    k_softmax<<<dim3(N_, B_), 256, 0, stream>>>(ATTN, smask, flag, hsel, t2p4,
                                                adiag, den2, X, AX2);

    // ---- top-2 threshold + candidate selection (no ATTN rescan) ----
    k_top2sel<<<B_, 256, 0, stream>>>(t2p4, thr, selcnt, sel);
    k_ax2_sparse<<<B_, 256, 0, stream>>>(ATTN, X, selcnt, sel, AX2, den2);

    // ---- GCN layer 1 (xW1 already in BBA from merged GEMM) ----
    mm<1><<<dim3(6, 16, B_), 256, 0, stream>>>(AX2, sNDC, DC_, W1T, 0, DC_, nullptr, 0,
        W1b, BBA, D_, den2, nullptr, nullptr, BBB, nullptr, sND, D_, N_, D_, DC_,
        nullptr, nullptr, nullptr, 0, 0);

    // ---- fc ----
    mm<2><<<dim3(6, 16, B_), 256, 0, stream>>>(BBB, sND, D_, F1T, 0, D_, nullptr, 0,
        nullptr, nullptr, 0, nullptr, nullptr, nullptr, BBC, nullptr, sND, D_, N_, D_, D_,
        nullptr, nullptr, nullptr, 0, 0);
    mm<3><<<dim3(6, 16, B_), 256, 0, stream>>>(BBC, sND, D_, F2T, 0, D_, nullptr, 0,
        nullptr, nullptr, 0, nullptr, nullptr, nullptr, nullptr, out, sND, D_, N_, D_, D_,
        nullptr, nullptr, nullptr, 0, 0);
}

// Round 16
// 386.224 us; speedup vs baseline: 1.4823x; 1.0024x over previous
//
#include <hip/hip_runtime.h>
#include <cstdint>
#include <cstddef>

typedef __bf16 bf16;
typedef __bf16 bf16x8 __attribute__((ext_vector_type(8)));
typedef float f32x4 __attribute__((ext_vector_type(4)));

#define B_ 8
#define N_ 1024
#define D_ 768
#define H_ 3
#define DC_ 1536
#define DK_ 512
#define PC_ 766
#define MB_ (1024ull*1024ull)

// ---------------- workspace layout (byte offsets) ----------------
static const size_t O_DEN   = 0;
static const size_t O_DEN2  = 32768;
static const size_t O_ADIAG = 65536;
static const size_t O_RST   = 98304;      // float2[8192] row stats {mx, keep/sum} (64KB)
static const size_t O_THR   = 163840;
static const size_t O_CNTS  = 164096;
static const size_t O_HSEL  = 164352;
static const size_t O_SELC  = 164608;
static const size_t O_FLAG  = 164864;
static const size_t O_QKB   = 165120;
static const size_t O_SEL   = 180224;
static const size_t O_ATTN  = 262144;            // f32 [8,1024,1024] 32MB (raw masked scores)
static const size_t O_X     = O_ATTN + 32*MB_;   // bf16 [8,1024,1536] 24MB
static const size_t O_AX2   = O_X    + 24*MB_;   // bf16 [8,1024,1536] 24MB (QK out overlays early)
static const size_t O_ADJB  = O_AX2  + 24*MB_;   // bf16 [8,1024,1024] 16MB
static const size_t O_INT   = O_ADJB + 16*MB_;   // bf16 [8,768,1024] inputs^T -> OUT0T (12MB)
static const size_t O_BBA   = O_INT  + 12*MB_;
static const size_t O_BBB   = O_BBA  + 12*MB_;
static const size_t O_BBC   = O_BBB  + 12*MB_;   // [T2P4 during attention phase] -> fc1out
static const size_t O_W0T   = O_BBC  + 12*MB_;   // [768][768]
static const size_t O_W1T   = O_W0T + 1179648;   // [768][1536]
static const size_t O_QKWT  = O_W1T + 2359296;   // [3072][1536]
static const size_t O_CWB   = O_QKWT + 9437184;  // CW2 [1024][3072]
static const size_t O_LCT   = O_CWB + 6291456;
static const size_t O_F1T   = O_LCT + 1179648;
static const size_t O_F2T   = O_F1T + 1179648;
static const size_t WS_NEED = O_F2T + 1179648;
static const size_t O_OUT0T = O_INT;
// t2p float4[8*1024] (128KB) overlays BBC head (dead until fc1 writes it).
static const size_t O_T2P4  = O_BBC;

// ---------------- helpers ----------------
__device__ __forceinline__ bool mask_at(const void* p, int flag, size_t i) {
    switch (flag) {
        case 1:  return ((const int*)p)[i] != 0;
        case 2:  return ((const float*)p)[i] != 0.0f;
        case 3:  return ((const long long*)p)[i] != 0;
        default: return ((const unsigned char*)p)[i] != 0;
    }
}

__device__ __forceinline__ void gload16(const void* g, void* l) {
    __builtin_amdgcn_global_load_lds(
        (const __attribute__((address_space(1))) void*)g,
        (__attribute__((address_space(3))) void*)l, 16, 0, 0);
}

__device__ inline float blockMax256(float v) {
    __shared__ float red[4];
    for (int off = 32; off; off >>= 1) v = fmaxf(v, __shfl_xor(v, off));
    int lane = threadIdx.x & 63, wid = threadIdx.x >> 6;
    if (lane == 0) red[wid] = v;
    __syncthreads();
    v = fmaxf(fmaxf(red[0], red[1]), fmaxf(red[2], red[3]));
    __syncthreads();
    return v;
}

__device__ inline float blockSum256(float v) {
    __shared__ float red[4];
    for (int off = 32; off; off >>= 1) v += __shfl_xor(v, off);
    int lane = threadIdx.x & 63, wid = threadIdx.x >> 6;
    if (lane == 0) red[wid] = v;
    __syncthreads();
    v = red[0] + red[1] + red[2] + red[3];
    __syncthreads();
    return v;
}

// shared epilogue (scalar variants)
template<int EPI>
__device__ __forceinline__ void epi_store(
    float v, int b, int m, int n, int M,
    const int boff, const float* __restrict__ bias,
    const bf16* __restrict__ Dadd, int ldd,
    const float* __restrict__ denv,
    const void* __restrict__ smask, int flag, int h0,
    bf16* __restrict__ Cb, float* __restrict__ Cf, size_t sC, int ldc,
    const float* __restrict__ bias2, bf16* __restrict__ Cb2, size_t sC2, int ldc2)
{
    size_t oidx = (size_t)b * sC + (size_t)m * ldc + n;
    if (EPI == 0) {
        Cb[oidx] = (bf16)(v + bias[boff + n]);
    } else if (EPI == 1) {
        v = fmaxf((v + bias[n]) / denv[(size_t)b * M + m], 0.f)
            + (float)Dadd[((size_t)b * M + m) * ldd + n];
        Cb[oidx] = (bf16)v;
    } else if (EPI == 2) {
        Cb[oidx] = (bf16)fmaxf(v, 0.f);
    } else if (EPI == 3) {
        Cf[oidx] = v;
    } else if (EPI == 4) {
        size_t mi = (((size_t)b * H_ + h0) * N_ + m) * N_ + n;
        Cf[oidx] = mask_at(smask, flag, mi) ? -1e9f : v * 0.04419417382415922f;
    } else if (EPI == 5) {
        Cb[oidx] = (n < PC_) ? (bf16)fmaxf(v + bias[m], 0.f) : (bf16)0.f;
    } else if (EPI == 7) {
        if (n < 1024)
            Cb[(size_t)b * sC + (size_t)m * ldc + n] = (bf16)(v + bias[boff + n]);
        else
            Cb2[(size_t)b * sC2 + (size_t)m * ldc2 + (n - 1024)] = (bf16)(v + bias2[n - 1024]);
    } else {
        Cb[oidx] = (bf16)v;
    }
}

// ================= bf16 MFMA NT GEMM (64x128 tile) =================
// R10 geometry: 4 waves (each 32x64), BK=64, 2-phase dbuf, counted vmcnt(6),
// raw s_barrier pairs, conflict-free 8-chunk XOR swizzle.
// EPI 8: GCN epilogue stored TRANSPOSED (Cb[b][n][m], one 8B store per fragment).
template<int EPI>
__global__ __launch_bounds__(256) void mm(
    const bf16* __restrict__ A, size_t sA, int lda,
    const bf16* __restrict__ Bt, size_t sB, int ldb,
    const int* __restrict__ rowIdx, int rowMul,
    const float* __restrict__ bias,
    const bf16* __restrict__ Dadd, int ldd,
    const float* __restrict__ denv,
    const void* __restrict__ smask, const int* __restrict__ flagp,
    bf16* __restrict__ Cb, float* __restrict__ Cf, size_t sC, int ldc,
    int M, int N, int K,
    const bf16* __restrict__ Bt2, const float* __restrict__ bias2,
    bf16* __restrict__ Cb2, size_t sC2, int ldc2)
{
    __shared__ __align__(16) bf16 As[2][64 * 64];
    __shared__ __align__(16) bf16 Bs[2][128 * 64];

    const int gx = gridDim.x, gy = gridDim.y;
    const int nwg = gx * gy * (int)gridDim.z;
    int lin = ((int)blockIdx.z * gy + (int)blockIdx.y) * gx + (int)blockIdx.x;
    int cpx = nwg >> 3;
    int swz = (lin & 7) * cpx + (lin >> 3);
    int ty = swz % gy;
    int tt = swz / gy;
    int tx = tt % gx;
    int b  = tt / gx;

    const int bm = ty * 64, bn = tx * 128;
    const int tid = threadIdx.x;
    const int lane = tid & 63, w = tid >> 6;
    const int wr = w >> 1, wc = w & 1;
    const int boff = rowIdx ? rowIdx[b] * rowMul : 0;

    const bf16* Ab = A + (size_t)b * sA;
    const bf16* Bb = Bt + (size_t)b * sB;

    const bf16* Bsrc = Bb;
    int bRow0 = boff + bn;
    if (EPI == 7 && bn >= 1024) { Bsrc = Bt2; bRow0 = bn - 1024; }

    const int sr = lane >> 3;
    const int gk = ((lane & 7) ^ (lane >> 3)) * 8;

    f32x4 zero = {0.f, 0.f, 0.f, 0.f};
    f32x4 acc[2][4];
    #pragma unroll
    for (int i = 0; i < 2; ++i)
        #pragma unroll
        for (int j = 0; j < 4; ++j) acc[i][j] = zero;

    #pragma unroll
    for (int q = 0; q < 2; ++q)
        gload16((const void*)(Ab + (size_t)(bm + w * 16 + q * 8 + sr) * lda + gk),
                (void*)(As[0] + (w * 16 + q * 8) * 64));
    #pragma unroll
    for (int q = 0; q < 4; ++q)
        gload16((const void*)(Bsrc + (size_t)(bRow0 + w * 32 + q * 8 + sr) * ldb + gk),
                (void*)(Bs[0] + (w * 32 + q * 8) * 64));

    const int rl = lane & 15;
    const int g8 = lane >> 4;
    const int rx = lane & 7;

    int cur = 0;
    for (int k0 = 0; k0 < K; k0 += 64) {
        int nxt = cur ^ 1;
        if (k0 + 64 < K) {
            #pragma unroll
            for (int q = 0; q < 2; ++q)
                gload16((const void*)(Ab + (size_t)(bm + w * 16 + q * 8 + sr) * lda + k0 + 64 + gk),
                        (void*)(As[nxt] + (w * 16 + q * 8) * 64));
            #pragma unroll
            for (int q = 0; q < 4; ++q)
                gload16((const void*)(Bsrc + (size_t)(bRow0 + w * 32 + q * 8 + sr) * ldb + k0 + 64 + gk),
                        (void*)(Bs[nxt] + (w * 32 + q * 8) * 64));
            asm volatile("s_waitcnt vmcnt(6)" ::: "memory");
        } else {
            asm volatile("s_waitcnt vmcnt(0)" ::: "memory");
        }
        __builtin_amdgcn_s_barrier();
        __builtin_amdgcn_sched_barrier(0);

        bf16x8 af[2][2], bfv[4][2];
        #pragma unroll
        for (int ks = 0; ks < 2; ++ks) {
            int e = ks * 4 + g8;
            #pragma unroll
            for (int i = 0; i < 2; ++i)
                af[i][ks] = *(const bf16x8*)(As[cur] + (wr * 32 + i * 16 + rl) * 64 + (e ^ rx) * 8);
            #pragma unroll
            for (int j = 0; j < 4; ++j)
                bfv[j][ks] = *(const bf16x8*)(Bs[cur] + (wc * 64 + j * 16 + rl) * 64 + (e ^ rx) * 8);
        }
        #pragma unroll
        for (int ks = 0; ks < 2; ++ks)
            #pragma unroll
            for (int i = 0; i < 2; ++i)
                #pragma unroll
                for (int j = 0; j < 4; ++j)
                    acc[i][j] = __builtin_amdgcn_mfma_f32_16x16x32_bf16(af[i][ks], bfv[j][ks], acc[i][j], 0, 0, 0);

        __builtin_amdgcn_s_barrier();
        __builtin_amdgcn_sched_barrier(0);
        cur = nxt;
    }

    const int r0 = (lane >> 4) * 4, c0 = lane & 15;
    int flag = 0, h0 = 0;
    if (EPI == 4) { flag = flagp[0]; h0 = rowIdx[b]; }
    if (EPI == 8) {
        #pragma unroll
        for (int i = 0; i < 2; ++i) {
            int m0 = bm + wr * 32 + i * 16 + r0;
            #pragma unroll
            for (int j = 0; j < 4; ++j) {
                int n = bn + wc * 64 + j * 16 + c0;
                union { bf16 h[4]; uint2 u; } o;
                #pragma unroll
                for (int r = 0; r < 4; ++r) {
                    int m = m0 + r;
                    float v = fmaxf((acc[i][j][r] + bias[n]) / denv[(size_t)b * M + m], 0.f)
                              + (float)Dadd[((size_t)b * M + m) * ldd + n];
                    o.h[r] = (bf16)v;
                }
                *(uint2*)&Cb[(size_t)b * sC + (size_t)n * ldc + m0] = o.u;
            }
        }
        return;
    }
    #pragma unroll
    for (int i = 0; i < 2; ++i)
        #pragma unroll
        for (int r = 0; r < 4; ++r) {
            int m = bm + wr * 32 + i * 16 + r0 + r;
            #pragma unroll
            for (int j = 0; j < 4; ++j) {
                int n = bn + wc * 64 + j * 16 + c0;
                epi_store<EPI>(acc[i][j][r], b, m, n, M, boff, bias, Dadd, ldd, denv,
                               smask, flag, h0, Cb, Cf, sC, ldc, bias2, Cb2, sC2, ldc2);
            }
        }
}

// ================= jammed pair of independent GEMMs (64x128 tile) =================
__global__ __launch_bounds__(256) void mmJam(
    const bf16* __restrict__ A0, size_t sA0, int lda0,
    const bf16* __restrict__ B0t, size_t sB0, int ldb0,
    const float* __restrict__ bias0,
    bf16* __restrict__ C0, size_t sC0, int ldc0, int K0,
    const bf16* __restrict__ A1, size_t sA1, int lda1,
    const bf16* __restrict__ B1t, size_t sB1, int ldb1,
    bf16* __restrict__ C1, size_t sC1, int ldc1, int K1)
{
    __shared__ __align__(16) bf16 As[2][64 * 64];
    __shared__ __align__(16) bf16 Bs[2][128 * 64];

    const int gx = gridDim.x, gy = gridDim.y;   // gz = 16 (2 jobs x 8 batches)
    const int nwg = gx * gy * (int)gridDim.z;
    int lin = ((int)blockIdx.z * gy + (int)blockIdx.y) * gx + (int)blockIdx.x;
    int cpx = nwg >> 3;
    int swz = (lin & 7) * cpx + (lin >> 3);
    int ty = swz % gy;
    int tt = swz / gy;
    int tx = tt % gx;
    int zz = tt / gx;
    int job = zz >> 3;
    int b   = zz & 7;

    const bf16* A  = job ? A1 : A0;
    const bf16* Bt = job ? B1t : B0t;
    bf16* C        = job ? C1 : C0;
    const size_t sA = job ? sA1 : sA0;
    const size_t sB = job ? sB1 : sB0;
    const size_t sC = job ? sC1 : sC0;
    const int lda = job ? lda1 : lda0;
    const int ldb = job ? ldb1 : ldb0;
    const int ldc = job ? ldc1 : ldc0;
    const int K   = job ? K1 : K0;

    const int bm = ty * 64, bn = tx * 128;
    const int tid = threadIdx.x;
    const int lane = tid & 63, w = tid >> 6;
    const int wr = w >> 1, wc = w & 1;

    const bf16* Ab = A + (size_t)b * sA;
    const bf16* Bb = Bt + (size_t)b * sB;

    const int sr = lane >> 3;
    const int gk = ((lane & 7) ^ (lane >> 3)) * 8;

    f32x4 zero = {0.f, 0.f, 0.f, 0.f};
    f32x4 acc[2][4];
    #pragma unroll
    for (int i = 0; i < 2; ++i)
        #pragma unroll
        for (int j = 0; j < 4; ++j) acc[i][j] = zero;

    #pragma unroll
    for (int q = 0; q < 2; ++q)
        gload16((const void*)(Ab + (size_t)(bm + w * 16 + q * 8 + sr) * lda + gk),
                (void*)(As[0] + (w * 16 + q * 8) * 64));
    #pragma unroll
    for (int q = 0; q < 4; ++q)
        gload16((const void*)(Bb + (size_t)(bn + w * 32 + q * 8 + sr) * ldb + gk),
                (void*)(Bs[0] + (w * 32 + q * 8) * 64));

    const int rl = lane & 15;
    const int g8 = lane >> 4;
    const int rx = lane & 7;

    int cur = 0;
    for (int k0 = 0; k0 < K; k0 += 64) {
        int nxt = cur ^ 1;
        if (k0 + 64 < K) {
            #pragma unroll
            for (int q = 0; q < 2; ++q)
                gload16((const void*)(Ab + (size_t)(bm + w * 16 + q * 8 + sr) * lda + k0 + 64 + gk),
                        (void*)(As[nxt] + (w * 16 + q * 8) * 64));
            #pragma unroll
            for (int q = 0; q < 4; ++q)
                gload16((const void*)(Bb + (size_t)(bn + w * 32 + q * 8 + sr) * ldb + k0 + 64 + gk),
                        (void*)(Bs[nxt] + (w * 32 + q * 8) * 64));
            asm volatile("s_waitcnt vmcnt(6)" ::: "memory");
        } else {
            asm volatile("s_waitcnt vmcnt(0)" ::: "memory");
        }
        __builtin_amdgcn_s_barrier();
        __builtin_amdgcn_sched_barrier(0);

        bf16x8 af[2][2], bfv[4][2];
        #pragma unroll
        for (int ks = 0; ks < 2; ++ks) {
            int e = ks * 4 + g8;
            #pragma unroll
            for (int i = 0; i < 2; ++i)
                af[i][ks] = *(const bf16x8*)(As[cur] + (wr * 32 + i * 16 + rl) * 64 + (e ^ rx) * 8);
            #pragma unroll
            for (int j = 0; j < 4; ++j)
                bfv[j][ks] = *(const bf16x8*)(Bs[cur] + (wc * 64 + j * 16 + rl) * 64 + (e ^ rx) * 8);
        }
        #pragma unroll
        for (int ks = 0; ks < 2; ++ks)
            #pragma unroll
            for (int i = 0; i < 2; ++i)
                #pragma unroll
                for (int j = 0; j < 4; ++j)
                    acc[i][j] = __builtin_amdgcn_mfma_f32_16x16x32_bf16(af[i][ks], bfv[j][ks], acc[i][j], 0, 0, 0);

        __builtin_amdgcn_s_barrier();
        __builtin_amdgcn_sched_barrier(0);
        cur = nxt;
    }

    const int r0 = (lane >> 4) * 4, c0 = lane & 15;
    #pragma unroll
    for (int i = 0; i < 2; ++i)
        #pragma unroll
        for (int r = 0; r < 4; ++r) {
            int m = bm + wr * 32 + i * 16 + r0 + r;
            #pragma unroll
            for (int j = 0; j < 4; ++j) {
                int n = bn + wc * 64 + j * 16 + c0;
                float v = acc[i][j][r];
                if (job == 0) v += bias0[n];
                C[(size_t)b * sC + (size_t)m * ldc + n] = (bf16)v;
            }
        }
}

// ================= bf16 MFMA NT GEMM (128x128 tile) =================
template<int EPI>
__global__ __launch_bounds__(256) void mm2(
    const bf16* __restrict__ A, size_t sA, int lda,
    const bf16* __restrict__ Bt, size_t sB, int ldb,
    const int* __restrict__ rowIdx, int rowMul,
    const float* __restrict__ bias,
    const bf16* __restrict__ Dadd, int ldd,
    const float* __restrict__ denv,
    const void* __restrict__ smask, const int* __restrict__ flagp,
    bf16* __restrict__ Cb, float* __restrict__ Cf, size_t sC, int ldc,
    int M, int N, int K,
    const bf16* __restrict__ Bt2, const float* __restrict__ bias2,
    bf16* __restrict__ Cb2, size_t sC2, int ldc2)
{
    __shared__ __align__(16) bf16 As[2][128 * 64];
    __shared__ __align__(16) bf16 Bs[2][128 * 64];

    const int gx = gridDim.x, gy = gridDim.y;
    const int nwg = gx * gy * (int)gridDim.z;
    int lin = ((int)blockIdx.z * gy + (int)blockIdx.y) * gx + (int)blockIdx.x;
    int cpx = nwg >> 3;
    int swz = (lin & 7) * cpx + (lin >> 3);
    int ty = swz % gy;
    int tt = swz / gy;
    int tx = tt % gx;
    int b  = tt / gx;

    const int bm = ty * 128, bn = tx * 128;
    const int tid = threadIdx.x;
    const int lane = tid & 63, w = tid >> 6;
    const int wr = w >> 1, wc = w & 1;
    const int boff = rowIdx ? rowIdx[b] * rowMul : 0;

    const bf16* Ab = A + (size_t)b * sA;
    const bf16* Bb = Bt + (size_t)b * sB;

    const bf16* Bsrc = Bb;
    int bRow0 = boff + bn;
    if (EPI == 7 && bn >= 1024) { Bsrc = Bt2; bRow0 = bn - 1024; }

    const int sr = lane >> 3;
    const int gk = ((lane & 7) ^ (lane >> 3)) * 8;

    f32x4 zero = {0.f, 0.f, 0.f, 0.f};
    f32x4 acc[4][4];
    #pragma unroll
    for (int i = 0; i < 4; ++i)
        #pragma unroll
        for (int j = 0; j < 4; ++j) acc[i][j] = zero;

    #pragma unroll
    for (int q = 0; q < 4; ++q)
        gload16((const void*)(Ab + (size_t)(bm + w * 32 + q * 8 + sr) * lda + gk),
                (void*)(As[0] + (w * 32 + q * 8) * 64));
    #pragma unroll
    for (int q = 0; q < 4; ++q)
        gload16((const void*)(Bsrc + (size_t)(bRow0 + w * 32 + q * 8 + sr) * ldb + gk),
                (void*)(Bs[0] + (w * 32 + q * 8) * 64));

    const int rl = lane & 15;
    const int g8 = lane >> 4;
    const int rx = lane & 7;

    int cur = 0;
    for (int k0 = 0; k0 < K; k0 += 64) {
        int nxt = cur ^ 1;
        if (k0 + 64 < K) {
            #pragma unroll
            for (int q = 0; q < 4; ++q)
                gload16((const void*)(Ab + (size_t)(bm + w * 32 + q * 8 + sr) * lda + k0 + 64 + gk),
                        (void*)(As[nxt] + (w * 32 + q * 8) * 64));
            #pragma unroll
            for (int q = 0; q < 4; ++q)
                gload16((const void*)(Bsrc + (size_t)(bRow0 + w * 32 + q * 8 + sr) * ldb + k0 + 64 + gk),
                        (void*)(Bs[nxt] + (w * 32 + q * 8) * 64));
            asm volatile("s_waitcnt vmcnt(8)" ::: "memory");
        } else {
            asm volatile("s_waitcnt vmcnt(0)" ::: "memory");
        }
        __builtin_amdgcn_s_barrier();
        __builtin_amdgcn_sched_barrier(0);

        #pragma unroll
        for (int ks = 0; ks < 2; ++ks) {
            int e = ks * 4 + g8;
            bf16x8 af[4], bfv[4];
            #pragma unroll
            for (int i = 0; i < 4; ++i)
                af[i] = *(const bf16x8*)(As[cur] + (wr * 64 + i * 16 + rl) * 64 + (e ^ rx) * 8);
            #pragma unroll
            for (int j = 0; j < 4; ++j)
                bfv[j] = *(const bf16x8*)(Bs[cur] + (wc * 64 + j * 16 + rl) * 64 + (e ^ rx) * 8);
            #pragma unroll
            for (int i = 0; i < 4; ++i)
                #pragma unroll
                for (int j = 0; j < 4; ++j)
                    acc[i][j] = __builtin_amdgcn_mfma_f32_16x16x32_bf16(af[i], bfv[j], acc[i][j], 0, 0, 0);
        }

        __builtin_amdgcn_s_barrier();
        __builtin_amdgcn_sched_barrier(0);
        cur = nxt;
    }

    const int r0 = (lane >> 4) * 4, c0 = lane & 15;
    int flag = 0, h0 = 0;
    if (EPI == 4) { flag = flagp[0]; h0 = rowIdx[b]; }
    #pragma unroll
    for (int i = 0; i < 4; ++i)
        #pragma unroll
        for (int r = 0; r < 4; ++r) {
            int m = bm + wr * 64 + i * 16 + r0 + r;
            #pragma unroll
            for (int j = 0; j < 4; ++j) {
                int n = bn + wc * 64 + j * 16 + c0;
                epi_store<EPI>(acc[i][j][r], b, m, n, M, boff, bias, Dadd, ldd, denv,
                               smask, flag, h0, Cb, Cf, sC, ldc, bias2, Cb2, sC2, ldc2);
            }
        }
}

// ================= prep device functions =================

__device__ int d_detect(const unsigned int* __restrict__ sm) {
    __shared__ int sGt1, sF32, sOddNZ, sFlag;
    if (threadIdx.x == 0) { sGt1 = 0; sF32 = 0; sOddNZ = 0; }
    __syncthreads();
    int gt1 = 0, f32c = 0, oddnz = 0;
    for (int s = 0; s < 16; ++s) {
        int idx = s * 256 + threadIdx.x;
        unsigned wv = sm[idx];
        if (wv > 1u) gt1 = 1;
        if (wv == 0x3F800000u) f32c++;
        if ((idx & 1) && wv != 0u) oddnz = 1;
    }
    if (gt1)   atomicOr(&sGt1, 1);
    if (f32c)  atomicAdd(&sF32, f32c);
    if (oddnz) atomicOr(&sOddNZ, 1);
    __syncthreads();
    if (threadIdx.x == 0) {
        int f;
        if (sF32 > 512) f = 2;
        else if (!sGt1) f = sOddNZ ? 1 : 3;
        else f = 0;
        sFlag = f;
    }
    __syncthreads();
    return sFlag;
}

__device__ void d_trcvt(const float* __restrict__ src, bf16* __restrict__ dst,
                        int R, int C, int Rpad, int Cpad,
                        size_t sSrc, size_t sDst, int mode, int bx, int by, int bz) {
    __shared__ float t[32][33];
    int r0 = by * 32, c0 = bx * 32;
    int tx = threadIdx.x & 31, ty = threadIdx.x >> 5;
    const float* s = src + (size_t)bz * sSrc;
    bf16* d = dst + (size_t)bz * sDst;
    #pragma unroll
    for (int q = 0; q < 4; ++q) {
        int r = r0 + ty + q * 8, c = c0 + tx;
        t[ty + q * 8][tx] = (r < R && c < C) ? s[(size_t)r * C + c] : 0.f;
    }
    __syncthreads();
    #pragma unroll
    for (int q = 0; q < 4; ++q) {
        int dr = c0 + ty + q * 8, dc = r0 + tx;
        if (dr < Cpad && dc < Rpad) {
            int drm = dr;
            if (mode == 1) drm = (dr >> 9) * 1024 + (dr & 511);
            else if (mode == 2) drm = (dr >> 9) * 1024 + 512 + (dr & 511);
            d[(size_t)drm * Rpad + dc] = (bf16)t[tx][ty + q * 8];
        }
    }
}

// job boundaries (flat z)
#define PB_DET   1
#define PB_QKB   13
#define PB_CW2   1037
#define PB_ADJ   9229
#define PB_ROWS  17421
#define PB_INT   23565
#define PB_W0    24141
#define PB_W1    25293
#define PB_QW    27597
#define PB_KW    29901
#define PB_LC    30477
#define PB_F1    31053
#define PB_F2    31629
#define PB_CNT   31653

__global__ __launch_bounds__(256) void k_prep(
    const void* __restrict__ smask, int* __restrict__ flag, int* __restrict__ counts,
    const float* __restrict__ adj, bf16* __restrict__ adjb, float* __restrict__ den,
    const float* __restrict__ inputs, bf16* __restrict__ X, bf16* __restrict__ INT_,
    const float* __restrict__ convw, bf16* __restrict__ CW2,
    const float* __restrict__ qb, const float* __restrict__ kb, float* __restrict__ qkbD,
    const float* __restrict__ W0w, bf16* __restrict__ W0T,
    const float* __restrict__ W1w, bf16* __restrict__ W1T,
    const float* __restrict__ qw, const float* __restrict__ kw, bf16* __restrict__ QKWT,
    const float* __restrict__ lincw, bf16* __restrict__ LCT,
    const float* __restrict__ fc1w, bf16* __restrict__ F1T,
    const float* __restrict__ fc2w, bf16* __restrict__ F2T)
{
    const int id = blockIdx.x;
    const size_t sND = (size_t)N_ * D_;
    if (id < PB_DET) {
        int f = d_detect((const unsigned int*)smask);
        if (threadIdx.x == 0) flag[0] = f;
    } else if (id < PB_QKB) {
        int idx = (id - PB_DET) * 256 + threadIdx.x;
        if (idx < 3072) {
            int h = idx >> 10, rem = idx & 1023, s = rem >> 9, r = rem & 511;
            qkbD[idx] = (s ? kb : qb)[h * 512 + r];
        }
    } else if (id < PB_CW2) {
        int o = id - PB_QKB;
        const float* s = convw + (size_t)o * 3072;
        bf16* dp = CW2 + (size_t)o * 3072;
        for (int q = 0; q < 4; ++q) {
            int i = q * 256 + threadIdx.x;
            float v0 = s[i * 3], v1 = s[i * 3 + 1], v2 = s[i * 3 + 2];
            dp[i] = (bf16)v0; dp[1024 + i] = (bf16)v1; dp[2048 + i] = (bf16)v2;
        }
    } else if (id < PB_ADJ) {
        int t = id - PB_CW2;
        int row = t & 1023, b = t >> 10;
        size_t base = ((size_t)b * N_ + row) * N_;
        float4 v = ((const float4*)(adj + base))[threadIdx.x];
        union { bf16 b[4]; uint2 u; } o;
        o.b[0] = (bf16)v.x; o.b[1] = (bf16)v.y; o.b[2] = (bf16)v.z; o.b[3] = (bf16)v.w;
        ((uint2*)(adjb + base))[threadIdx.x] = o.u;
        float s = blockSum256(v.x + v.y + v.z + v.w);
        if (threadIdx.x == 0) den[b * N_ + row] = s + 1.0f;
    } else if (id < PB_ROWS) {
        int row = id - PB_ADJ;
        int t = threadIdx.x;
        if (t < 192) {
            float4 v = ((const float4*)(inputs + (size_t)row * D_))[t];
            union { bf16 b[4]; uint2 u; } o;
            o.b[0] = (bf16)v.x; o.b[1] = (bf16)v.y; o.b[2] = (bf16)v.z; o.b[3] = (bf16)v.w;
            *(uint2*)(X + (size_t)row * DC_ + t * 4) = o.u;
        }
    } else if (id < PB_INT) {
        int t = id - PB_ROWS;
        int bx = t % 24; int u = t / 24; int by = u % 32; int bz = u / 32;
        d_trcvt(inputs, INT_, N_, D_, N_, D_, sND, sND, 0, bx, by, bz);
    } else if (id < PB_W0) {
        int t = id - PB_INT;
        d_trcvt(W0w, W0T, D_, D_, D_, D_, 0, 0, 0, t % 24, t / 24, 0);
    } else if (id < PB_W1) {
        int t = id - PB_W0;
        d_trcvt(W1w, W1T, DC_, D_, DC_, D_, 0, 0, 0, t % 24, t / 24, 0);
    } else if (id < PB_QW) {
        int t = id - PB_W1;
        d_trcvt(qw, QKWT, DC_, DC_, DC_, DC_, 0, 0, 1, t % 48, t / 48, 0);
    } else if (id < PB_KW) {
        int t = id - PB_QW;
        d_trcvt(kw, QKWT, DC_, DC_, DC_, DC_, 0, 0, 2, t % 48, t / 48, 0);
    } else if (id < PB_LC) {
        int t = id - PB_KW;
        d_trcvt(lincw, LCT, PC_, D_, D_, D_, 0, 0, 0, t % 24, t / 24, 0);
    } else if (id < PB_F1) {
        int t = id - PB_LC;
        d_trcvt(fc1w, F1T, D_, D_, D_, D_, 0, 0, 0, t % 24, t / 24, 0);
    } else if (id < PB_F2) {
        int t = id - PB_F1;
        d_trcvt(fc2w, F2T, D_, D_, D_, D_, 0, 0, 0, t % 24, t / 24, 0);
    } else if (id < PB_CNT) {
        int bh = id - PB_F2;
        int f = d_detect((const unsigned int*)smask);
        float c = 0.f;
        for (int s = 0; s < 4; ++s) {
            int q = s * 256 + threadIdx.x;
            size_t mi = ((size_t)bh * N_ + q) * N_;
            if (!mask_at(smask, f, mi)) c += 1.f;
        }
        c = blockSum256(c);
        if (threadIdx.x == 0) counts[bh] = (int)(c + 0.5f);
    }
}

// ================= remaining support kernels =================

__global__ void k_select_head(const int* __restrict__ counts, int* __restrict__ hsel) {
    if (threadIdx.x != 0 || blockIdx.x != 0) return;
    float p[B_][H_];
    for (int h = 0; h < H_; ++h) {
        float mx = -1e30f;
        for (int b = 0; b < B_; ++b) mx = fmaxf(mx, (float)counts[b * H_ + h]);
        float s = 0.f;
        for (int b = 0; b < B_; ++b) { p[b][h] = expf((float)counts[b * H_ + h] - mx); s += p[b][h]; }
        for (int b = 0; b < B_; ++b) p[b][h] /= s;
    }
    for (int b = 0; b < B_; ++b) {
        int best = 0; float bv = p[b][0];
        for (int h = 1; h < H_; ++h) if (p[b][h] > bv) { bv = p[b][h]; best = h; }
        hsel[b] = best;
    }
}

// row stats + per-row top2 (normalized value, col) + diag/den2 + ax2 diag init.
// READ-ONLY on ATTN: raw masked scores stay in place; normalized attention is
// recomputed on demand as exp(raw - mx) * inv  (inv = keep/sum) -- bit-identical.
__global__ __launch_bounds__(256) void k_softmax(const float* __restrict__ Sc,
                                                 const void* __restrict__ smask,
                                                 const int* __restrict__ flagp,
                                                 const int* __restrict__ hsel,
                                                 float4* __restrict__ t2p,
                                                 float2* __restrict__ rowst,
                                                 float* __restrict__ adiag,
                                                 float* __restrict__ den2,
                                                 const bf16* __restrict__ x,
                                                 bf16* __restrict__ ax2) {
    __shared__ float s1[256], s2[256];
    __shared__ int sc1[256], sc2[256];
    __shared__ float sdiag;
    int b = blockIdx.y, row = blockIdx.x;
    int h0 = hsel[b], flag = flagp[0];
    const float* rp = Sc + ((size_t)b * N_ + row) * N_;
    float v[4];
    float mx = -INFINITY;
    #pragma unroll
    for (int s = 0; s < 4; ++s) { v[s] = rp[s * 256 + threadIdx.x]; mx = fmaxf(mx, v[s]); }
    mx = blockMax256(mx);
    float sum = 0.f;
    #pragma unroll
    for (int s = 0; s < 4; ++s) { v[s] = expf(v[s] - mx); sum += v[s]; }
    sum = blockSum256(sum);
    size_t ki = (((size_t)b * H_ + h0) * N_ + row) * N_;
    float keep = mask_at(smask, flag, ki) ? 0.f : 1.f;
    float inv = keep / sum;
    float m1 = -INFINITY, m2 = -INFINITY;
    int c1 = 0, c2 = 0;
    #pragma unroll
    for (int s = 0; s < 4; ++s) {
        int col = s * 256 + threadIdx.x;
        float xv = v[s] * inv;
        if (col == row) sdiag = xv;
        if (xv > m1) { m2 = m1; c2 = c1; m1 = xv; c1 = col; }
        else if (xv > m2) { m2 = xv; c2 = col; }
    }
    int tid = threadIdx.x;
    s1[tid] = m1; sc1[tid] = c1; s2[tid] = m2; sc2[tid] = c2;
    __syncthreads();
    for (int off = 128; off; off >>= 1) {
        if (tid < off) {
            float a1 = s1[tid], a2 = s2[tid];
            int ac1 = sc1[tid], ac2 = sc2[tid];
            float b1 = s1[tid + off], b2 = s2[tid + off];
            int bc1 = sc1[tid + off], bc2 = sc2[tid + off];
            float n1, n2; int nc1, nc2;
            if (b1 > a1) {
                n1 = b1; nc1 = bc1;
                if (a1 >= b2) { n2 = a1; nc2 = ac1; } else { n2 = b2; nc2 = bc2; }
            } else {
                n1 = a1; nc1 = ac1;
                if (b1 >= a2) { n2 = b1; nc2 = bc1; } else { n2 = a2; nc2 = ac2; }
            }
            s1[tid] = n1; sc1[tid] = nc1; s2[tid] = n2; sc2[tid] = nc2;
        }
        __syncthreads();
    }
    if (tid == 0) {
        float4 o; o.x = s1[0]; o.y = (float)sc1[0]; o.z = s2[0]; o.w = (float)sc2[0];
        t2p[(size_t)b * N_ + row] = o;
        float2 rs; rs.x = mx; rs.y = inv;
        rowst[(size_t)b * N_ + row] = rs;
        adiag[b * N_ + row] = sdiag;
        den2[b * N_ + row] = sdiag + 1.0f;
    }
    __syncthreads();
    float a = sdiag;
    const bf16* xp = x + ((size_t)b * N_ + row) * DC_;
    bf16* op = ax2 + ((size_t)b * N_ + row) * DC_;
    #pragma unroll
    for (int s = 0; s < 6; ++s) {
        int d = s * 256 + threadIdx.x;
        op[d] = (bf16)(a * (float)xp[d]);
    }
}

// global top-2 threshold + candidate selection from per-row top2 records
__global__ __launch_bounds__(256) void k_top2sel(const float4* __restrict__ t2p,
                                                 float* __restrict__ thr,
                                                 int* __restrict__ selcnt,
                                                 int* __restrict__ sel) {
    __shared__ float s1[256], s2[256];
    __shared__ int scnt;
    int b = blockIdx.x, tid = threadIdx.x;
    float m1 = -INFINITY, m2 = -INFINITY;
    for (int s = 0; s < 4; ++s) {
        float4 p = t2p[(size_t)b * N_ + s * 256 + tid];
        float n1 = fmaxf(m1, p.x);
        float n2 = fmaxf(fminf(m1, p.x), fmaxf(m2, p.z));
        m1 = n1; m2 = n2;
    }
    s1[tid] = m1; s2[tid] = m2;
    __syncthreads();
    for (int off = 128; off; off >>= 1) {
        if (tid < off) {
            float a1 = s1[tid], a2 = s2[tid], b1 = s1[tid + off], b2 = s2[tid + off];
            s1[tid] = fmaxf(a1, b1);
            s2[tid] = fmaxf(fminf(a1, b1), fmaxf(a2, b2));
        }
        __syncthreads();
    }
    if (tid == 0) { thr[b] = s2[0]; scnt = 0; }
    __syncthreads();
    float t = s2[0];
    for (int s = 0; s < 4; ++s) {
        int row = s * 256 + tid;
        float4 p = t2p[(size_t)b * N_ + row];
        if (p.x >= t) {
            int pos = atomicAdd(&scnt, 1);
            if (pos < 512) {
                sel[((size_t)b * 512 + pos) * 2]     = row;
                sel[((size_t)b * 512 + pos) * 2 + 1] = (int)p.y;
            }
        }
        if (p.z >= t) {
            int pos = atomicAdd(&scnt, 1);
            if (pos < 512) {
                sel[((size_t)b * 512 + pos) * 2]     = row;
                sel[((size_t)b * 512 + pos) * 2 + 1] = (int)p.w;
            }
        }
    }
    __syncthreads();
    if (tid == 0) selcnt[b] = scnt;
}

// sparse symmetrized top-2 contributions; attention values recomputed from
// raw scores + row stats (exp(raw - mx) * inv), identical to stored values.
__global__ __launch_bounds__(256) void k_ax2_sparse(const float* __restrict__ attn,
                                                    const float2* __restrict__ rowst,
                                                    const bf16* __restrict__ x,
                                                    const int* __restrict__ selcnt,
                                                    const int* __restrict__ sel,
                                                    bf16* __restrict__ ax2,
                                                    float* __restrict__ den2) {
    int b = blockIdx.x;
    int cnt = selcnt[b]; if (cnt > 512) cnt = 512;
    __shared__ int si[1024];
    if (threadIdx.x == 0) {
        for (int e = 0; e < cnt; ++e) {
            si[e * 2]     = sel[((size_t)b * 512 + e) * 2];
            si[e * 2 + 1] = sel[((size_t)b * 512 + e) * 2 + 1];
        }
        for (int a = 1; a < cnt; ++a) {
            int ii = si[a * 2], jj = si[a * 2 + 1];
            long long key = (long long)ii * N_ + jj;
            int p = a - 1;
            while (p >= 0 && ((long long)si[p * 2] * N_ + si[p * 2 + 1]) > key) {
                si[(p + 1) * 2] = si[p * 2]; si[(p + 1) * 2 + 1] = si[p * 2 + 1]; --p;
            }
            si[(p + 1) * 2] = ii; si[(p + 1) * 2 + 1] = jj;
        }
    }
    __syncthreads();
    const float* ap = attn + (size_t)b * N_ * N_;
    const float2* rs = rowst + (size_t)b * N_;
    for (int e = 0; e < cnt; ++e) {
        int i = si[e * 2], j = si[e * 2 + 1];
        if (i == j) continue;
        float2 ri_s = rs[i], rj_s = rs[j];
        float aij = expf(ap[(size_t)i * N_ + j] - ri_s.x) * ri_s.y;
        float aji = expf(ap[(size_t)j * N_ + i] - rj_s.x) * rj_s.y;
        bf16* ri = ax2 + ((size_t)b * N_ + i) * DC_;
        bf16* rj = ax2 + ((size_t)b * N_ + j) * DC_;
        const bf16* xi = x + ((size_t)b * N_ + i) * DC_;
        const bf16* xj = x + ((size_t)b * N_ + j) * DC_;
        for (int s = 0; s < 6; ++s) {
            int d = s * 256 + threadIdx.x;
            ri[d] = (bf16)((float)ri[d] + aij * (float)xj[d]);
            rj[d] = (bf16)((float)rj[d] + aji * (float)xi[d]);
        }
        if (threadIdx.x == 0) {
            den2[b * N_ + i] += aij;
            den2[b * N_ + j] += aji;
        }
        __syncthreads();
    }
}

// ---------------- launch ----------------
extern "C" void kernel_launch(void* const* d_in, const int* in_sizes, int n_in,
                              void* d_out, int out_size, void* d_ws, size_t ws_size,
                              hipStream_t stream) {
    if (n_in < 17) return;
    if (ws_size < WS_NEED) return;

    const float* adj    = (const float*)d_in[0];
    const float* inputs = (const float*)d_in[1];
    const void*  smask  = d_in[2];
    const float* W0w = (const float*)d_in[3];
    const float* W0b = (const float*)d_in[4];
    const float* W1w = (const float*)d_in[5];
    const float* W1b = (const float*)d_in[6];
    const float* qw  = (const float*)d_in[7];
    const float* qb  = (const float*)d_in[8];
    const float* kw  = (const float*)d_in[9];
    const float* kb  = (const float*)d_in[10];
    const float* convw = (const float*)d_in[11];
    const float* convb = (const float*)d_in[12];
    const float* lincw = (const float*)d_in[13];
    const float* lincb = (const float*)d_in[14];
    const float* fc1w  = (const float*)d_in[15];
    const float* fc2w  = (const float*)d_in[16];

    char* W = (char*)d_ws;
    float* out = (float*)d_out;

    float* den    = (float*)(W + O_DEN);
    float* den2   = (float*)(W + O_DEN2);
    float* adiag  = (float*)(W + O_ADIAG);
    float2* rowst = (float2*)(W + O_RST);
    float* thr    = (float*)(W + O_THR);
    int*   counts = (int*)(W + O_CNTS);
    int*   hsel   = (int*)(W + O_HSEL);
    int*   selcnt = (int*)(W + O_SELC);
    int*   flag   = (int*)(W + O_FLAG);
    float* qkb    = (float*)(W + O_QKB);
    int*   sel    = (int*)(W + O_SEL);
    float* ATTN   = (float*)(W + O_ATTN);
    float4* t2p4  = (float4*)(W + O_T2P4);
    bf16* X     = (bf16*)(W + O_X);
    bf16* AX2   = (bf16*)(W + O_AX2);
    bf16* QKOUT = (bf16*)(W + O_AX2);
    bf16* ADJB  = (bf16*)(W + O_ADJB);
    bf16* INT_  = (bf16*)(W + O_INT);
    bf16* OUT0T = (bf16*)(W + O_OUT0T);
    bf16* BBA   = (bf16*)(W + O_BBA);
    bf16* BBB   = (bf16*)(W + O_BBB);
    bf16* BBC   = (bf16*)(W + O_BBC);
    bf16* W0T   = (bf16*)(W + O_W0T);
    bf16* W1T   = (bf16*)(W + O_W1T);
    bf16* QKWT  = (bf16*)(W + O_QKWT);
    bf16* CW2   = (bf16*)(W + O_CWB);
    bf16* LCT   = (bf16*)(W + O_LCT);
    bf16* F1T   = (bf16*)(W + O_F1T);
    bf16* F2T   = (bf16*)(W + O_F2T);

    const size_t sND  = (size_t)N_ * D_;
    const size_t sNDC = (size_t)N_ * DC_;
    const size_t sNN  = (size_t)N_ * N_;

    // ---- all prep in one dispatch ----
    k_prep<<<PB_CNT, 256, 0, stream>>>(smask, flag, counts,
        adj, ADJB, den, inputs, X, INT_, convw, CW2,
        qb, kb, qkb, W0w, W0T, W1w, W1T, qw, kw, QKWT,
        lincw, LCT, fc1w, F1T, fc2w, F2T);
    k_select_head<<<1, 64, 0, stream>>>(counts, hsel);

    // ---- GCN layer 0: xW0 and Ax jammed in one dispatch (independent) ----
    mmJam<<<dim3(6, 16, 16), 256, 0, stream>>>(
        X, sNDC, DC_, W0T, 0, D_, W0b, BBA, sND, D_, D_,
        ADJB, sNN, N_, INT_, sND, N_, BBB, sND, D_, N_);
    // out0 written DIRECTLY TRANSPOSED into OUT0T (EPI 8)
    mm<8><<<dim3(6, 16, B_), 256, 0, stream>>>(BBB, sND, D_, W0T, 0, D_, nullptr, 0,
        W0b, BBA, D_, den, nullptr, nullptr, OUT0T, nullptr, sND, N_, N_, D_, D_,
        nullptr, nullptr, nullptr, 0, 0);
    mm<5><<<dim3(6, 16, B_), 256, 0, stream>>>(CW2, 0, 3072, OUT0T, sND, N_, nullptr, 0,
        convb, nullptr, 0, nullptr, nullptr, nullptr, BBB, nullptr, sND, D_, N_, D_, 3072,
        nullptr, nullptr, nullptr, 0, 0);
    mm<0><<<dim3(6, 16, B_), 256, 0, stream>>>(BBB, sND, D_, LCT, 0, D_, nullptr, 0,
        lincb, nullptr, 0, nullptr, nullptr, nullptr, X + D_, nullptr, sNDC, DC_, N_, D_, D_,
        nullptr, nullptr, nullptr, 0, 0);

    // ---- merged Q|K projection + xW1 (EPI 7, 128x128 tiles): N = 1792, grid 896 ----
    mm2<7><<<dim3(14, 8, B_), 256, 0, stream>>>(X, sNDC, DC_, QKWT, 0, DC_, hsel, 1024,
        qkb, nullptr, 0, nullptr, nullptr, nullptr, QKOUT, nullptr, sNN, N_, N_, 1792, DC_,
        W1T, W1b, BBA, sND, D_);

    // ---- scores (fp32, masked; 128x128 tiles): grid 512 = 2/CU balanced ----
    mm2<4><<<dim3(8, 8, B_), 256, 0, stream>>>(QKOUT, sNN, N_, QKOUT + 512, sNN, N_, hsel, 0,
        nullptr, nullptr, 0, nullptr, smask, flag, nullptr, ATTN, sNN, N_, N_, N_, DK_,
        nullptr, nullptr, nullptr, 0, 0);

    // ---- row stats + top2 + diag/den2 + ax2 init (ATTN read-only; no 32MB write) ----
    k_softmax<<<dim3(N_, B_), 256, 0, stream>>>(ATTN, smask, flag, hsel, t2p4,
                                                rowst, adiag, den2, X, AX2);

    // ---- top-2 threshold + candidate selection (no ATTN rescan) ----
    k_top2sel<<<B_, 256, 0, stream>>>(t2p4, thr, selcnt, sel);
    k_ax2_sparse<<<B_, 256, 0, stream>>>(ATTN, rowst, X, selcnt, sel, AX2, den2);

    // ---- GCN layer 1 (xW1 already in BBA from merged GEMM) ----
    mm<1><<<dim3(6, 16, B_), 256, 0, stream>>>(AX2, sNDC, DC_, W1T, 0, DC_, nullptr, 0,
        W1b, BBA, D_, den2, nullptr, nullptr, BBB, nullptr, sND, D_, N_, D_, DC_,
        nullptr, nullptr, nullptr, 0, 0);

    // ---- fc ----
    mm<2><<<dim3(6, 16, B_), 256, 0, stream>>>(BBB, sND, D_, F1T, 0, D_, nullptr, 0,
        nullptr, nullptr, 0, nullptr, nullptr, nullptr, BBC, nullptr, sND, D_, N_, D_, D_,
        nullptr, nullptr, nullptr, 0, 0);
    mm<3><<<dim3(6, 16, B_), 256, 0, stream>>>(BBC, sND, D_, F2T, 0, D_, nullptr, 0,
        nullptr, nullptr, 0, nullptr, nullptr, nullptr, nullptr, out, sND, D_, N_, D_, D_,
        nullptr, nullptr, nullptr, 0, 0);
}